// Round 8
// baseline (900.811 us; speedup 1.0000x reference)
//
#include <hip/hip_runtime.h>
#include <hip/hip_bf16.h>

// ---------------------------------------------------------------------------
// PDNConv GNN, MI355X round 8.
// Round-7 profile: edge_mlp_mfma #1 (73 us) with 4.05M LDS bank conflicts —
// it restaged block-invariant W1t into LDS 9375x and read it back conflicted.
//  Fix 1: LDS-free edge MLP — B-frags in registers from global (L1-hot),
//         A-frags gathered per-lane from eattr, 256 edges/block.
//  Fix 2: aggregate gather traffic halved — lin GEMM emits bf16 hl16 only;
//         aggregate gathers 256B/row instead of 512B (f32 accumulate kept).
// Everything else unchanged from round 7.
// ---------------------------------------------------------------------------

#define NN 50000
#define EE 600000
#define GG 256
#define HID 128
#define EDIM 16
#define EHID 64
#define NL 4
#define MIN_F 200
#define MH 256
#define MOUT 128
#define PH 512
#define PIN 256
#define SCAN_B 196  // ceil(NN/256)

typedef __hip_bfloat16 bf16;
typedef __attribute__((ext_vector_type(8))) short bf16x8;
typedef __attribute__((ext_vector_type(4))) float f32x4;

__device__ __forceinline__ float bfl(unsigned u) { return __uint_as_float(u << 16); }
__device__ __forceinline__ float bfh(unsigned u) { return __uint_as_float(u & 0xffff0000u); }
__device__ __forceinline__ float b2f(bf16 x) { return __bfloat162float(x); }
__device__ __forceinline__ float ldf(const void* p, long i, bool bf) {
  return bf ? __bfloat162float(((const bf16*)p)[i]) : ((const float*)p)[i];
}
__device__ __forceinline__ unsigned short f2bf_bits(float v) {
  bf16 h = __float2bfloat16(v);
  return *reinterpret_cast<unsigned short*>(&h);
}

// ---------------- dtype probe ------------------------------------------------
__global__ void probe_kernel(const unsigned short* __restrict__ xs, int* flag) {
  if (threadIdx.x == 0 && blockIdx.x == 0) {
    int sane = 0;
    for (int i = 0; i < 128; i++) {
      unsigned e = (xs[i] >> 7) & 0xFF;
      if (e >= 96 && e <= 159) sane++;
    }
    *flag = (sane >= 112) ? 1 : 0;  // 1 = bf16 inputs
  }
}

// ---------------- input -> f32 conversion (4 elems/thread) ------------------
__global__ __launch_bounds__(256) void cvt_any(const void* __restrict__ in,
                                               float* __restrict__ outp, int n4,
                                               const int* __restrict__ flag) {
  bool bf = *flag != 0;
  int i = blockIdx.x * 256 + threadIdx.x;
  if (i >= n4) return;
  float4 v;
  if (bf) {
    uint2 u = reinterpret_cast<const uint2*>(in)[i];
    v.x = bfl(u.x); v.y = bfh(u.x); v.z = bfl(u.y); v.w = bfh(u.y);
  } else {
    v = reinterpret_cast<const float4*>(in)[i];
  }
  reinterpret_cast<float4*>(outp)[i] = v;
}

// ---------------- mol_features [G,200] -> padded f32 [G,256] ----------------
__global__ __launch_bounds__(256) void cvt_molf(const void* __restrict__ in,
                                                float* __restrict__ outp,
                                                const int* __restrict__ flag) {
  bool bf = *flag != 0;
  int i = blockIdx.x * 256 + threadIdx.x;  // GG*50
  if (i >= GG * 50) return;
  int row = i / 50, c4 = (i % 50) * 4;
  float4 v;
  if (bf) {
    const unsigned short* p = (const unsigned short*)in + (size_t)row * MIN_F + c4;
    uint2 u = *reinterpret_cast<const uint2*>(p);
    v.x = bfl(u.x); v.y = bfh(u.x); v.z = bfl(u.y); v.w = bfh(u.y);
  } else {
    v = *reinterpret_cast<const float4*>((const float*)in + (size_t)row * MIN_F + c4);
  }
  *reinterpret_cast<float4*>(&outp[(size_t)row * 256 + c4]) = v;
}

// ---------------- weight prep: node GEMM weights -> bf16 Wt[n][k] -----------
__global__ __launch_bounds__(256) void prep_weights(const void* __restrict__ lin_W,
                                                    const void* __restrict__ gW,
                                                    unsigned short* __restrict__ Wt,
                                                    const int* __restrict__ flag) {
  bool bf = *flag != 0;
  int idx = blockIdx.x * 256 + threadIdx.x;  // 0 .. 8*16384-1
  if (idx >= 8 * 16384) return;
  int mat = idx >> 14;
  int rem = idx & 16383;
  int n = rem >> 7, k = rem & 127;
  const void* src = (mat < 4) ? lin_W : gW;
  long srcIdx = (long)(mat & 3) * 16384 + (long)k * 128 + n;
  Wt[idx] = f2bf_bits(ldf(src, srcIdx, bf));
}

// ---------------- weight prep: edge MLP W1 -> bf16 W1t[256 cols][32 K] ------
__global__ __launch_bounds__(256) void prep_edge_w(const void* __restrict__ mW1,
                                                   unsigned short* __restrict__ W1t,
                                                   const int* __restrict__ flag) {
  bool bf = *flag != 0;
  int idx = blockIdx.x * 256 + threadIdx.x;  // 256*32
  if (idx >= 256 * 32) return;
  int col = idx >> 5, k = idx & 31;
  float v = 0.f;
  if (k < EDIM) v = ldf(mW1, (long)(col >> 6) * (EDIM * EHID) + (long)k * EHID + (col & 63), bf);
  W1t[idx] = f2bf_bits(v);
}

// ---------------- weight prep: tail (MLP+predictor) -> bf16 [N][Kp], K-pad --
__global__ __launch_bounds__(256) void prep_tail(
    const void* __restrict__ mlpW0, const void* __restrict__ mlpW1,
    const void* __restrict__ mlpW2, const void* __restrict__ mlpW3,
    const void* __restrict__ predW0, const void* __restrict__ predW1,
    unsigned short* __restrict__ T, const int* __restrict__ flag) {
  bool bf = *flag != 0;
  int idx = blockIdx.x * 256 + threadIdx.x;
  const void* src; int N, Kp, Ksrc, off;
  if      (idx < 65536)  { src = mlpW0;  N = 256; Kp = 256; Ksrc = 200; off = 0; }
  else if (idx < 131072) { src = mlpW1;  N = 256; Kp = 256; Ksrc = 256; off = 65536; }
  else if (idx < 196608) { src = mlpW2;  N = 256; Kp = 256; Ksrc = 256; off = 131072; }
  else if (idx < 229376) { src = mlpW3;  N = 128; Kp = 256; Ksrc = 256; off = 196608; }
  else if (idx < 360448) { src = predW0; N = 512; Kp = 256; Ksrc = 256; off = 229376; }
  else if (idx < 622592) { src = predW1; N = 512; Kp = 512; Ksrc = 512; off = 360448; }
  else return;
  int rem = idx - off;
  int n = rem / Kp, k = rem % Kp;
  float v = (k < Ksrc) ? ldf(src, (long)k * N + n, bf) : 0.f;
  T[idx] = f2bf_bits(v);
}

// ---------------- CSR build: histogram / 3-phase scan / fill ----------------
__global__ __launch_bounds__(256) void count_kernel(const int* __restrict__ ei,
                                                    int* __restrict__ cnt) {
  int e = blockIdx.x * 256 + threadIdx.x;
  if (e >= EE) return;
  int c = ei[EE + e];
  c = min(max(c, 0), NN - 1);
  atomicAdd(&cnt[c], 1);
}

__global__ __launch_bounds__(256) void scan_phase1(const int* __restrict__ cnt,
                                                   int* __restrict__ bsum) {
  __shared__ int red[256];
  int tid = threadIdx.x;
  int i = blockIdx.x * 256 + tid;
  red[tid] = (i < NN) ? cnt[i] : 0;
  __syncthreads();
  for (int off = 128; off > 0; off >>= 1) {
    if (tid < off) red[tid] += red[tid + off];
    __syncthreads();
  }
  if (tid == 0) bsum[blockIdx.x] = red[0];
}

__global__ __launch_bounds__(256) void scan_phase2(int* __restrict__ bsum,
                                                   int* __restrict__ offs) {
  __shared__ int buf[256];
  int tid = threadIdx.x;
  int v = (tid < SCAN_B) ? bsum[tid] : 0;
  buf[tid] = v;
  __syncthreads();
  for (int off = 1; off < 256; off <<= 1) {
    int t = (tid >= off) ? buf[tid - off] : 0;
    __syncthreads();
    buf[tid] += t;
    __syncthreads();
  }
  if (tid < SCAN_B) bsum[tid] = buf[tid] - v;  // exclusive block offsets
  if (tid == 255) offs[NN] = buf[255];
}

__global__ __launch_bounds__(256) void scan_phase3(const int* __restrict__ cnt,
                                                   const int* __restrict__ bsum,
                                                   int* __restrict__ offs) {
  __shared__ int buf[256];
  int tid = threadIdx.x;
  int i = blockIdx.x * 256 + tid;
  int v = (i < NN) ? cnt[i] : 0;
  buf[tid] = v;
  __syncthreads();
  for (int off = 1; off < 256; off <<= 1) {
    int t = (tid >= off) ? buf[tid - off] : 0;
    __syncthreads();
    buf[tid] += t;
    __syncthreads();
  }
  if (i < NN) offs[i] = bsum[blockIdx.x] + buf[tid] - v;
}

__global__ __launch_bounds__(256) void fill_kernel(const int* __restrict__ ei,
                                                   const int* __restrict__ offs,
                                                   int* __restrict__ cursor,
                                                   int* __restrict__ csr_src,
                                                   int* __restrict__ csr_eid) {
  int e = blockIdx.x * 256 + threadIdx.x;
  if (e >= EE) return;
  int c = ei[EE + e];
  c = min(max(c, 0), NN - 1);
  int pos = offs[c] + atomicAdd(&cursor[c], 1);
  pos = min(max(pos, 0), EE - 1);
  csr_src[pos] = ei[e];
  csr_eid[pos] = e;
}

// ---------------- edge-gate MLP via MFMA, LDS-free --------------------------
// B-fragments (block-invariant 16 KB W1t) live in registers, loaded from
// global (L1-hot). A-fragments gathered per-lane from eattr. 256 edges/block:
// 4 waves x 4 sequential 16-edge fragments.
__global__ __launch_bounds__(256) void edge_mlp_mfma(
    const void* __restrict__ eattr, const unsigned short* __restrict__ W1t,
    const void* __restrict__ mb1, const void* __restrict__ mW2,
    const void* __restrict__ mb2, const int* __restrict__ csr_eid,
    float* __restrict__ csr_val, const int* __restrict__ flag) {
  bool bf = *flag != 0;
  int tid = threadIdx.x;
  int wave = tid >> 6, lane = tid & 63;
  int l15 = lane & 15, quad = lane >> 4;

  // B frags: lane (l15,quad) holds W1t[t*16+l15][quad*8 .. +8)  (coalesced 1KB/t)
  bf16x8 bfrag[16];
#pragma unroll
  for (int t = 0; t < 16; t++)
    bfrag[t] = *reinterpret_cast<const bf16x8*>(&W1t[(t * 16 + l15) * 32 + quad * 8]);

  float b1v[16], w2v[16];
#pragma unroll
  for (int t = 0; t < 16; t++) {
    int col = t * 16 + l15;
    b1v[t] = ldf(mb1, col, bf);
    w2v[t] = ldf(mW2, col, bf);
  }
  float b2v0 = ldf(mb2, 0, bf), b2v1 = ldf(mb2, 1, bf);
  float b2v2 = ldf(mb2, 2, bf), b2v3 = ldf(mb2, 3, bf);

  int ebase = blockIdx.x * 256 + wave * 64;
#pragma unroll
  for (int f = 0; f < 4; f++) {
    int fbase = ebase + f * 16;
    if (fbase < EE) {
      int eidx = min(fbase + l15, EE - 1);
      long eid = csr_eid[eidx];
      bf16x8 a = (bf16x8){0, 0, 0, 0, 0, 0, 0, 0};
      if (quad < 2) {
        if (bf) {
          uint4 v = *reinterpret_cast<const uint4*>((const bf16*)eattr + eid * EDIM + quad * 8);
          a = *reinterpret_cast<bf16x8*>(&v);
        } else {
          const float4* p =
              reinterpret_cast<const float4*>((const float*)eattr + eid * EDIM + quad * 8);
          float4 v0 = p[0], v1 = p[1];
          a[0] = (short)f2bf_bits(v0.x); a[1] = (short)f2bf_bits(v0.y);
          a[2] = (short)f2bf_bits(v0.z); a[3] = (short)f2bf_bits(v0.w);
          a[4] = (short)f2bf_bits(v1.x); a[5] = (short)f2bf_bits(v1.y);
          a[6] = (short)f2bf_bits(v1.z); a[7] = (short)f2bf_bits(v1.w);
        }
      }
      float s0[4] = {0.f, 0.f, 0.f, 0.f};
      float s1[4] = {0.f, 0.f, 0.f, 0.f};
      float s2[4] = {0.f, 0.f, 0.f, 0.f};
      float s3[4] = {0.f, 0.f, 0.f, 0.f};
#pragma unroll
      for (int t = 0; t < 16; t++) {
        f32x4 acc = __builtin_amdgcn_mfma_f32_16x16x32_bf16(
            a, bfrag[t], (f32x4){0.f, 0.f, 0.f, 0.f}, 0, 0, 0);
        float* s = (t < 4) ? s0 : (t < 8) ? s1 : (t < 12) ? s2 : s3;
#pragma unroll
        for (int r = 0; r < 4; r++)
          s[r] += fmaxf(acc[r] + b1v[t], 0.f) * w2v[t];
      }
#pragma unroll
      for (int m = 1; m <= 8; m <<= 1) {
#pragma unroll
        for (int r = 0; r < 4; r++) {
          s0[r] += __shfl_xor(s0[r], m);
          s1[r] += __shfl_xor(s1[r], m);
          s2[r] += __shfl_xor(s2[r], m);
          s3[r] += __shfl_xor(s3[r], m);
        }
      }
      if (l15 < NL) {
        float b2 = (l15 == 0) ? b2v0 : (l15 == 1) ? b2v1 : (l15 == 2) ? b2v2 : b2v3;
#pragma unroll
        for (int r = 0; r < 4; r++) {
          float sv = (l15 == 0) ? s0[r] : (l15 == 1) ? s1[r] : (l15 == 2) ? s2[r] : s3[r];
          int e = fbase + quad * 4 + r;
          if (e < EE)
            csr_val[(size_t)l15 * EE + e] = 1.f / (1.f + __expf(-(sv + b2)));
        }
      }
    }
  }
}

// ---------------- degree / dinv per layer -----------------------------------
__global__ __launch_bounds__(256) void deg_kernel(const int* __restrict__ offs,
                                                  const float* __restrict__ csr_val,
                                                  float* __restrict__ dinv_all) {
  int n = blockIdx.x * 256 + threadIdx.x;
  if (n >= NN) return;
  int s = offs[n], e = offs[n + 1];
  float d0 = 1.f, d1 = 1.f, d2 = 1.f, d3 = 1.f;  // self-loop weight 1.0
  for (int k = s; k < e; k++) {
    d0 += csr_val[k];
    d1 += csr_val[EE + k];
    d2 += csr_val[2 * (size_t)EE + k];
    d3 += csr_val[3 * (size_t)EE + k];
  }
  dinv_all[n] = rsqrtf(d0);
  dinv_all[NN + n] = rsqrtf(d1);
  dinv_all[2 * NN + n] = rsqrtf(d2);
  dinv_all[3 * NN + n] = rsqrtf(d3);
}

// csr_val[l][k] *= dinv_l[src_k]
__global__ __launch_bounds__(256) void csr_scale_kernel(const int* __restrict__ csr_src,
                                                        const float* __restrict__ dinv_all,
                                                        float* __restrict__ csr_val) {
  int k = blockIdx.x * 256 + threadIdx.x;
  if (k >= EE) return;
  int s = csr_src[k];
  s = min(max(s, 0), NN - 1);
#pragma unroll
  for (int l = 0; l < NL; l++)
    csr_val[(size_t)l * EE + k] *= dinv_all[(size_t)l * NN + s];
}

// ---------------- node GEMM via MFMA ----------------------------------------
// out[N,128] = A[N,128](f32 -> bf16) @ Wt[n][k] (+bias)(+relu)
// Writes f32 (outp) and/or bf16 (out16) — either may be null.
__global__ __launch_bounds__(256) void gemm_nodes_mfma(
    const float* __restrict__ A, const unsigned short* __restrict__ Wt,
    const void* __restrict__ bias, long boff, float* __restrict__ outp,
    unsigned short* __restrict__ out16, int relu, const int* __restrict__ flag) {
  __shared__ alignas(16) unsigned short sA[64 * 136];
  __shared__ alignas(16) unsigned short sW[128 * 136];
  int tid = threadIdx.x;
  int rbase = blockIdx.x * 64;

#pragma unroll
  for (int p = 0; p < 8; p++) {
    int idx8 = p * 256 + tid;
    int n = idx8 >> 4, kc = idx8 & 15;
    uint4 v = reinterpret_cast<const uint4*>(Wt)[idx8];
    *reinterpret_cast<uint4*>(&sW[n * 136 + kc * 8]) = v;
  }
#pragma unroll
  for (int p = 0; p < 8; p++) {
    int idx = p * 1024 + tid * 4;
    int m = idx >> 7, k = idx & 127;
    int row = rbase + m;
    float4 v = make_float4(0.f, 0.f, 0.f, 0.f);
    if (row < NN) v = *reinterpret_cast<const float4*>(&A[(size_t)row * HID + k]);
    ushort4 b;
    b.x = f2bf_bits(v.x); b.y = f2bf_bits(v.y);
    b.z = f2bf_bits(v.z); b.w = f2bf_bits(v.w);
    *reinterpret_cast<ushort4*>(&sA[m * 136 + k]) = b;
  }
  __syncthreads();

  int wave = tid >> 6, lane = tid & 63;
  int l15 = lane & 15, quad = lane >> 4;
  int mstrip = wave * 16;

  f32x4 acc[8];
#pragma unroll
  for (int t = 0; t < 8; t++) acc[t] = (f32x4){0.f, 0.f, 0.f, 0.f};

#pragma unroll
  for (int ks = 0; ks < 4; ks++) {
    int k0 = ks * 32 + quad * 8;
    bf16x8 a = *reinterpret_cast<const bf16x8*>(&sA[(mstrip + l15) * 136 + k0]);
#pragma unroll
    for (int t = 0; t < 8; t++) {
      bf16x8 b = *reinterpret_cast<const bf16x8*>(&sW[(t * 16 + l15) * 136 + k0]);
      acc[t] = __builtin_amdgcn_mfma_f32_16x16x32_bf16(a, b, acc[t], 0, 0, 0);
    }
  }

  bool bf = *flag != 0;
#pragma unroll
  for (int t = 0; t < 8; t++) {
    int n = t * 16 + l15;
    float bv = (boff >= 0) ? ldf(bias, boff + n, bf) : 0.f;
#pragma unroll
    for (int r = 0; r < 4; r++) {
      int row = rbase + mstrip + quad * 4 + r;
      if (row < NN) {
        float o = acc[t][r] + bv;
        if (relu) o = fmaxf(o, 0.f);
        if (outp) outp[(size_t)row * HID + n] = o;
        if (out16) out16[(size_t)row * HID + n] = f2bf_bits(o);
      }
    }
  }
}

// ---------------- tail GEMM via MFMA ----------------------------------------
__global__ __launch_bounds__(256) void gemm_tail_mfma(
    const float* __restrict__ A, int lda, const unsigned short* __restrict__ Wt,
    int Kp, const void* __restrict__ bias, float* __restrict__ outp, int ldo,
    int relu, const int* __restrict__ flag) {
  __shared__ alignas(16) unsigned short sA[64 * 264];
  __shared__ alignas(16) unsigned short sW[64 * 264];
  int tid = threadIdx.x;
  int rbase = blockIdx.x * 64;
  int nbase = blockIdx.y * 64;
  int wave = tid >> 6, lane = tid & 63;
  int l15 = lane & 15, quad = lane >> 4;
  int mstrip = wave * 16;

  f32x4 acc[4];
#pragma unroll
  for (int t = 0; t < 4; t++) acc[t] = (f32x4){0.f, 0.f, 0.f, 0.f};

  for (int kc = 0; kc < Kp; kc += 256) {
#pragma unroll 4
    for (int p = 0; p < 16; p++) {
      int idx = p * 1024 + tid * 4;
      int m = idx >> 8, k = idx & 255;
      float4 v = *reinterpret_cast<const float4*>(&A[(size_t)(rbase + m) * lda + kc + k]);
      ushort4 b;
      b.x = f2bf_bits(v.x); b.y = f2bf_bits(v.y);
      b.z = f2bf_bits(v.z); b.w = f2bf_bits(v.w);
      *reinterpret_cast<ushort4*>(&sA[m * 264 + k]) = b;
    }
#pragma unroll 4
    for (int p = 0; p < 8; p++) {
      int idx8 = p * 256 + tid;
      int n = idx8 >> 5, kk = (idx8 & 31) * 8;
      uint4 v = *reinterpret_cast<const uint4*>(&Wt[(size_t)(nbase + n) * Kp + kc + kk]);
      *reinterpret_cast<uint4*>(&sW[n * 264 + kk]) = v;
    }
    __syncthreads();
#pragma unroll
    for (int ks = 0; ks < 8; ks++) {
      int k0 = ks * 32 + quad * 8;
      bf16x8 a = *reinterpret_cast<const bf16x8*>(&sA[(mstrip + l15) * 264 + k0]);
#pragma unroll
      for (int nt = 0; nt < 4; nt++) {
        bf16x8 b = *reinterpret_cast<const bf16x8*>(&sW[(nt * 16 + l15) * 264 + k0]);
        acc[nt] = __builtin_amdgcn_mfma_f32_16x16x32_bf16(a, b, acc[nt], 0, 0, 0);
      }
    }
    __syncthreads();
  }

  bool bf = *flag != 0;
#pragma unroll
  for (int nt = 0; nt < 4; nt++) {
    int col = nbase + nt * 16 + l15;
    float bv = ldf(bias, col, bf);
#pragma unroll
    for (int r = 0; r < 4; r++) {
      int row = rbase + mstrip + quad * 4 + r;
      float o = acc[nt][r] + bv;
      if (relu) o = fmaxf(o, 0.f);
      outp[(size_t)row * ldo + col] = o;
    }
  }
}

// ---------------- aggregation (bf16 gather, f32 accumulate) -----------------
// out[n] = dinv[n]*(sum_k val_k*hl16[src_k]) + dinv[n]^2*hl16[n] + bias
__global__ __launch_bounds__(128) void aggregate_kernel(
    const unsigned short* __restrict__ hl16, const int* __restrict__ offs,
    const int* __restrict__ csr_src, const float* __restrict__ csr_val,
    const float* __restrict__ dinv, const void* __restrict__ bias, long boff,
    float* __restrict__ outp, const int* __restrict__ flag) {
  bool bf = *flag != 0;
  int n = blockIdx.x;
  int c = threadIdx.x;
  __shared__ int s_src[128];
  __shared__ float s_val[128];
  int start = offs[n], end = offs[n + 1];
  float acc = 0.f;
  for (int base = start; base < end; base += 128) {
    int k = base + c;
    if (k < end) {
      s_src[c] = min(max(csr_src[k], 0), NN - 1);
      s_val[c] = csr_val[k];
    }
    __syncthreads();
    int m = min(128, end - base);
    for (int j = 0; j < m; j++)
      acc = fmaf(s_val[j], bfl((unsigned)hl16[(size_t)s_src[j] * HID + c]), acc);
    __syncthreads();
  }
  float dn = dinv[n];
  float selfv = bfl((unsigned)hl16[(size_t)n * HID + c]);
  outp[(size_t)n * HID + c] = dn * acc + dn * dn * selfv + ldf(bias, boff + c, bf);
}

// ---------------- mean pool per graph (sorted batch_index) ------------------
__global__ __launch_bounds__(128) void pool_kernel(const float* __restrict__ h,
                                                   const int* __restrict__ batch,
                                                   float* __restrict__ cat) {
  int g = blockIdx.x, c = threadIdx.x;
  int lo = 0, hi = NN;
  while (lo < hi) { int mid = (lo + hi) >> 1; if (batch[mid] < g) lo = mid + 1; else hi = mid; }
  int start = lo;
  hi = NN;
  while (lo < hi) { int mid = (lo + hi) >> 1; if (batch[mid] < g + 1) lo = mid + 1; else hi = mid; }
  int end = lo;
  float s = 0.f;
  for (int n = start; n < end; n++) s += h[(size_t)n * HID + c];
  float cntf = (float)(end - start);
  cat[(size_t)g * PIN + c] = s / fmaxf(cntf, 1.f);
}

// ---------------- final [G,512] @ [512,1] + b -> out ------------------------
__global__ __launch_bounds__(64) void final_kernel(const float* __restrict__ A,
                                                   const void* __restrict__ W,
                                                   const void* __restrict__ b,
                                                   void* __restrict__ outp,
                                                   const int* __restrict__ flag) {
  bool bf = *flag != 0;
  int g = blockIdx.x, lane = threadIdx.x;
  float s = 0.f;
  for (int k = lane; k < PH; k += 64) s = fmaf(A[(size_t)g * PH + k], ldf(W, k, bf), s);
#pragma unroll
  for (int off = 32; off > 0; off >>= 1) s += __shfl_down(s, off);
  if (lane == 0) {
    float r = s + ldf(b, 0, bf);
    if (bf) ((bf16*)outp)[g] = __float2bfloat16(r);
    else    ((float*)outp)[g] = r;
  }
}

// ---------------------------------------------------------------------------
extern "C" void kernel_launch(void* const* d_in, const int* in_sizes, int n_in,
                              void* d_out, int out_size, void* d_ws, size_t ws_size,
                              hipStream_t stream) {
  const void* x      = d_in[0];
  const int*  ei     = (const int*)d_in[1];
  const void* eattr  = d_in[2];
  const int*  batch  = (const int*)d_in[3];
  const void* molf   = d_in[4];
  const void* lin_W  = d_in[5];
  const void* mW1    = d_in[6];
  const void* mb1    = d_in[7];
  const void* mW2    = d_in[8];
  const void* mb2    = d_in[9];
  const void* cbias  = d_in[10];
  const void* gW     = d_in[11];
  const void* gb     = d_in[12];
  const void* mlpW0  = d_in[13];
  const void* mlpb0  = d_in[14];
  const void* mlpW1  = d_in[15];
  const void* mlpb1  = d_in[16];
  const void* mlpW2  = d_in[17];
  const void* mlpb2  = d_in[18];
  const void* mlpW3  = d_in[19];
  const void* mlpb3  = d_in[20];
  const void* predW0 = d_in[21];
  const void* predb0 = d_in[22];
  const void* predW1 = d_in[23];
  const void* predb1 = d_in[24];
  const void* outW   = d_in[25];
  const void* outb   = d_in[26];

  char* base = (char*)d_ws;
  size_t off = 0;
  auto alloc = [&](size_t bytes) -> char* {
    char* p = base + off;
    off = (off + bytes + 255) & ~(size_t)255;
    return p;
  };
  float* bufA     = (float*)alloc((size_t)NN * HID * 4);   // h (layer state, f32)
  float* bufB     = (float*)alloc((size_t)NN * HID * 4);   // t (aggregate out, f32)
  unsigned short* hl16 = (unsigned short*)alloc((size_t)NN * HID * 2);  // lin out, bf16
  float* dinv_all = (float*)alloc((size_t)NL * NN * 4);
  int*   cnt      = (int*)alloc((size_t)NN * 4);
  int*   offs     = (int*)alloc((size_t)(NN + 1) * 4);
  int*   cursor   = (int*)alloc((size_t)NN * 4);
  int*   bsum     = (int*)alloc((size_t)256 * 4);
  int*   csr_src  = (int*)alloc((size_t)EE * 4);
  int*   csr_eid  = (int*)alloc((size_t)EE * 4);
  float* csr_val  = (float*)alloc((size_t)NL * EE * 4);
  unsigned short* Wt    = (unsigned short*)alloc((size_t)8 * HID * HID * 2);
  unsigned short* tailW = (unsigned short*)alloc((size_t)622592 * 2);
  unsigned short* edgeW = (unsigned short*)alloc((size_t)256 * 32 * 2);
  int*   flag     = (int*)alloc(256);
  float* molf32   = (float*)alloc((size_t)GG * 256 * 4);
  float* m0       = (float*)alloc((size_t)GG * MH * 4);
  float* m1       = (float*)alloc((size_t)GG * MH * 4);
  float* cat      = (float*)alloc((size_t)GG * PIN * 4);
  float* p0       = (float*)alloc((size_t)GG * PH * 4);
  float* p1       = (float*)alloc((size_t)GG * PH * 4);

  hipMemsetAsync(cnt, 0, (size_t)NN * 4, stream);
  hipMemsetAsync(cursor, 0, (size_t)NN * 4, stream);
  hipMemsetAsync(molf32, 0, (size_t)GG * 256 * 4, stream);

  // dtype probe first — everything downstream branches on it
  probe_kernel<<<1, 64, 0, stream>>>((const unsigned short*)x, flag);

  // weight prep
  prep_weights<<<512, 256, 0, stream>>>(lin_W, gW, Wt, flag);
  prep_tail<<<(622592 + 255) / 256, 256, 0, stream>>>(mlpW0, mlpW1, mlpW2, mlpW3,
                                                      predW0, predW1, tailW, flag);
  prep_edge_w<<<32, 256, 0, stream>>>(mW1, edgeW, flag);

  // x -> f32
  {
    int n4 = NN * HID / 4;
    cvt_any<<<(n4 + 255) / 256, 256, 0, stream>>>(x, bufA, n4, flag);
  }
  // CSR build (3-phase parallel scan)
  count_kernel<<<(EE + 255) / 256, 256, 0, stream>>>(ei, cnt);
  scan_phase1<<<SCAN_B, 256, 0, stream>>>(cnt, bsum);
  scan_phase2<<<1, 256, 0, stream>>>(bsum, offs);
  scan_phase3<<<SCAN_B, 256, 0, stream>>>(cnt, bsum, offs);
  fill_kernel<<<(EE + 255) / 256, 256, 0, stream>>>(ei, offs, cursor, csr_src, csr_eid);
  // edge gates (MFMA, LDS-free, CSR order), degrees, scaling
  edge_mlp_mfma<<<(EE + 255) / 256, 256, 0, stream>>>(eattr, edgeW, mb1, mW2, mb2,
                                                      csr_eid, csr_val, flag);
  deg_kernel<<<(NN + 255) / 256, 256, 0, stream>>>(offs, csr_val, dinv_all);
  csr_scale_kernel<<<(EE + 255) / 256, 256, 0, stream>>>(csr_src, dinv_all, csr_val);

  // GCN layers: lin(h)->hl16(bf16); aggregate(hl16)->bufB; gcn(bufB)->h
  float* h = bufA;
  float* t = bufB;
  const int gemm_blocks = (NN + 63) / 64;  // 782
  for (int l = 0; l < NL; l++) {
    gemm_nodes_mfma<<<gemm_blocks, 256, 0, stream>>>(
        h, Wt + (size_t)l * HID * HID, nullptr, -1, nullptr, hl16, 0, flag);
    aggregate_kernel<<<NN, 128, 0, stream>>>(hl16, offs, csr_src,
                                             csr_val + (size_t)l * EE,
                                             dinv_all + (size_t)l * NN, cbias,
                                             (long)l * HID, t, flag);
    gemm_nodes_mfma<<<gemm_blocks, 256, 0, stream>>>(
        t, Wt + (size_t)(4 + l) * HID * HID, gb, (long)l * HID, h, nullptr, 1, flag);
  }

  // pooling -> cat[:, 0:128]
  pool_kernel<<<GG, 128, 0, stream>>>(h, batch, cat);

  // molecular MLP -> cat[:, 128:256]  (MFMA tail, K-padded weights)
  cvt_molf<<<(GG * 50 + 255) / 256, 256, 0, stream>>>(molf, molf32, flag);
  gemm_tail_mfma<<<dim3(4, 4), 256, 0, stream>>>(molf32, 256, tailW + 0,      256, mlpb0, m0, 256, 1, flag);
  gemm_tail_mfma<<<dim3(4, 4), 256, 0, stream>>>(m0,     256, tailW + 65536,  256, mlpb1, m1, 256, 1, flag);
  gemm_tail_mfma<<<dim3(4, 4), 256, 0, stream>>>(m1,     256, tailW + 131072, 256, mlpb2, m0, 256, 1, flag);
  gemm_tail_mfma<<<dim3(4, 2), 256, 0, stream>>>(m0,     256, tailW + 196608, 256, mlpb3, cat + MOUT, 256, 1, flag);

  // predictor
  gemm_tail_mfma<<<dim3(4, 8), 256, 0, stream>>>(cat, 256, tailW + 229376, 256, predb0, p0, 512, 1, flag);
  gemm_tail_mfma<<<dim3(4, 8), 256, 0, stream>>>(p0,  512, tailW + 360448, 512, predb1, p1, 512, 1, flag);
  final_kernel<<<GG, 64, 0, stream>>>(p1, outW, outb, d_out, flag);
}

// Round 9
// 802.091 us; speedup vs baseline: 1.1231x; 1.1231x over previous
//
#include <hip/hip_runtime.h>
#include <hip/hip_bf16.h>

// ---------------------------------------------------------------------------
// PDNConv GNN, MI355X round 9.
// Round-8 regression root-caused: edge_mlp_mfma's epilogue used runtime-
// selected pointers into local arrays (float* s = cond ? s0 : s1 ...), which
// forced the accumulators into scratch -> 288 MB of HBM write traffic and
// 183 us. Fix: constant-indexed s[4][4] (t>>2 in an unrolled loop), cndmask
// value-selects instead of dynamic indexing, float4 csr_val store.
// Everything else identical to round 8 (bf16 aggregate gather kept; absmax
// was unchanged at 7.32e-4).
// ---------------------------------------------------------------------------

#define NN 50000
#define EE 600000
#define GG 256
#define HID 128
#define EDIM 16
#define EHID 64
#define NL 4
#define MIN_F 200
#define MH 256
#define MOUT 128
#define PH 512
#define PIN 256
#define SCAN_B 196  // ceil(NN/256)

typedef __hip_bfloat16 bf16;
typedef __attribute__((ext_vector_type(8))) short bf16x8;
typedef __attribute__((ext_vector_type(4))) float f32x4;

__device__ __forceinline__ float bfl(unsigned u) { return __uint_as_float(u << 16); }
__device__ __forceinline__ float bfh(unsigned u) { return __uint_as_float(u & 0xffff0000u); }
__device__ __forceinline__ float b2f(bf16 x) { return __bfloat162float(x); }
__device__ __forceinline__ float ldf(const void* p, long i, bool bf) {
  return bf ? __bfloat162float(((const bf16*)p)[i]) : ((const float*)p)[i];
}
__device__ __forceinline__ unsigned short f2bf_bits(float v) {
  bf16 h = __float2bfloat16(v);
  return *reinterpret_cast<unsigned short*>(&h);
}

// ---------------- dtype probe ------------------------------------------------
__global__ void probe_kernel(const unsigned short* __restrict__ xs, int* flag) {
  if (threadIdx.x == 0 && blockIdx.x == 0) {
    int sane = 0;
    for (int i = 0; i < 128; i++) {
      unsigned e = (xs[i] >> 7) & 0xFF;
      if (e >= 96 && e <= 159) sane++;
    }
    *flag = (sane >= 112) ? 1 : 0;  // 1 = bf16 inputs
  }
}

// ---------------- input -> f32 conversion (4 elems/thread) ------------------
__global__ __launch_bounds__(256) void cvt_any(const void* __restrict__ in,
                                               float* __restrict__ outp, int n4,
                                               const int* __restrict__ flag) {
  bool bf = *flag != 0;
  int i = blockIdx.x * 256 + threadIdx.x;
  if (i >= n4) return;
  float4 v;
  if (bf) {
    uint2 u = reinterpret_cast<const uint2*>(in)[i];
    v.x = bfl(u.x); v.y = bfh(u.x); v.z = bfl(u.y); v.w = bfh(u.y);
  } else {
    v = reinterpret_cast<const float4*>(in)[i];
  }
  reinterpret_cast<float4*>(outp)[i] = v;
}

// ---------------- mol_features [G,200] -> padded f32 [G,256] ----------------
__global__ __launch_bounds__(256) void cvt_molf(const void* __restrict__ in,
                                                float* __restrict__ outp,
                                                const int* __restrict__ flag) {
  bool bf = *flag != 0;
  int i = blockIdx.x * 256 + threadIdx.x;  // GG*50
  if (i >= GG * 50) return;
  int row = i / 50, c4 = (i % 50) * 4;
  float4 v;
  if (bf) {
    const unsigned short* p = (const unsigned short*)in + (size_t)row * MIN_F + c4;
    uint2 u = *reinterpret_cast<const uint2*>(p);
    v.x = bfl(u.x); v.y = bfh(u.x); v.z = bfl(u.y); v.w = bfh(u.y);
  } else {
    v = *reinterpret_cast<const float4*>((const float*)in + (size_t)row * MIN_F + c4);
  }
  *reinterpret_cast<float4*>(&outp[(size_t)row * 256 + c4]) = v;
}

// ---------------- weight prep: node GEMM weights -> bf16 Wt[n][k] -----------
__global__ __launch_bounds__(256) void prep_weights(const void* __restrict__ lin_W,
                                                    const void* __restrict__ gW,
                                                    unsigned short* __restrict__ Wt,
                                                    const int* __restrict__ flag) {
  bool bf = *flag != 0;
  int idx = blockIdx.x * 256 + threadIdx.x;  // 0 .. 8*16384-1
  if (idx >= 8 * 16384) return;
  int mat = idx >> 14;
  int rem = idx & 16383;
  int n = rem >> 7, k = rem & 127;
  const void* src = (mat < 4) ? lin_W : gW;
  long srcIdx = (long)(mat & 3) * 16384 + (long)k * 128 + n;
  Wt[idx] = f2bf_bits(ldf(src, srcIdx, bf));
}

// ---------------- weight prep: edge MLP W1 -> bf16 W1t[256 cols][32 K] ------
__global__ __launch_bounds__(256) void prep_edge_w(const void* __restrict__ mW1,
                                                   unsigned short* __restrict__ W1t,
                                                   const int* __restrict__ flag) {
  bool bf = *flag != 0;
  int idx = blockIdx.x * 256 + threadIdx.x;  // 256*32
  if (idx >= 256 * 32) return;
  int col = idx >> 5, k = idx & 31;
  float v = 0.f;
  if (k < EDIM) v = ldf(mW1, (long)(col >> 6) * (EDIM * EHID) + (long)k * EHID + (col & 63), bf);
  W1t[idx] = f2bf_bits(v);
}

// ---------------- weight prep: tail (MLP+predictor) -> bf16 [N][Kp], K-pad --
__global__ __launch_bounds__(256) void prep_tail(
    const void* __restrict__ mlpW0, const void* __restrict__ mlpW1,
    const void* __restrict__ mlpW2, const void* __restrict__ mlpW3,
    const void* __restrict__ predW0, const void* __restrict__ predW1,
    unsigned short* __restrict__ T, const int* __restrict__ flag) {
  bool bf = *flag != 0;
  int idx = blockIdx.x * 256 + threadIdx.x;
  const void* src; int N, Kp, Ksrc, off;
  if      (idx < 65536)  { src = mlpW0;  N = 256; Kp = 256; Ksrc = 200; off = 0; }
  else if (idx < 131072) { src = mlpW1;  N = 256; Kp = 256; Ksrc = 256; off = 65536; }
  else if (idx < 196608) { src = mlpW2;  N = 256; Kp = 256; Ksrc = 256; off = 131072; }
  else if (idx < 229376) { src = mlpW3;  N = 128; Kp = 256; Ksrc = 256; off = 196608; }
  else if (idx < 360448) { src = predW0; N = 512; Kp = 256; Ksrc = 256; off = 229376; }
  else if (idx < 622592) { src = predW1; N = 512; Kp = 512; Ksrc = 512; off = 360448; }
  else return;
  int rem = idx - off;
  int n = rem / Kp, k = rem % Kp;
  float v = (k < Ksrc) ? ldf(src, (long)k * N + n, bf) : 0.f;
  T[idx] = f2bf_bits(v);
}

// ---------------- CSR build: histogram / 3-phase scan / fill ----------------
__global__ __launch_bounds__(256) void count_kernel(const int* __restrict__ ei,
                                                    int* __restrict__ cnt) {
  int e = blockIdx.x * 256 + threadIdx.x;
  if (e >= EE) return;
  int c = ei[EE + e];
  c = min(max(c, 0), NN - 1);
  atomicAdd(&cnt[c], 1);
}

__global__ __launch_bounds__(256) void scan_phase1(const int* __restrict__ cnt,
                                                   int* __restrict__ bsum) {
  __shared__ int red[256];
  int tid = threadIdx.x;
  int i = blockIdx.x * 256 + tid;
  red[tid] = (i < NN) ? cnt[i] : 0;
  __syncthreads();
  for (int off = 128; off > 0; off >>= 1) {
    if (tid < off) red[tid] += red[tid + off];
    __syncthreads();
  }
  if (tid == 0) bsum[blockIdx.x] = red[0];
}

__global__ __launch_bounds__(256) void scan_phase2(int* __restrict__ bsum,
                                                   int* __restrict__ offs) {
  __shared__ int buf[256];
  int tid = threadIdx.x;
  int v = (tid < SCAN_B) ? bsum[tid] : 0;
  buf[tid] = v;
  __syncthreads();
  for (int off = 1; off < 256; off <<= 1) {
    int t = (tid >= off) ? buf[tid - off] : 0;
    __syncthreads();
    buf[tid] += t;
    __syncthreads();
  }
  if (tid < SCAN_B) bsum[tid] = buf[tid] - v;  // exclusive block offsets
  if (tid == 255) offs[NN] = buf[255];
}

__global__ __launch_bounds__(256) void scan_phase3(const int* __restrict__ cnt,
                                                   const int* __restrict__ bsum,
                                                   int* __restrict__ offs) {
  __shared__ int buf[256];
  int tid = threadIdx.x;
  int i = blockIdx.x * 256 + tid;
  int v = (i < NN) ? cnt[i] : 0;
  buf[tid] = v;
  __syncthreads();
  for (int off = 1; off < 256; off <<= 1) {
    int t = (tid >= off) ? buf[tid - off] : 0;
    __syncthreads();
    buf[tid] += t;
    __syncthreads();
  }
  if (i < NN) offs[i] = bsum[blockIdx.x] + buf[tid] - v;
}

__global__ __launch_bounds__(256) void fill_kernel(const int* __restrict__ ei,
                                                   const int* __restrict__ offs,
                                                   int* __restrict__ cursor,
                                                   int* __restrict__ csr_src,
                                                   int* __restrict__ csr_eid) {
  int e = blockIdx.x * 256 + threadIdx.x;
  if (e >= EE) return;
  int c = ei[EE + e];
  c = min(max(c, 0), NN - 1);
  int pos = offs[c] + atomicAdd(&cursor[c], 1);
  pos = min(max(pos, 0), EE - 1);
  csr_src[pos] = ei[e];
  csr_eid[pos] = e;
}

// ---------------- edge-gate MLP via MFMA, LDS-free, scratch-free ------------
// B-fragments (block-invariant 16 KB W1t) in registers from global (L1-hot).
// Accumulator s[4][4] only ever indexed with compile-time constants.
__global__ __launch_bounds__(256) void edge_mlp_mfma(
    const void* __restrict__ eattr, const unsigned short* __restrict__ W1t,
    const void* __restrict__ mb1, const void* __restrict__ mW2,
    const void* __restrict__ mb2, const int* __restrict__ csr_eid,
    float* __restrict__ csr_val, const int* __restrict__ flag) {
  bool bf = *flag != 0;
  int tid = threadIdx.x;
  int wave = tid >> 6, lane = tid & 63;
  int l15 = lane & 15, quad = lane >> 4;

  // B frags: lane (l15,quad) holds W1t[t*16+l15][quad*8 .. +8)
  bf16x8 bfrag[16];
#pragma unroll
  for (int t = 0; t < 16; t++)
    bfrag[t] = *reinterpret_cast<const bf16x8*>(&W1t[(t * 16 + l15) * 32 + quad * 8]);

  float b1v[16], w2v[16];
#pragma unroll
  for (int t = 0; t < 16; t++) {
    int col = t * 16 + l15;
    b1v[t] = ldf(mb1, col, bf);
    w2v[t] = ldf(mW2, col, bf);
  }
  float b2v0 = ldf(mb2, 0, bf), b2v1 = ldf(mb2, 1, bf);
  float b2v2 = ldf(mb2, 2, bf), b2v3 = ldf(mb2, 3, bf);
  float b2 = b2v0;
  b2 = (l15 == 1) ? b2v1 : b2;
  b2 = (l15 == 2) ? b2v2 : b2;
  b2 = (l15 == 3) ? b2v3 : b2;

  int ebase = blockIdx.x * 256 + wave * 64;
#pragma unroll
  for (int f = 0; f < 4; f++) {
    int fbase = ebase + f * 16;
    if (fbase < EE) {  // EE%16==0 -> whole fragment in-bounds
      long eid = csr_eid[fbase + l15];
      bf16x8 a = (bf16x8){0, 0, 0, 0, 0, 0, 0, 0};
      if (quad < 2) {
        if (bf) {
          uint4 v = *reinterpret_cast<const uint4*>((const bf16*)eattr + eid * EDIM + quad * 8);
          a = *reinterpret_cast<bf16x8*>(&v);
        } else {
          const float4* p =
              reinterpret_cast<const float4*>((const float*)eattr + eid * EDIM + quad * 8);
          float4 v0 = p[0], v1 = p[1];
          a[0] = (short)f2bf_bits(v0.x); a[1] = (short)f2bf_bits(v0.y);
          a[2] = (short)f2bf_bits(v0.z); a[3] = (short)f2bf_bits(v0.w);
          a[4] = (short)f2bf_bits(v1.x); a[5] = (short)f2bf_bits(v1.y);
          a[6] = (short)f2bf_bits(v1.z); a[7] = (short)f2bf_bits(v1.w);
        }
      }
      float s[4][4];
#pragma unroll
      for (int g = 0; g < 4; g++)
#pragma unroll
        for (int r = 0; r < 4; r++) s[g][r] = 0.f;
#pragma unroll
      for (int t = 0; t < 16; t++) {   // t constant per iteration -> s[t>>2] constant
        f32x4 acc = __builtin_amdgcn_mfma_f32_16x16x32_bf16(
            a, bfrag[t], (f32x4){0.f, 0.f, 0.f, 0.f}, 0, 0, 0);
#pragma unroll
        for (int r = 0; r < 4; r++)
          s[t / 4][r] += fmaxf(acc[r] + b1v[t], 0.f) * w2v[t];
      }
#pragma unroll
      for (int m = 1; m <= 8; m <<= 1)
#pragma unroll
        for (int g = 0; g < 4; g++)
#pragma unroll
          for (int r = 0; r < 4; r++) s[g][r] += __shfl_xor(s[g][r], m);

      if (l15 < NL) {
        float4 o;
        float* op = &o.x;
#pragma unroll
        for (int r = 0; r < 4; r++) {
          float sv = s[0][r];                    // cndmask chain, constant indices
          sv = (l15 == 1) ? s[1][r] : sv;
          sv = (l15 == 2) ? s[2][r] : sv;
          sv = (l15 == 3) ? s[3][r] : sv;
          op[r] = 1.f / (1.f + __expf(-(sv + b2)));
        }
        *reinterpret_cast<float4*>(&csr_val[(size_t)l15 * EE + fbase + quad * 4]) = o;
      }
    }
  }
}

// ---------------- degree / dinv per layer -----------------------------------
__global__ __launch_bounds__(256) void deg_kernel(const int* __restrict__ offs,
                                                  const float* __restrict__ csr_val,
                                                  float* __restrict__ dinv_all) {
  int n = blockIdx.x * 256 + threadIdx.x;
  if (n >= NN) return;
  int s = offs[n], e = offs[n + 1];
  float d0 = 1.f, d1 = 1.f, d2 = 1.f, d3 = 1.f;  // self-loop weight 1.0
  for (int k = s; k < e; k++) {
    d0 += csr_val[k];
    d1 += csr_val[EE + k];
    d2 += csr_val[2 * (size_t)EE + k];
    d3 += csr_val[3 * (size_t)EE + k];
  }
  dinv_all[n] = rsqrtf(d0);
  dinv_all[NN + n] = rsqrtf(d1);
  dinv_all[2 * NN + n] = rsqrtf(d2);
  dinv_all[3 * NN + n] = rsqrtf(d3);
}

// csr_val[l][k] *= dinv_l[src_k]
__global__ __launch_bounds__(256) void csr_scale_kernel(const int* __restrict__ csr_src,
                                                        const float* __restrict__ dinv_all,
                                                        float* __restrict__ csr_val) {
  int k = blockIdx.x * 256 + threadIdx.x;
  if (k >= EE) return;
  int s = csr_src[k];
  s = min(max(s, 0), NN - 1);
#pragma unroll
  for (int l = 0; l < NL; l++)
    csr_val[(size_t)l * EE + k] *= dinv_all[(size_t)l * NN + s];
}

// ---------------- node GEMM via MFMA ----------------------------------------
// out[N,128] = A[N,128](f32 -> bf16) @ Wt[n][k] (+bias)(+relu)
__global__ __launch_bounds__(256) void gemm_nodes_mfma(
    const float* __restrict__ A, const unsigned short* __restrict__ Wt,
    const void* __restrict__ bias, long boff, float* __restrict__ outp,
    unsigned short* __restrict__ out16, int relu, const int* __restrict__ flag) {
  __shared__ alignas(16) unsigned short sA[64 * 136];
  __shared__ alignas(16) unsigned short sW[128 * 136];
  int tid = threadIdx.x;
  int rbase = blockIdx.x * 64;

#pragma unroll
  for (int p = 0; p < 8; p++) {
    int idx8 = p * 256 + tid;
    int n = idx8 >> 4, kc = idx8 & 15;
    uint4 v = reinterpret_cast<const uint4*>(Wt)[idx8];
    *reinterpret_cast<uint4*>(&sW[n * 136 + kc * 8]) = v;
  }
#pragma unroll
  for (int p = 0; p < 8; p++) {
    int idx = p * 1024 + tid * 4;
    int m = idx >> 7, k = idx & 127;
    int row = rbase + m;
    float4 v = make_float4(0.f, 0.f, 0.f, 0.f);
    if (row < NN) v = *reinterpret_cast<const float4*>(&A[(size_t)row * HID + k]);
    ushort4 b;
    b.x = f2bf_bits(v.x); b.y = f2bf_bits(v.y);
    b.z = f2bf_bits(v.z); b.w = f2bf_bits(v.w);
    *reinterpret_cast<ushort4*>(&sA[m * 136 + k]) = b;
  }
  __syncthreads();

  int wave = tid >> 6, lane = tid & 63;
  int l15 = lane & 15, quad = lane >> 4;
  int mstrip = wave * 16;

  f32x4 acc[8];
#pragma unroll
  for (int t = 0; t < 8; t++) acc[t] = (f32x4){0.f, 0.f, 0.f, 0.f};

#pragma unroll
  for (int ks = 0; ks < 4; ks++) {
    int k0 = ks * 32 + quad * 8;
    bf16x8 a = *reinterpret_cast<const bf16x8*>(&sA[(mstrip + l15) * 136 + k0]);
#pragma unroll
    for (int t = 0; t < 8; t++) {
      bf16x8 b = *reinterpret_cast<const bf16x8*>(&sW[(t * 16 + l15) * 136 + k0]);
      acc[t] = __builtin_amdgcn_mfma_f32_16x16x32_bf16(a, b, acc[t], 0, 0, 0);
    }
  }

  bool bf = *flag != 0;
#pragma unroll
  for (int t = 0; t < 8; t++) {
    int n = t * 16 + l15;
    float bv = (boff >= 0) ? ldf(bias, boff + n, bf) : 0.f;
#pragma unroll
    for (int r = 0; r < 4; r++) {
      int row = rbase + mstrip + quad * 4 + r;
      if (row < NN) {
        float o = acc[t][r] + bv;
        if (relu) o = fmaxf(o, 0.f);
        if (outp) outp[(size_t)row * HID + n] = o;
        if (out16) out16[(size_t)row * HID + n] = f2bf_bits(o);
      }
    }
  }
}

// ---------------- tail GEMM via MFMA ----------------------------------------
__global__ __launch_bounds__(256) void gemm_tail_mfma(
    const float* __restrict__ A, int lda, const unsigned short* __restrict__ Wt,
    int Kp, const void* __restrict__ bias, float* __restrict__ outp, int ldo,
    int relu, const int* __restrict__ flag) {
  __shared__ alignas(16) unsigned short sA[64 * 264];
  __shared__ alignas(16) unsigned short sW[64 * 264];
  int tid = threadIdx.x;
  int rbase = blockIdx.x * 64;
  int nbase = blockIdx.y * 64;
  int wave = tid >> 6, lane = tid & 63;
  int l15 = lane & 15, quad = lane >> 4;
  int mstrip = wave * 16;

  f32x4 acc[4];
#pragma unroll
  for (int t = 0; t < 4; t++) acc[t] = (f32x4){0.f, 0.f, 0.f, 0.f};

  for (int kc = 0; kc < Kp; kc += 256) {
#pragma unroll 4
    for (int p = 0; p < 16; p++) {
      int idx = p * 1024 + tid * 4;
      int m = idx >> 8, k = idx & 255;
      float4 v = *reinterpret_cast<const float4*>(&A[(size_t)(rbase + m) * lda + kc + k]);
      ushort4 b;
      b.x = f2bf_bits(v.x); b.y = f2bf_bits(v.y);
      b.z = f2bf_bits(v.z); b.w = f2bf_bits(v.w);
      *reinterpret_cast<ushort4*>(&sA[m * 264 + k]) = b;
    }
#pragma unroll 4
    for (int p = 0; p < 8; p++) {
      int idx8 = p * 256 + tid;
      int n = idx8 >> 5, kk = (idx8 & 31) * 8;
      uint4 v = *reinterpret_cast<const uint4*>(&Wt[(size_t)(nbase + n) * Kp + kc + kk]);
      *reinterpret_cast<uint4*>(&sW[n * 264 + kk]) = v;
    }
    __syncthreads();
#pragma unroll
    for (int ks = 0; ks < 8; ks++) {
      int k0 = ks * 32 + quad * 8;
      bf16x8 a = *reinterpret_cast<const bf16x8*>(&sA[(mstrip + l15) * 264 + k0]);
#pragma unroll
      for (int nt = 0; nt < 4; nt++) {
        bf16x8 b = *reinterpret_cast<const bf16x8*>(&sW[(nt * 16 + l15) * 264 + k0]);
        acc[nt] = __builtin_amdgcn_mfma_f32_16x16x32_bf16(a, b, acc[nt], 0, 0, 0);
      }
    }
    __syncthreads();
  }

  bool bf = *flag != 0;
#pragma unroll
  for (int nt = 0; nt < 4; nt++) {
    int col = nbase + nt * 16 + l15;
    float bv = ldf(bias, col, bf);
#pragma unroll
    for (int r = 0; r < 4; r++) {
      int row = rbase + mstrip + quad * 4 + r;
      float o = acc[nt][r] + bv;
      if (relu) o = fmaxf(o, 0.f);
      outp[(size_t)row * ldo + col] = o;
    }
  }
}

// ---------------- aggregation (bf16 gather, f32 accumulate) -----------------
__global__ __launch_bounds__(128) void aggregate_kernel(
    const unsigned short* __restrict__ hl16, const int* __restrict__ offs,
    const int* __restrict__ csr_src, const float* __restrict__ csr_val,
    const float* __restrict__ dinv, const void* __restrict__ bias, long boff,
    float* __restrict__ outp, const int* __restrict__ flag) {
  bool bf = *flag != 0;
  int n = blockIdx.x;
  int c = threadIdx.x;
  __shared__ int s_src[128];
  __shared__ float s_val[128];
  int start = offs[n], end = offs[n + 1];
  float acc = 0.f;
  for (int base = start; base < end; base += 128) {
    int k = base + c;
    if (k < end) {
      s_src[c] = min(max(csr_src[k], 0), NN - 1);
      s_val[c] = csr_val[k];
    }
    __syncthreads();
    int m = min(128, end - base);
    for (int j = 0; j < m; j++)
      acc = fmaf(s_val[j], bfl((unsigned)hl16[(size_t)s_src[j] * HID + c]), acc);
    __syncthreads();
  }
  float dn = dinv[n];
  float selfv = bfl((unsigned)hl16[(size_t)n * HID + c]);
  outp[(size_t)n * HID + c] = dn * acc + dn * dn * selfv + ldf(bias, boff + c, bf);
}

// ---------------- mean pool per graph (sorted batch_index) ------------------
__global__ __launch_bounds__(128) void pool_kernel(const float* __restrict__ h,
                                                   const int* __restrict__ batch,
                                                   float* __restrict__ cat) {
  int g = blockIdx.x, c = threadIdx.x;
  int lo = 0, hi = NN;
  while (lo < hi) { int mid = (lo + hi) >> 1; if (batch[mid] < g) lo = mid + 1; else hi = mid; }
  int start = lo;
  hi = NN;
  while (lo < hi) { int mid = (lo + hi) >> 1; if (batch[mid] < g + 1) lo = mid + 1; else hi = mid; }
  int end = lo;
  float s = 0.f;
  for (int n = start; n < end; n++) s += h[(size_t)n * HID + c];
  float cntf = (float)(end - start);
  cat[(size_t)g * PIN + c] = s / fmaxf(cntf, 1.f);
}

// ---------------- final [G,512] @ [512,1] + b -> out ------------------------
__global__ __launch_bounds__(64) void final_kernel(const float* __restrict__ A,
                                                   const void* __restrict__ W,
                                                   const void* __restrict__ b,
                                                   void* __restrict__ outp,
                                                   const int* __restrict__ flag) {
  bool bf = *flag != 0;
  int g = blockIdx.x, lane = threadIdx.x;
  float s = 0.f;
  for (int k = lane; k < PH; k += 64) s = fmaf(A[(size_t)g * PH + k], ldf(W, k, bf), s);
#pragma unroll
  for (int off = 32; off > 0; off >>= 1) s += __shfl_down(s, off);
  if (lane == 0) {
    float r = s + ldf(b, 0, bf);
    if (bf) ((bf16*)outp)[g] = __float2bfloat16(r);
    else    ((float*)outp)[g] = r;
  }
}

// ---------------------------------------------------------------------------
extern "C" void kernel_launch(void* const* d_in, const int* in_sizes, int n_in,
                              void* d_out, int out_size, void* d_ws, size_t ws_size,
                              hipStream_t stream) {
  const void* x      = d_in[0];
  const int*  ei     = (const int*)d_in[1];
  const void* eattr  = d_in[2];
  const int*  batch  = (const int*)d_in[3];
  const void* molf   = d_in[4];
  const void* lin_W  = d_in[5];
  const void* mW1    = d_in[6];
  const void* mb1    = d_in[7];
  const void* mW2    = d_in[8];
  const void* mb2    = d_in[9];
  const void* cbias  = d_in[10];
  const void* gW     = d_in[11];
  const void* gb     = d_in[12];
  const void* mlpW0  = d_in[13];
  const void* mlpb0  = d_in[14];
  const void* mlpW1  = d_in[15];
  const void* mlpb1  = d_in[16];
  const void* mlpW2  = d_in[17];
  const void* mlpb2  = d_in[18];
  const void* mlpW3  = d_in[19];
  const void* mlpb3  = d_in[20];
  const void* predW0 = d_in[21];
  const void* predb0 = d_in[22];
  const void* predW1 = d_in[23];
  const void* predb1 = d_in[24];
  const void* outW   = d_in[25];
  const void* outb   = d_in[26];

  char* base = (char*)d_ws;
  size_t off = 0;
  auto alloc = [&](size_t bytes) -> char* {
    char* p = base + off;
    off = (off + bytes + 255) & ~(size_t)255;
    return p;
  };
  float* bufA     = (float*)alloc((size_t)NN * HID * 4);   // h (layer state, f32)
  float* bufB     = (float*)alloc((size_t)NN * HID * 4);   // t (aggregate out, f32)
  unsigned short* hl16 = (unsigned short*)alloc((size_t)NN * HID * 2);  // lin out, bf16
  float* dinv_all = (float*)alloc((size_t)NL * NN * 4);
  int*   cnt      = (int*)alloc((size_t)NN * 4);
  int*   offs     = (int*)alloc((size_t)(NN + 1) * 4);
  int*   cursor   = (int*)alloc((size_t)NN * 4);
  int*   bsum     = (int*)alloc((size_t)256 * 4);
  int*   csr_src  = (int*)alloc((size_t)EE * 4);
  int*   csr_eid  = (int*)alloc((size_t)EE * 4);
  float* csr_val  = (float*)alloc((size_t)NL * EE * 4);
  unsigned short* Wt    = (unsigned short*)alloc((size_t)8 * HID * HID * 2);
  unsigned short* tailW = (unsigned short*)alloc((size_t)622592 * 2);
  unsigned short* edgeW = (unsigned short*)alloc((size_t)256 * 32 * 2);
  int*   flag     = (int*)alloc(256);
  float* molf32   = (float*)alloc((size_t)GG * 256 * 4);
  float* m0       = (float*)alloc((size_t)GG * MH * 4);
  float* m1       = (float*)alloc((size_t)GG * MH * 4);
  float* cat      = (float*)alloc((size_t)GG * PIN * 4);
  float* p0       = (float*)alloc((size_t)GG * PH * 4);
  float* p1       = (float*)alloc((size_t)GG * PH * 4);

  hipMemsetAsync(cnt, 0, (size_t)NN * 4, stream);
  hipMemsetAsync(cursor, 0, (size_t)NN * 4, stream);
  hipMemsetAsync(molf32, 0, (size_t)GG * 256 * 4, stream);

  // dtype probe first — everything downstream branches on it
  probe_kernel<<<1, 64, 0, stream>>>((const unsigned short*)x, flag);

  // weight prep
  prep_weights<<<512, 256, 0, stream>>>(lin_W, gW, Wt, flag);
  prep_tail<<<(622592 + 255) / 256, 256, 0, stream>>>(mlpW0, mlpW1, mlpW2, mlpW3,
                                                      predW0, predW1, tailW, flag);
  prep_edge_w<<<32, 256, 0, stream>>>(mW1, edgeW, flag);

  // x -> f32
  {
    int n4 = NN * HID / 4;
    cvt_any<<<(n4 + 255) / 256, 256, 0, stream>>>(x, bufA, n4, flag);
  }
  // CSR build (3-phase parallel scan)
  count_kernel<<<(EE + 255) / 256, 256, 0, stream>>>(ei, cnt);
  scan_phase1<<<SCAN_B, 256, 0, stream>>>(cnt, bsum);
  scan_phase2<<<1, 256, 0, stream>>>(bsum, offs);
  scan_phase3<<<SCAN_B, 256, 0, stream>>>(cnt, bsum, offs);
  fill_kernel<<<(EE + 255) / 256, 256, 0, stream>>>(ei, offs, cursor, csr_src, csr_eid);
  // edge gates (MFMA, LDS-free, CSR order), degrees, scaling
  edge_mlp_mfma<<<(EE + 255) / 256, 256, 0, stream>>>(eattr, edgeW, mb1, mW2, mb2,
                                                      csr_eid, csr_val, flag);
  deg_kernel<<<(NN + 255) / 256, 256, 0, stream>>>(offs, csr_val, dinv_all);
  csr_scale_kernel<<<(EE + 255) / 256, 256, 0, stream>>>(csr_src, dinv_all, csr_val);

  // GCN layers: lin(h)->hl16(bf16); aggregate(hl16)->bufB; gcn(bufB)->h
  float* h = bufA;
  float* t = bufB;
  const int gemm_blocks = (NN + 63) / 64;  // 782
  for (int l = 0; l < NL; l++) {
    gemm_nodes_mfma<<<gemm_blocks, 256, 0, stream>>>(
        h, Wt + (size_t)l * HID * HID, nullptr, -1, nullptr, hl16, 0, flag);
    aggregate_kernel<<<NN, 128, 0, stream>>>(hl16, offs, csr_src,
                                             csr_val + (size_t)l * EE,
                                             dinv_all + (size_t)l * NN, cbias,
                                             (long)l * HID, t, flag);
    gemm_nodes_mfma<<<gemm_blocks, 256, 0, stream>>>(
        t, Wt + (size_t)(4 + l) * HID * HID, gb, (long)l * HID, h, nullptr, 1, flag);
  }

  // pooling -> cat[:, 0:128]
  pool_kernel<<<GG, 128, 0, stream>>>(h, batch, cat);

  // molecular MLP -> cat[:, 128:256]  (MFMA tail, K-padded weights)
  cvt_molf<<<(GG * 50 + 255) / 256, 256, 0, stream>>>(molf, molf32, flag);
  gemm_tail_mfma<<<dim3(4, 4), 256, 0, stream>>>(molf32, 256, tailW + 0,      256, mlpb0, m0, 256, 1, flag);
  gemm_tail_mfma<<<dim3(4, 4), 256, 0, stream>>>(m0,     256, tailW + 65536,  256, mlpb1, m1, 256, 1, flag);
  gemm_tail_mfma<<<dim3(4, 4), 256, 0, stream>>>(m1,     256, tailW + 131072, 256, mlpb2, m0, 256, 1, flag);
  gemm_tail_mfma<<<dim3(4, 2), 256, 0, stream>>>(m0,     256, tailW + 196608, 256, mlpb3, cat + MOUT, 256, 1, flag);

  // predictor
  gemm_tail_mfma<<<dim3(4, 8), 256, 0, stream>>>(cat, 256, tailW + 229376, 256, predb0, p0, 512, 1, flag);
  gemm_tail_mfma<<<dim3(4, 8), 256, 0, stream>>>(p0,  512, tailW + 360448, 512, predb1, p1, 512, 1, flag);
  final_kernel<<<GG, 64, 0, stream>>>(p1, outW, outb, d_out, flag);
}

// Round 10
// 763.362 us; speedup vs baseline: 1.1801x; 1.0507x over previous
//
#include <hip/hip_runtime.h>
#include <hip/hip_bf16.h>

// ---------------------------------------------------------------------------
// PDNConv GNN, MI355X round 10.
// Round-9: edge_mlp's `float s[4][4]` was promoted BY THE COMPILER to LDS
// (LDS_Block_Size=16384 with no __shared__ declared; 3.6M bank conflicts).
// Fix: 16 named scalar accumulators, macro-expanded explicit component code —
// no local arrays in the hot path, guaranteed VGPRs.
// Everything else identical to round 9.
// ---------------------------------------------------------------------------

#define NN 50000
#define EE 600000
#define GG 256
#define HID 128
#define EDIM 16
#define EHID 64
#define NL 4
#define MIN_F 200
#define MH 256
#define MOUT 128
#define PH 512
#define PIN 256
#define SCAN_B 196  // ceil(NN/256)

typedef __hip_bfloat16 bf16;
typedef __attribute__((ext_vector_type(8))) short bf16x8;
typedef __attribute__((ext_vector_type(4))) float f32x4;

__device__ __forceinline__ float bfl(unsigned u) { return __uint_as_float(u << 16); }
__device__ __forceinline__ float bfh(unsigned u) { return __uint_as_float(u & 0xffff0000u); }
__device__ __forceinline__ float b2f(bf16 x) { return __bfloat162float(x); }
__device__ __forceinline__ float ldf(const void* p, long i, bool bf) {
  return bf ? __bfloat162float(((const bf16*)p)[i]) : ((const float*)p)[i];
}
__device__ __forceinline__ unsigned short f2bf_bits(float v) {
  bf16 h = __float2bfloat16(v);
  return *reinterpret_cast<unsigned short*>(&h);
}

// ---------------- dtype probe ------------------------------------------------
__global__ void probe_kernel(const unsigned short* __restrict__ xs, int* flag) {
  if (threadIdx.x == 0 && blockIdx.x == 0) {
    int sane = 0;
    for (int i = 0; i < 128; i++) {
      unsigned e = (xs[i] >> 7) & 0xFF;
      if (e >= 96 && e <= 159) sane++;
    }
    *flag = (sane >= 112) ? 1 : 0;  // 1 = bf16 inputs
  }
}

// ---------------- input -> f32 conversion (4 elems/thread) ------------------
__global__ __launch_bounds__(256) void cvt_any(const void* __restrict__ in,
                                               float* __restrict__ outp, int n4,
                                               const int* __restrict__ flag) {
  bool bf = *flag != 0;
  int i = blockIdx.x * 256 + threadIdx.x;
  if (i >= n4) return;
  float4 v;
  if (bf) {
    uint2 u = reinterpret_cast<const uint2*>(in)[i];
    v.x = bfl(u.x); v.y = bfh(u.x); v.z = bfl(u.y); v.w = bfh(u.y);
  } else {
    v = reinterpret_cast<const float4*>(in)[i];
  }
  reinterpret_cast<float4*>(outp)[i] = v;
}

// ---------------- mol_features [G,200] -> padded f32 [G,256] ----------------
__global__ __launch_bounds__(256) void cvt_molf(const void* __restrict__ in,
                                                float* __restrict__ outp,
                                                const int* __restrict__ flag) {
  bool bf = *flag != 0;
  int i = blockIdx.x * 256 + threadIdx.x;  // GG*50
  if (i >= GG * 50) return;
  int row = i / 50, c4 = (i % 50) * 4;
  float4 v;
  if (bf) {
    const unsigned short* p = (const unsigned short*)in + (size_t)row * MIN_F + c4;
    uint2 u = *reinterpret_cast<const uint2*>(p);
    v.x = bfl(u.x); v.y = bfh(u.x); v.z = bfl(u.y); v.w = bfh(u.y);
  } else {
    v = *reinterpret_cast<const float4*>((const float*)in + (size_t)row * MIN_F + c4);
  }
  *reinterpret_cast<float4*>(&outp[(size_t)row * 256 + c4]) = v;
}

// ---------------- weight prep: node GEMM weights -> bf16 Wt[n][k] -----------
__global__ __launch_bounds__(256) void prep_weights(const void* __restrict__ lin_W,
                                                    const void* __restrict__ gW,
                                                    unsigned short* __restrict__ Wt,
                                                    const int* __restrict__ flag) {
  bool bf = *flag != 0;
  int idx = blockIdx.x * 256 + threadIdx.x;  // 0 .. 8*16384-1
  if (idx >= 8 * 16384) return;
  int mat = idx >> 14;
  int rem = idx & 16383;
  int n = rem >> 7, k = rem & 127;
  const void* src = (mat < 4) ? lin_W : gW;
  long srcIdx = (long)(mat & 3) * 16384 + (long)k * 128 + n;
  Wt[idx] = f2bf_bits(ldf(src, srcIdx, bf));
}

// ---------------- weight prep: edge MLP W1 -> bf16 W1t[256 cols][32 K] ------
__global__ __launch_bounds__(256) void prep_edge_w(const void* __restrict__ mW1,
                                                   unsigned short* __restrict__ W1t,
                                                   const int* __restrict__ flag) {
  bool bf = *flag != 0;
  int idx = blockIdx.x * 256 + threadIdx.x;  // 256*32
  if (idx >= 256 * 32) return;
  int col = idx >> 5, k = idx & 31;
  float v = 0.f;
  if (k < EDIM) v = ldf(mW1, (long)(col >> 6) * (EDIM * EHID) + (long)k * EHID + (col & 63), bf);
  W1t[idx] = f2bf_bits(v);
}

// ---------------- weight prep: tail (MLP+predictor) -> bf16 [N][Kp], K-pad --
__global__ __launch_bounds__(256) void prep_tail(
    const void* __restrict__ mlpW0, const void* __restrict__ mlpW1,
    const void* __restrict__ mlpW2, const void* __restrict__ mlpW3,
    const void* __restrict__ predW0, const void* __restrict__ predW1,
    unsigned short* __restrict__ T, const int* __restrict__ flag) {
  bool bf = *flag != 0;
  int idx = blockIdx.x * 256 + threadIdx.x;
  const void* src; int N, Kp, Ksrc, off;
  if      (idx < 65536)  { src = mlpW0;  N = 256; Kp = 256; Ksrc = 200; off = 0; }
  else if (idx < 131072) { src = mlpW1;  N = 256; Kp = 256; Ksrc = 256; off = 65536; }
  else if (idx < 196608) { src = mlpW2;  N = 256; Kp = 256; Ksrc = 256; off = 131072; }
  else if (idx < 229376) { src = mlpW3;  N = 128; Kp = 256; Ksrc = 256; off = 196608; }
  else if (idx < 360448) { src = predW0; N = 512; Kp = 256; Ksrc = 256; off = 229376; }
  else if (idx < 622592) { src = predW1; N = 512; Kp = 512; Ksrc = 512; off = 360448; }
  else return;
  int rem = idx - off;
  int n = rem / Kp, k = rem % Kp;
  float v = (k < Ksrc) ? ldf(src, (long)k * N + n, bf) : 0.f;
  T[idx] = f2bf_bits(v);
}

// ---------------- CSR build: histogram / 3-phase scan / fill ----------------
__global__ __launch_bounds__(256) void count_kernel(const int* __restrict__ ei,
                                                    int* __restrict__ cnt) {
  int e = blockIdx.x * 256 + threadIdx.x;
  if (e >= EE) return;
  int c = ei[EE + e];
  c = min(max(c, 0), NN - 1);
  atomicAdd(&cnt[c], 1);
}

__global__ __launch_bounds__(256) void scan_phase1(const int* __restrict__ cnt,
                                                   int* __restrict__ bsum) {
  __shared__ int red[256];
  int tid = threadIdx.x;
  int i = blockIdx.x * 256 + tid;
  red[tid] = (i < NN) ? cnt[i] : 0;
  __syncthreads();
  for (int off = 128; off > 0; off >>= 1) {
    if (tid < off) red[tid] += red[tid + off];
    __syncthreads();
  }
  if (tid == 0) bsum[blockIdx.x] = red[0];
}

__global__ __launch_bounds__(256) void scan_phase2(int* __restrict__ bsum,
                                                   int* __restrict__ offs) {
  __shared__ int buf[256];
  int tid = threadIdx.x;
  int v = (tid < SCAN_B) ? bsum[tid] : 0;
  buf[tid] = v;
  __syncthreads();
  for (int off = 1; off < 256; off <<= 1) {
    int t = (tid >= off) ? buf[tid - off] : 0;
    __syncthreads();
    buf[tid] += t;
    __syncthreads();
  }
  if (tid < SCAN_B) bsum[tid] = buf[tid] - v;  // exclusive block offsets
  if (tid == 255) offs[NN] = buf[255];
}

__global__ __launch_bounds__(256) void scan_phase3(const int* __restrict__ cnt,
                                                   const int* __restrict__ bsum,
                                                   int* __restrict__ offs) {
  __shared__ int buf[256];
  int tid = threadIdx.x;
  int i = blockIdx.x * 256 + tid;
  int v = (i < NN) ? cnt[i] : 0;
  buf[tid] = v;
  __syncthreads();
  for (int off = 1; off < 256; off <<= 1) {
    int t = (tid >= off) ? buf[tid - off] : 0;
    __syncthreads();
    buf[tid] += t;
    __syncthreads();
  }
  if (i < NN) offs[i] = bsum[blockIdx.x] + buf[tid] - v;
}

__global__ __launch_bounds__(256) void fill_kernel(const int* __restrict__ ei,
                                                   const int* __restrict__ offs,
                                                   int* __restrict__ cursor,
                                                   int* __restrict__ csr_src,
                                                   int* __restrict__ csr_eid) {
  int e = blockIdx.x * 256 + threadIdx.x;
  if (e >= EE) return;
  int c = ei[EE + e];
  c = min(max(c, 0), NN - 1);
  int pos = offs[c] + atomicAdd(&cursor[c], 1);
  pos = min(max(pos, 0), EE - 1);
  csr_src[pos] = ei[e];
  csr_eid[pos] = e;
}

// ---------------- edge-gate MLP via MFMA: LDS-free, array-free hot path -----
// 16 NAMED scalar accumulators (sGR: layer-group G, acc-row R) — compiler
// cannot promote them to LDS/scratch. B-frags in registers from global.
__global__ __launch_bounds__(256) void edge_mlp_mfma(
    const void* __restrict__ eattr, const unsigned short* __restrict__ W1t,
    const void* __restrict__ mb1, const void* __restrict__ mW2,
    const void* __restrict__ mb2, const int* __restrict__ csr_eid,
    float* __restrict__ csr_val, const int* __restrict__ flag) {
  bool bf = *flag != 0;
  int tid = threadIdx.x;
  int wave = tid >> 6, lane = tid & 63;
  int l15 = lane & 15, quad = lane >> 4;

  // B frags: lane (l15,quad) holds W1t[t*16+l15][quad*8 .. +8)
  bf16x8 bfrag[16];
#pragma unroll
  for (int t = 0; t < 16; t++)
    bfrag[t] = *reinterpret_cast<const bf16x8*>(&W1t[(t * 16 + l15) * 32 + quad * 8]);

  float b1v[16], w2v[16];
#pragma unroll
  for (int t = 0; t < 16; t++) {
    int col = t * 16 + l15;
    b1v[t] = ldf(mb1, col, bf);
    w2v[t] = ldf(mW2, col, bf);
  }
  float b2v0 = ldf(mb2, 0, bf), b2v1 = ldf(mb2, 1, bf);
  float b2v2 = ldf(mb2, 2, bf), b2v3 = ldf(mb2, 3, bf);
  float b2 = b2v0;
  b2 = (l15 == 1) ? b2v1 : b2;
  b2 = (l15 == 2) ? b2v2 : b2;
  b2 = (l15 == 3) ? b2v3 : b2;

  int ebase = blockIdx.x * 256 + wave * 64;
#pragma unroll
  for (int f = 0; f < 4; f++) {
    int fbase = ebase + f * 16;
    if (fbase < EE) {  // EE%16==0 -> whole fragment in-bounds
      long eid = csr_eid[fbase + l15];
      bf16x8 a = (bf16x8){0, 0, 0, 0, 0, 0, 0, 0};
      if (quad < 2) {
        if (bf) {
          uint4 v = *reinterpret_cast<const uint4*>((const bf16*)eattr + eid * EDIM + quad * 8);
          a = *reinterpret_cast<bf16x8*>(&v);
        } else {
          const float4* p =
              reinterpret_cast<const float4*>((const float*)eattr + eid * EDIM + quad * 8);
          float4 v0 = p[0], v1 = p[1];
          a[0] = (short)f2bf_bits(v0.x); a[1] = (short)f2bf_bits(v0.y);
          a[2] = (short)f2bf_bits(v0.z); a[3] = (short)f2bf_bits(v0.w);
          a[4] = (short)f2bf_bits(v1.x); a[5] = (short)f2bf_bits(v1.y);
          a[6] = (short)f2bf_bits(v1.z); a[7] = (short)f2bf_bits(v1.w);
        }
      }
      // 16 named accumulators — never an array.
      float s00 = 0.f, s01 = 0.f, s02 = 0.f, s03 = 0.f;
      float s10 = 0.f, s11 = 0.f, s12 = 0.f, s13 = 0.f;
      float s20 = 0.f, s21 = 0.f, s22 = 0.f, s23 = 0.f;
      float s30 = 0.f, s31 = 0.f, s32 = 0.f, s33 = 0.f;
#define DO_T(T, S0, S1, S2, S3)                                               \
  {                                                                           \
    f32x4 acc = __builtin_amdgcn_mfma_f32_16x16x32_bf16(                      \
        a, bfrag[T], (f32x4){0.f, 0.f, 0.f, 0.f}, 0, 0, 0);                   \
    S0 += fmaxf(acc.x + b1v[T], 0.f) * w2v[T];                                \
    S1 += fmaxf(acc.y + b1v[T], 0.f) * w2v[T];                                \
    S2 += fmaxf(acc.z + b1v[T], 0.f) * w2v[T];                                \
    S3 += fmaxf(acc.w + b1v[T], 0.f) * w2v[T];                                \
  }
      DO_T(0,  s00, s01, s02, s03) DO_T(1,  s00, s01, s02, s03)
      DO_T(2,  s00, s01, s02, s03) DO_T(3,  s00, s01, s02, s03)
      DO_T(4,  s10, s11, s12, s13) DO_T(5,  s10, s11, s12, s13)
      DO_T(6,  s10, s11, s12, s13) DO_T(7,  s10, s11, s12, s13)
      DO_T(8,  s20, s21, s22, s23) DO_T(9,  s20, s21, s22, s23)
      DO_T(10, s20, s21, s22, s23) DO_T(11, s20, s21, s22, s23)
      DO_T(12, s30, s31, s32, s33) DO_T(13, s30, s31, s32, s33)
      DO_T(14, s30, s31, s32, s33) DO_T(15, s30, s31, s32, s33)
#undef DO_T
#define RED_STEP(M)                                                           \
  s00 += __shfl_xor(s00, M); s01 += __shfl_xor(s01, M);                       \
  s02 += __shfl_xor(s02, M); s03 += __shfl_xor(s03, M);                       \
  s10 += __shfl_xor(s10, M); s11 += __shfl_xor(s11, M);                       \
  s12 += __shfl_xor(s12, M); s13 += __shfl_xor(s13, M);                       \
  s20 += __shfl_xor(s20, M); s21 += __shfl_xor(s21, M);                       \
  s22 += __shfl_xor(s22, M); s23 += __shfl_xor(s23, M);                       \
  s30 += __shfl_xor(s30, M); s31 += __shfl_xor(s31, M);                       \
  s32 += __shfl_xor(s32, M); s33 += __shfl_xor(s33, M);
      RED_STEP(1) RED_STEP(2) RED_STEP(4) RED_STEP(8)
#undef RED_STEP
      if (l15 < NL) {
        float r0 = s00, r1 = s01, r2 = s02, r3 = s03;
        r0 = (l15 == 1) ? s10 : r0; r1 = (l15 == 1) ? s11 : r1;
        r2 = (l15 == 1) ? s12 : r2; r3 = (l15 == 1) ? s13 : r3;
        r0 = (l15 == 2) ? s20 : r0; r1 = (l15 == 2) ? s21 : r1;
        r2 = (l15 == 2) ? s22 : r2; r3 = (l15 == 2) ? s23 : r3;
        r0 = (l15 == 3) ? s30 : r0; r1 = (l15 == 3) ? s31 : r1;
        r2 = (l15 == 3) ? s32 : r2; r3 = (l15 == 3) ? s33 : r3;
        float4 o;
        o.x = 1.f / (1.f + __expf(-(r0 + b2)));
        o.y = 1.f / (1.f + __expf(-(r1 + b2)));
        o.z = 1.f / (1.f + __expf(-(r2 + b2)));
        o.w = 1.f / (1.f + __expf(-(r3 + b2)));
        *reinterpret_cast<float4*>(&csr_val[(size_t)l15 * EE + fbase + quad * 4]) = o;
      }
    }
  }
}

// ---------------- degree / dinv per layer -----------------------------------
__global__ __launch_bounds__(256) void deg_kernel(const int* __restrict__ offs,
                                                  const float* __restrict__ csr_val,
                                                  float* __restrict__ dinv_all) {
  int n = blockIdx.x * 256 + threadIdx.x;
  if (n >= NN) return;
  int s = offs[n], e = offs[n + 1];
  float d0 = 1.f, d1 = 1.f, d2 = 1.f, d3 = 1.f;  // self-loop weight 1.0
  for (int k = s; k < e; k++) {
    d0 += csr_val[k];
    d1 += csr_val[EE + k];
    d2 += csr_val[2 * (size_t)EE + k];
    d3 += csr_val[3 * (size_t)EE + k];
  }
  dinv_all[n] = rsqrtf(d0);
  dinv_all[NN + n] = rsqrtf(d1);
  dinv_all[2 * NN + n] = rsqrtf(d2);
  dinv_all[3 * NN + n] = rsqrtf(d3);
}

// csr_val[l][k] *= dinv_l[src_k]
__global__ __launch_bounds__(256) void csr_scale_kernel(const int* __restrict__ csr_src,
                                                        const float* __restrict__ dinv_all,
                                                        float* __restrict__ csr_val) {
  int k = blockIdx.x * 256 + threadIdx.x;
  if (k >= EE) return;
  int s = csr_src[k];
  s = min(max(s, 0), NN - 1);
#pragma unroll
  for (int l = 0; l < NL; l++)
    csr_val[(size_t)l * EE + k] *= dinv_all[(size_t)l * NN + s];
}

// ---------------- node GEMM via MFMA ----------------------------------------
__global__ __launch_bounds__(256) void gemm_nodes_mfma(
    const float* __restrict__ A, const unsigned short* __restrict__ Wt,
    const void* __restrict__ bias, long boff, float* __restrict__ outp,
    unsigned short* __restrict__ out16, int relu, const int* __restrict__ flag) {
  __shared__ alignas(16) unsigned short sA[64 * 136];
  __shared__ alignas(16) unsigned short sW[128 * 136];
  int tid = threadIdx.x;
  int rbase = blockIdx.x * 64;

#pragma unroll
  for (int p = 0; p < 8; p++) {
    int idx8 = p * 256 + tid;
    int n = idx8 >> 4, kc = idx8 & 15;
    uint4 v = reinterpret_cast<const uint4*>(Wt)[idx8];
    *reinterpret_cast<uint4*>(&sW[n * 136 + kc * 8]) = v;
  }
#pragma unroll
  for (int p = 0; p < 8; p++) {
    int idx = p * 1024 + tid * 4;
    int m = idx >> 7, k = idx & 127;
    int row = rbase + m;
    float4 v = make_float4(0.f, 0.f, 0.f, 0.f);
    if (row < NN) v = *reinterpret_cast<const float4*>(&A[(size_t)row * HID + k]);
    ushort4 b;
    b.x = f2bf_bits(v.x); b.y = f2bf_bits(v.y);
    b.z = f2bf_bits(v.z); b.w = f2bf_bits(v.w);
    *reinterpret_cast<ushort4*>(&sA[m * 136 + k]) = b;
  }
  __syncthreads();

  int wave = tid >> 6, lane = tid & 63;
  int l15 = lane & 15, quad = lane >> 4;
  int mstrip = wave * 16;

  f32x4 acc[8];
#pragma unroll
  for (int t = 0; t < 8; t++) acc[t] = (f32x4){0.f, 0.f, 0.f, 0.f};

#pragma unroll
  for (int ks = 0; ks < 4; ks++) {
    int k0 = ks * 32 + quad * 8;
    bf16x8 a = *reinterpret_cast<const bf16x8*>(&sA[(mstrip + l15) * 136 + k0]);
#pragma unroll
    for (int t = 0; t < 8; t++) {
      bf16x8 b = *reinterpret_cast<const bf16x8*>(&sW[(t * 16 + l15) * 136 + k0]);
      acc[t] = __builtin_amdgcn_mfma_f32_16x16x32_bf16(a, b, acc[t], 0, 0, 0);
    }
  }

  bool bf = *flag != 0;
#pragma unroll
  for (int t = 0; t < 8; t++) {
    int n = t * 16 + l15;
    float bv = (boff >= 0) ? ldf(bias, boff + n, bf) : 0.f;
#pragma unroll
    for (int r = 0; r < 4; r++) {
      int row = rbase + mstrip + quad * 4 + r;
      if (row < NN) {
        float o = acc[t][r] + bv;
        if (relu) o = fmaxf(o, 0.f);
        if (outp) outp[(size_t)row * HID + n] = o;
        if (out16) out16[(size_t)row * HID + n] = f2bf_bits(o);
      }
    }
  }
}

// ---------------- tail GEMM via MFMA ----------------------------------------
__global__ __launch_bounds__(256) void gemm_tail_mfma(
    const float* __restrict__ A, int lda, const unsigned short* __restrict__ Wt,
    int Kp, const void* __restrict__ bias, float* __restrict__ outp, int ldo,
    int relu, const int* __restrict__ flag) {
  __shared__ alignas(16) unsigned short sA[64 * 264];
  __shared__ alignas(16) unsigned short sW[64 * 264];
  int tid = threadIdx.x;
  int rbase = blockIdx.x * 64;
  int nbase = blockIdx.y * 64;
  int wave = tid >> 6, lane = tid & 63;
  int l15 = lane & 15, quad = lane >> 4;
  int mstrip = wave * 16;

  f32x4 acc[4];
#pragma unroll
  for (int t = 0; t < 4; t++) acc[t] = (f32x4){0.f, 0.f, 0.f, 0.f};

  for (int kc = 0; kc < Kp; kc += 256) {
#pragma unroll 4
    for (int p = 0; p < 16; p++) {
      int idx = p * 1024 + tid * 4;
      int m = idx >> 8, k = idx & 255;
      float4 v = *reinterpret_cast<const float4*>(&A[(size_t)(rbase + m) * lda + kc + k]);
      ushort4 b;
      b.x = f2bf_bits(v.x); b.y = f2bf_bits(v.y);
      b.z = f2bf_bits(v.z); b.w = f2bf_bits(v.w);
      *reinterpret_cast<ushort4*>(&sA[m * 264 + k]) = b;
    }
#pragma unroll 4
    for (int p = 0; p < 8; p++) {
      int idx8 = p * 256 + tid;
      int n = idx8 >> 5, kk = (idx8 & 31) * 8;
      uint4 v = *reinterpret_cast<const uint4*>(&Wt[(size_t)(nbase + n) * Kp + kc + kk]);
      *reinterpret_cast<uint4*>(&sW[n * 264 + kk]) = v;
    }
    __syncthreads();
#pragma unroll
    for (int ks = 0; ks < 8; ks++) {
      int k0 = ks * 32 + quad * 8;
      bf16x8 a = *reinterpret_cast<const bf16x8*>(&sA[(mstrip + l15) * 264 + k0]);
#pragma unroll
      for (int nt = 0; nt < 4; nt++) {
        bf16x8 b = *reinterpret_cast<const bf16x8*>(&sW[(nt * 16 + l15) * 264 + k0]);
        acc[nt] = __builtin_amdgcn_mfma_f32_16x16x32_bf16(a, b, acc[nt], 0, 0, 0);
      }
    }
    __syncthreads();
  }

  bool bf = *flag != 0;
#pragma unroll
  for (int nt = 0; nt < 4; nt++) {
    int col = nbase + nt * 16 + l15;
    float bv = ldf(bias, col, bf);
#pragma unroll
    for (int r = 0; r < 4; r++) {
      int row = rbase + mstrip + quad * 4 + r;
      float o = acc[nt][r] + bv;
      if (relu) o = fmaxf(o, 0.f);
      outp[(size_t)row * ldo + col] = o;
    }
  }
}

// ---------------- aggregation (bf16 gather, f32 accumulate) -----------------
__global__ __launch_bounds__(128) void aggregate_kernel(
    const unsigned short* __restrict__ hl16, const int* __restrict__ offs,
    const int* __restrict__ csr_src, const float* __restrict__ csr_val,
    const float* __restrict__ dinv, const void* __restrict__ bias, long boff,
    float* __restrict__ outp, const int* __restrict__ flag) {
  bool bf = *flag != 0;
  int n = blockIdx.x;
  int c = threadIdx.x;
  __shared__ int s_src[128];
  __shared__ float s_val[128];
  int start = offs[n], end = offs[n + 1];
  float acc = 0.f;
  for (int base = start; base < end; base += 128) {
    int k = base + c;
    if (k < end) {
      s_src[c] = min(max(csr_src[k], 0), NN - 1);
      s_val[c] = csr_val[k];
    }
    __syncthreads();
    int m = min(128, end - base);
    for (int j = 0; j < m; j++)
      acc = fmaf(s_val[j], bfl((unsigned)hl16[(size_t)s_src[j] * HID + c]), acc);
    __syncthreads();
  }
  float dn = dinv[n];
  float selfv = bfl((unsigned)hl16[(size_t)n * HID + c]);
  outp[(size_t)n * HID + c] = dn * acc + dn * dn * selfv + ldf(bias, boff + c, bf);
}

// ---------------- mean pool per graph (sorted batch_index) ------------------
__global__ __launch_bounds__(128) void pool_kernel(const float* __restrict__ h,
                                                   const int* __restrict__ batch,
                                                   float* __restrict__ cat) {
  int g = blockIdx.x, c = threadIdx.x;
  int lo = 0, hi = NN;
  while (lo < hi) { int mid = (lo + hi) >> 1; if (batch[mid] < g) lo = mid + 1; else hi = mid; }
  int start = lo;
  hi = NN;
  while (lo < hi) { int mid = (lo + hi) >> 1; if (batch[mid] < g + 1) lo = mid + 1; else hi = mid; }
  int end = lo;
  float s = 0.f;
  for (int n = start; n < end; n++) s += h[(size_t)n * HID + c];
  float cntf = (float)(end - start);
  cat[(size_t)g * PIN + c] = s / fmaxf(cntf, 1.f);
}

// ---------------- final [G,512] @ [512,1] + b -> out ------------------------
__global__ __launch_bounds__(64) void final_kernel(const float* __restrict__ A,
                                                   const void* __restrict__ W,
                                                   const void* __restrict__ b,
                                                   void* __restrict__ outp,
                                                   const int* __restrict__ flag) {
  bool bf = *flag != 0;
  int g = blockIdx.x, lane = threadIdx.x;
  float s = 0.f;
  for (int k = lane; k < PH; k += 64) s = fmaf(A[(size_t)g * PH + k], ldf(W, k, bf), s);
#pragma unroll
  for (int off = 32; off > 0; off >>= 1) s += __shfl_down(s, off);
  if (lane == 0) {
    float r = s + ldf(b, 0, bf);
    if (bf) ((bf16*)outp)[g] = __float2bfloat16(r);
    else    ((float*)outp)[g] = r;
  }
}

// ---------------------------------------------------------------------------
extern "C" void kernel_launch(void* const* d_in, const int* in_sizes, int n_in,
                              void* d_out, int out_size, void* d_ws, size_t ws_size,
                              hipStream_t stream) {
  const void* x      = d_in[0];
  const int*  ei     = (const int*)d_in[1];
  const void* eattr  = d_in[2];
  const int*  batch  = (const int*)d_in[3];
  const void* molf   = d_in[4];
  const void* lin_W  = d_in[5];
  const void* mW1    = d_in[6];
  const void* mb1    = d_in[7];
  const void* mW2    = d_in[8];
  const void* mb2    = d_in[9];
  const void* cbias  = d_in[10];
  const void* gW     = d_in[11];
  const void* gb     = d_in[12];
  const void* mlpW0  = d_in[13];
  const void* mlpb0  = d_in[14];
  const void* mlpW1  = d_in[15];
  const void* mlpb1  = d_in[16];
  const void* mlpW2  = d_in[17];
  const void* mlpb2  = d_in[18];
  const void* mlpW3  = d_in[19];
  const void* mlpb3  = d_in[20];
  const void* predW0 = d_in[21];
  const void* predb0 = d_in[22];
  const void* predW1 = d_in[23];
  const void* predb1 = d_in[24];
  const void* outW   = d_in[25];
  const void* outb   = d_in[26];

  char* base = (char*)d_ws;
  size_t off = 0;
  auto alloc = [&](size_t bytes) -> char* {
    char* p = base + off;
    off = (off + bytes + 255) & ~(size_t)255;
    return p;
  };
  float* bufA     = (float*)alloc((size_t)NN * HID * 4);   // h (layer state, f32)
  float* bufB     = (float*)alloc((size_t)NN * HID * 4);   // t (aggregate out, f32)
  unsigned short* hl16 = (unsigned short*)alloc((size_t)NN * HID * 2);  // lin out, bf16
  float* dinv_all = (float*)alloc((size_t)NL * NN * 4);
  int*   cnt      = (int*)alloc((size_t)NN * 4);
  int*   offs     = (int*)alloc((size_t)(NN + 1) * 4);
  int*   cursor   = (int*)alloc((size_t)NN * 4);
  int*   bsum     = (int*)alloc((size_t)256 * 4);
  int*   csr_src  = (int*)alloc((size_t)EE * 4);
  int*   csr_eid  = (int*)alloc((size_t)EE * 4);
  float* csr_val  = (float*)alloc((size_t)NL * EE * 4);
  unsigned short* Wt    = (unsigned short*)alloc((size_t)8 * HID * HID * 2);
  unsigned short* tailW = (unsigned short*)alloc((size_t)622592 * 2);
  unsigned short* edgeW = (unsigned short*)alloc((size_t)256 * 32 * 2);
  int*   flag     = (int*)alloc(256);
  float* molf32   = (float*)alloc((size_t)GG * 256 * 4);
  float* m0       = (float*)alloc((size_t)GG * MH * 4);
  float* m1       = (float*)alloc((size_t)GG * MH * 4);
  float* cat      = (float*)alloc((size_t)GG * PIN * 4);
  float* p0       = (float*)alloc((size_t)GG * PH * 4);
  float* p1       = (float*)alloc((size_t)GG * PH * 4);

  hipMemsetAsync(cnt, 0, (size_t)NN * 4, stream);
  hipMemsetAsync(cursor, 0, (size_t)NN * 4, stream);
  hipMemsetAsync(molf32, 0, (size_t)GG * 256 * 4, stream);

  // dtype probe first — everything downstream branches on it
  probe_kernel<<<1, 64, 0, stream>>>((const unsigned short*)x, flag);

  // weight prep
  prep_weights<<<512, 256, 0, stream>>>(lin_W, gW, Wt, flag);
  prep_tail<<<(622592 + 255) / 256, 256, 0, stream>>>(mlpW0, mlpW1, mlpW2, mlpW3,
                                                      predW0, predW1, tailW, flag);
  prep_edge_w<<<32, 256, 0, stream>>>(mW1, edgeW, flag);

  // x -> f32
  {
    int n4 = NN * HID / 4;
    cvt_any<<<(n4 + 255) / 256, 256, 0, stream>>>(x, bufA, n4, flag);
  }
  // CSR build (3-phase parallel scan)
  count_kernel<<<(EE + 255) / 256, 256, 0, stream>>>(ei, cnt);
  scan_phase1<<<SCAN_B, 256, 0, stream>>>(cnt, bsum);
  scan_phase2<<<1, 256, 0, stream>>>(bsum, offs);
  scan_phase3<<<SCAN_B, 256, 0, stream>>>(cnt, bsum, offs);
  fill_kernel<<<(EE + 255) / 256, 256, 0, stream>>>(ei, offs, cursor, csr_src, csr_eid);
  // edge gates (MFMA, LDS-free, CSR order), degrees, scaling
  edge_mlp_mfma<<<(EE + 255) / 256, 256, 0, stream>>>(eattr, edgeW, mb1, mW2, mb2,
                                                      csr_eid, csr_val, flag);
  deg_kernel<<<(NN + 255) / 256, 256, 0, stream>>>(offs, csr_val, dinv_all);
  csr_scale_kernel<<<(EE + 255) / 256, 256, 0, stream>>>(csr_src, dinv_all, csr_val);

  // GCN layers: lin(h)->hl16(bf16); aggregate(hl16)->bufB; gcn(bufB)->h
  float* h = bufA;
  float* t = bufB;
  const int gemm_blocks = (NN + 63) / 64;  // 782
  for (int l = 0; l < NL; l++) {
    gemm_nodes_mfma<<<gemm_blocks, 256, 0, stream>>>(
        h, Wt + (size_t)l * HID * HID, nullptr, -1, nullptr, hl16, 0, flag);
    aggregate_kernel<<<NN, 128, 0, stream>>>(hl16, offs, csr_src,
                                             csr_val + (size_t)l * EE,
                                             dinv_all + (size_t)l * NN, cbias,
                                             (long)l * HID, t, flag);
    gemm_nodes_mfma<<<gemm_blocks, 256, 0, stream>>>(
        t, Wt + (size_t)(4 + l) * HID * HID, gb, (long)l * HID, h, nullptr, 1, flag);
  }

  // pooling -> cat[:, 0:128]
  pool_kernel<<<GG, 128, 0, stream>>>(h, batch, cat);

  // molecular MLP -> cat[:, 128:256]  (MFMA tail, K-padded weights)
  cvt_molf<<<(GG * 50 + 255) / 256, 256, 0, stream>>>(molf, molf32, flag);
  gemm_tail_mfma<<<dim3(4, 4), 256, 0, stream>>>(molf32, 256, tailW + 0,      256, mlpb0, m0, 256, 1, flag);
  gemm_tail_mfma<<<dim3(4, 4), 256, 0, stream>>>(m0,     256, tailW + 65536,  256, mlpb1, m1, 256, 1, flag);
  gemm_tail_mfma<<<dim3(4, 4), 256, 0, stream>>>(m1,     256, tailW + 131072, 256, mlpb2, m0, 256, 1, flag);
  gemm_tail_mfma<<<dim3(4, 2), 256, 0, stream>>>(m0,     256, tailW + 196608, 256, mlpb3, cat + MOUT, 256, 1, flag);

  // predictor
  gemm_tail_mfma<<<dim3(4, 8), 256, 0, stream>>>(cat, 256, tailW + 229376, 256, predb0, p0, 512, 1, flag);
  gemm_tail_mfma<<<dim3(4, 8), 256, 0, stream>>>(p0,  512, tailW + 360448, 512, predb1, p1, 512, 1, flag);
  final_kernel<<<GG, 64, 0, stream>>>(p1, outW, outb, d_out, flag);
}

// Round 11
// 731.806 us; speedup vs baseline: 1.2309x; 1.0431x over previous
//
#include <hip/hip_runtime.h>
#include <hip/hip_bf16.h>

// ---------------------------------------------------------------------------
// PDNConv GNN, MI355X round 11.
// Round-10 profile: pool_kernel #1 at 62.6 us — one block per graph (2
// waves/CU), ~195 serial row loads per thread: pure latency bound
// (occupancy 4.5%, VALUBusy 0.5%). Replaced with 2-phase pooling:
// (256 graphs x 8 chunks) partial sums -> combine+divide. ~8 us total.
// Everything else identical to round 10.
// ---------------------------------------------------------------------------

#define NN 50000
#define EE 600000
#define GG 256
#define HID 128
#define EDIM 16
#define EHID 64
#define NL 4
#define MIN_F 200
#define MH 256
#define MOUT 128
#define PH 512
#define PIN 256
#define SCAN_B 196  // ceil(NN/256)
#define PCH 8       // pooling chunks per graph

typedef __hip_bfloat16 bf16;
typedef __attribute__((ext_vector_type(8))) short bf16x8;
typedef __attribute__((ext_vector_type(4))) float f32x4;

__device__ __forceinline__ float bfl(unsigned u) { return __uint_as_float(u << 16); }
__device__ __forceinline__ float bfh(unsigned u) { return __uint_as_float(u & 0xffff0000u); }
__device__ __forceinline__ float b2f(bf16 x) { return __bfloat162float(x); }
__device__ __forceinline__ float ldf(const void* p, long i, bool bf) {
  return bf ? __bfloat162float(((const bf16*)p)[i]) : ((const float*)p)[i];
}
__device__ __forceinline__ unsigned short f2bf_bits(float v) {
  bf16 h = __float2bfloat16(v);
  return *reinterpret_cast<unsigned short*>(&h);
}

// ---------------- dtype probe ------------------------------------------------
__global__ void probe_kernel(const unsigned short* __restrict__ xs, int* flag) {
  if (threadIdx.x == 0 && blockIdx.x == 0) {
    int sane = 0;
    for (int i = 0; i < 128; i++) {
      unsigned e = (xs[i] >> 7) & 0xFF;
      if (e >= 96 && e <= 159) sane++;
    }
    *flag = (sane >= 112) ? 1 : 0;  // 1 = bf16 inputs
  }
}

// ---------------- input -> f32 conversion (4 elems/thread) ------------------
__global__ __launch_bounds__(256) void cvt_any(const void* __restrict__ in,
                                               float* __restrict__ outp, int n4,
                                               const int* __restrict__ flag) {
  bool bf = *flag != 0;
  int i = blockIdx.x * 256 + threadIdx.x;
  if (i >= n4) return;
  float4 v;
  if (bf) {
    uint2 u = reinterpret_cast<const uint2*>(in)[i];
    v.x = bfl(u.x); v.y = bfh(u.x); v.z = bfl(u.y); v.w = bfh(u.y);
  } else {
    v = reinterpret_cast<const float4*>(in)[i];
  }
  reinterpret_cast<float4*>(outp)[i] = v;
}

// ---------------- mol_features [G,200] -> padded f32 [G,256] ----------------
__global__ __launch_bounds__(256) void cvt_molf(const void* __restrict__ in,
                                                float* __restrict__ outp,
                                                const int* __restrict__ flag) {
  bool bf = *flag != 0;
  int i = blockIdx.x * 256 + threadIdx.x;  // GG*50
  if (i >= GG * 50) return;
  int row = i / 50, c4 = (i % 50) * 4;
  float4 v;
  if (bf) {
    const unsigned short* p = (const unsigned short*)in + (size_t)row * MIN_F + c4;
    uint2 u = *reinterpret_cast<const uint2*>(p);
    v.x = bfl(u.x); v.y = bfh(u.x); v.z = bfl(u.y); v.w = bfh(u.y);
  } else {
    v = *reinterpret_cast<const float4*>((const float*)in + (size_t)row * MIN_F + c4);
  }
  *reinterpret_cast<float4*>(&outp[(size_t)row * 256 + c4]) = v;
}

// ---------------- weight prep: node GEMM weights -> bf16 Wt[n][k] -----------
__global__ __launch_bounds__(256) void prep_weights(const void* __restrict__ lin_W,
                                                    const void* __restrict__ gW,
                                                    unsigned short* __restrict__ Wt,
                                                    const int* __restrict__ flag) {
  bool bf = *flag != 0;
  int idx = blockIdx.x * 256 + threadIdx.x;  // 0 .. 8*16384-1
  if (idx >= 8 * 16384) return;
  int mat = idx >> 14;
  int rem = idx & 16383;
  int n = rem >> 7, k = rem & 127;
  const void* src = (mat < 4) ? lin_W : gW;
  long srcIdx = (long)(mat & 3) * 16384 + (long)k * 128 + n;
  Wt[idx] = f2bf_bits(ldf(src, srcIdx, bf));
}

// ---------------- weight prep: edge MLP W1 -> bf16 W1t[256 cols][32 K] ------
__global__ __launch_bounds__(256) void prep_edge_w(const void* __restrict__ mW1,
                                                   unsigned short* __restrict__ W1t,
                                                   const int* __restrict__ flag) {
  bool bf = *flag != 0;
  int idx = blockIdx.x * 256 + threadIdx.x;  // 256*32
  if (idx >= 256 * 32) return;
  int col = idx >> 5, k = idx & 31;
  float v = 0.f;
  if (k < EDIM) v = ldf(mW1, (long)(col >> 6) * (EDIM * EHID) + (long)k * EHID + (col & 63), bf);
  W1t[idx] = f2bf_bits(v);
}

// ---------------- weight prep: tail (MLP+predictor) -> bf16 [N][Kp], K-pad --
__global__ __launch_bounds__(256) void prep_tail(
    const void* __restrict__ mlpW0, const void* __restrict__ mlpW1,
    const void* __restrict__ mlpW2, const void* __restrict__ mlpW3,
    const void* __restrict__ predW0, const void* __restrict__ predW1,
    unsigned short* __restrict__ T, const int* __restrict__ flag) {
  bool bf = *flag != 0;
  int idx = blockIdx.x * 256 + threadIdx.x;
  const void* src; int N, Kp, Ksrc, off;
  if      (idx < 65536)  { src = mlpW0;  N = 256; Kp = 256; Ksrc = 200; off = 0; }
  else if (idx < 131072) { src = mlpW1;  N = 256; Kp = 256; Ksrc = 256; off = 65536; }
  else if (idx < 196608) { src = mlpW2;  N = 256; Kp = 256; Ksrc = 256; off = 131072; }
  else if (idx < 229376) { src = mlpW3;  N = 128; Kp = 256; Ksrc = 256; off = 196608; }
  else if (idx < 360448) { src = predW0; N = 512; Kp = 256; Ksrc = 256; off = 229376; }
  else if (idx < 622592) { src = predW1; N = 512; Kp = 512; Ksrc = 512; off = 360448; }
  else return;
  int rem = idx - off;
  int n = rem / Kp, k = rem % Kp;
  float v = (k < Ksrc) ? ldf(src, (long)k * N + n, bf) : 0.f;
  T[idx] = f2bf_bits(v);
}

// ---------------- CSR build: histogram / 3-phase scan / fill ----------------
__global__ __launch_bounds__(256) void count_kernel(const int* __restrict__ ei,
                                                    int* __restrict__ cnt) {
  int e = blockIdx.x * 256 + threadIdx.x;
  if (e >= EE) return;
  int c = ei[EE + e];
  c = min(max(c, 0), NN - 1);
  atomicAdd(&cnt[c], 1);
}

__global__ __launch_bounds__(256) void scan_phase1(const int* __restrict__ cnt,
                                                   int* __restrict__ bsum) {
  __shared__ int red[256];
  int tid = threadIdx.x;
  int i = blockIdx.x * 256 + tid;
  red[tid] = (i < NN) ? cnt[i] : 0;
  __syncthreads();
  for (int off = 128; off > 0; off >>= 1) {
    if (tid < off) red[tid] += red[tid + off];
    __syncthreads();
  }
  if (tid == 0) bsum[blockIdx.x] = red[0];
}

__global__ __launch_bounds__(256) void scan_phase2(int* __restrict__ bsum,
                                                   int* __restrict__ offs) {
  __shared__ int buf[256];
  int tid = threadIdx.x;
  int v = (tid < SCAN_B) ? bsum[tid] : 0;
  buf[tid] = v;
  __syncthreads();
  for (int off = 1; off < 256; off <<= 1) {
    int t = (tid >= off) ? buf[tid - off] : 0;
    __syncthreads();
    buf[tid] += t;
    __syncthreads();
  }
  if (tid < SCAN_B) bsum[tid] = buf[tid] - v;  // exclusive block offsets
  if (tid == 255) offs[NN] = buf[255];
}

__global__ __launch_bounds__(256) void scan_phase3(const int* __restrict__ cnt,
                                                   const int* __restrict__ bsum,
                                                   int* __restrict__ offs) {
  __shared__ int buf[256];
  int tid = threadIdx.x;
  int i = blockIdx.x * 256 + tid;
  int v = (i < NN) ? cnt[i] : 0;
  buf[tid] = v;
  __syncthreads();
  for (int off = 1; off < 256; off <<= 1) {
    int t = (tid >= off) ? buf[tid - off] : 0;
    __syncthreads();
    buf[tid] += t;
    __syncthreads();
  }
  if (i < NN) offs[i] = bsum[blockIdx.x] + buf[tid] - v;
}

__global__ __launch_bounds__(256) void fill_kernel(const int* __restrict__ ei,
                                                   const int* __restrict__ offs,
                                                   int* __restrict__ cursor,
                                                   int* __restrict__ csr_src,
                                                   int* __restrict__ csr_eid) {
  int e = blockIdx.x * 256 + threadIdx.x;
  if (e >= EE) return;
  int c = ei[EE + e];
  c = min(max(c, 0), NN - 1);
  int pos = offs[c] + atomicAdd(&cursor[c], 1);
  pos = min(max(pos, 0), EE - 1);
  csr_src[pos] = ei[e];
  csr_eid[pos] = e;
}

// ---------------- edge-gate MLP via MFMA: LDS-free, array-free hot path -----
__global__ __launch_bounds__(256) void edge_mlp_mfma(
    const void* __restrict__ eattr, const unsigned short* __restrict__ W1t,
    const void* __restrict__ mb1, const void* __restrict__ mW2,
    const void* __restrict__ mb2, const int* __restrict__ csr_eid,
    float* __restrict__ csr_val, const int* __restrict__ flag) {
  bool bf = *flag != 0;
  int tid = threadIdx.x;
  int wave = tid >> 6, lane = tid & 63;
  int l15 = lane & 15, quad = lane >> 4;

  bf16x8 bfrag[16];
#pragma unroll
  for (int t = 0; t < 16; t++)
    bfrag[t] = *reinterpret_cast<const bf16x8*>(&W1t[(t * 16 + l15) * 32 + quad * 8]);

  float b1v[16], w2v[16];
#pragma unroll
  for (int t = 0; t < 16; t++) {
    int col = t * 16 + l15;
    b1v[t] = ldf(mb1, col, bf);
    w2v[t] = ldf(mW2, col, bf);
  }
  float b2v0 = ldf(mb2, 0, bf), b2v1 = ldf(mb2, 1, bf);
  float b2v2 = ldf(mb2, 2, bf), b2v3 = ldf(mb2, 3, bf);
  float b2 = b2v0;
  b2 = (l15 == 1) ? b2v1 : b2;
  b2 = (l15 == 2) ? b2v2 : b2;
  b2 = (l15 == 3) ? b2v3 : b2;

  int ebase = blockIdx.x * 256 + wave * 64;
#pragma unroll
  for (int f = 0; f < 4; f++) {
    int fbase = ebase + f * 16;
    if (fbase < EE) {  // EE%16==0 -> whole fragment in-bounds
      long eid = csr_eid[fbase + l15];
      bf16x8 a = (bf16x8){0, 0, 0, 0, 0, 0, 0, 0};
      if (quad < 2) {
        if (bf) {
          uint4 v = *reinterpret_cast<const uint4*>((const bf16*)eattr + eid * EDIM + quad * 8);
          a = *reinterpret_cast<bf16x8*>(&v);
        } else {
          const float4* p =
              reinterpret_cast<const float4*>((const float*)eattr + eid * EDIM + quad * 8);
          float4 v0 = p[0], v1 = p[1];
          a[0] = (short)f2bf_bits(v0.x); a[1] = (short)f2bf_bits(v0.y);
          a[2] = (short)f2bf_bits(v0.z); a[3] = (short)f2bf_bits(v0.w);
          a[4] = (short)f2bf_bits(v1.x); a[5] = (short)f2bf_bits(v1.y);
          a[6] = (short)f2bf_bits(v1.z); a[7] = (short)f2bf_bits(v1.w);
        }
      }
      float s00 = 0.f, s01 = 0.f, s02 = 0.f, s03 = 0.f;
      float s10 = 0.f, s11 = 0.f, s12 = 0.f, s13 = 0.f;
      float s20 = 0.f, s21 = 0.f, s22 = 0.f, s23 = 0.f;
      float s30 = 0.f, s31 = 0.f, s32 = 0.f, s33 = 0.f;
#define DO_T(T, S0, S1, S2, S3)                                               \
  {                                                                           \
    f32x4 acc = __builtin_amdgcn_mfma_f32_16x16x32_bf16(                      \
        a, bfrag[T], (f32x4){0.f, 0.f, 0.f, 0.f}, 0, 0, 0);                   \
    S0 += fmaxf(acc.x + b1v[T], 0.f) * w2v[T];                                \
    S1 += fmaxf(acc.y + b1v[T], 0.f) * w2v[T];                                \
    S2 += fmaxf(acc.z + b1v[T], 0.f) * w2v[T];                                \
    S3 += fmaxf(acc.w + b1v[T], 0.f) * w2v[T];                                \
  }
      DO_T(0,  s00, s01, s02, s03) DO_T(1,  s00, s01, s02, s03)
      DO_T(2,  s00, s01, s02, s03) DO_T(3,  s00, s01, s02, s03)
      DO_T(4,  s10, s11, s12, s13) DO_T(5,  s10, s11, s12, s13)
      DO_T(6,  s10, s11, s12, s13) DO_T(7,  s10, s11, s12, s13)
      DO_T(8,  s20, s21, s22, s23) DO_T(9,  s20, s21, s22, s23)
      DO_T(10, s20, s21, s22, s23) DO_T(11, s20, s21, s22, s23)
      DO_T(12, s30, s31, s32, s33) DO_T(13, s30, s31, s32, s33)
      DO_T(14, s30, s31, s32, s33) DO_T(15, s30, s31, s32, s33)
#undef DO_T
#define RED_STEP(M)                                                           \
  s00 += __shfl_xor(s00, M); s01 += __shfl_xor(s01, M);                       \
  s02 += __shfl_xor(s02, M); s03 += __shfl_xor(s03, M);                       \
  s10 += __shfl_xor(s10, M); s11 += __shfl_xor(s11, M);                       \
  s12 += __shfl_xor(s12, M); s13 += __shfl_xor(s13, M);                       \
  s20 += __shfl_xor(s20, M); s21 += __shfl_xor(s21, M);                       \
  s22 += __shfl_xor(s22, M); s23 += __shfl_xor(s23, M);                       \
  s30 += __shfl_xor(s30, M); s31 += __shfl_xor(s31, M);                       \
  s32 += __shfl_xor(s32, M); s33 += __shfl_xor(s33, M);
      RED_STEP(1) RED_STEP(2) RED_STEP(4) RED_STEP(8)
#undef RED_STEP
      if (l15 < NL) {
        float r0 = s00, r1 = s01, r2 = s02, r3 = s03;
        r0 = (l15 == 1) ? s10 : r0; r1 = (l15 == 1) ? s11 : r1;
        r2 = (l15 == 1) ? s12 : r2; r3 = (l15 == 1) ? s13 : r3;
        r0 = (l15 == 2) ? s20 : r0; r1 = (l15 == 2) ? s21 : r1;
        r2 = (l15 == 2) ? s22 : r2; r3 = (l15 == 2) ? s23 : r3;
        r0 = (l15 == 3) ? s30 : r0; r1 = (l15 == 3) ? s31 : r1;
        r2 = (l15 == 3) ? s32 : r2; r3 = (l15 == 3) ? s33 : r3;
        float4 o;
        o.x = 1.f / (1.f + __expf(-(r0 + b2)));
        o.y = 1.f / (1.f + __expf(-(r1 + b2)));
        o.z = 1.f / (1.f + __expf(-(r2 + b2)));
        o.w = 1.f / (1.f + __expf(-(r3 + b2)));
        *reinterpret_cast<float4*>(&csr_val[(size_t)l15 * EE + fbase + quad * 4]) = o;
      }
    }
  }
}

// ---------------- degree / dinv per layer -----------------------------------
__global__ __launch_bounds__(256) void deg_kernel(const int* __restrict__ offs,
                                                  const float* __restrict__ csr_val,
                                                  float* __restrict__ dinv_all) {
  int n = blockIdx.x * 256 + threadIdx.x;
  if (n >= NN) return;
  int s = offs[n], e = offs[n + 1];
  float d0 = 1.f, d1 = 1.f, d2 = 1.f, d3 = 1.f;  // self-loop weight 1.0
  for (int k = s; k < e; k++) {
    d0 += csr_val[k];
    d1 += csr_val[EE + k];
    d2 += csr_val[2 * (size_t)EE + k];
    d3 += csr_val[3 * (size_t)EE + k];
  }
  dinv_all[n] = rsqrtf(d0);
  dinv_all[NN + n] = rsqrtf(d1);
  dinv_all[2 * NN + n] = rsqrtf(d2);
  dinv_all[3 * NN + n] = rsqrtf(d3);
}

// csr_val[l][k] *= dinv_l[src_k]
__global__ __launch_bounds__(256) void csr_scale_kernel(const int* __restrict__ csr_src,
                                                        const float* __restrict__ dinv_all,
                                                        float* __restrict__ csr_val) {
  int k = blockIdx.x * 256 + threadIdx.x;
  if (k >= EE) return;
  int s = csr_src[k];
  s = min(max(s, 0), NN - 1);
#pragma unroll
  for (int l = 0; l < NL; l++)
    csr_val[(size_t)l * EE + k] *= dinv_all[(size_t)l * NN + s];
}

// ---------------- node GEMM via MFMA ----------------------------------------
__global__ __launch_bounds__(256) void gemm_nodes_mfma(
    const float* __restrict__ A, const unsigned short* __restrict__ Wt,
    const void* __restrict__ bias, long boff, float* __restrict__ outp,
    unsigned short* __restrict__ out16, int relu, const int* __restrict__ flag) {
  __shared__ alignas(16) unsigned short sA[64 * 136];
  __shared__ alignas(16) unsigned short sW[128 * 136];
  int tid = threadIdx.x;
  int rbase = blockIdx.x * 64;

#pragma unroll
  for (int p = 0; p < 8; p++) {
    int idx8 = p * 256 + tid;
    int n = idx8 >> 4, kc = idx8 & 15;
    uint4 v = reinterpret_cast<const uint4*>(Wt)[idx8];
    *reinterpret_cast<uint4*>(&sW[n * 136 + kc * 8]) = v;
  }
#pragma unroll
  for (int p = 0; p < 8; p++) {
    int idx = p * 1024 + tid * 4;
    int m = idx >> 7, k = idx & 127;
    int row = rbase + m;
    float4 v = make_float4(0.f, 0.f, 0.f, 0.f);
    if (row < NN) v = *reinterpret_cast<const float4*>(&A[(size_t)row * HID + k]);
    ushort4 b;
    b.x = f2bf_bits(v.x); b.y = f2bf_bits(v.y);
    b.z = f2bf_bits(v.z); b.w = f2bf_bits(v.w);
    *reinterpret_cast<ushort4*>(&sA[m * 136 + k]) = b;
  }
  __syncthreads();

  int wave = tid >> 6, lane = tid & 63;
  int l15 = lane & 15, quad = lane >> 4;
  int mstrip = wave * 16;

  f32x4 acc[8];
#pragma unroll
  for (int t = 0; t < 8; t++) acc[t] = (f32x4){0.f, 0.f, 0.f, 0.f};

#pragma unroll
  for (int ks = 0; ks < 4; ks++) {
    int k0 = ks * 32 + quad * 8;
    bf16x8 a = *reinterpret_cast<const bf16x8*>(&sA[(mstrip + l15) * 136 + k0]);
#pragma unroll
    for (int t = 0; t < 8; t++) {
      bf16x8 b = *reinterpret_cast<const bf16x8*>(&sW[(t * 16 + l15) * 136 + k0]);
      acc[t] = __builtin_amdgcn_mfma_f32_16x16x32_bf16(a, b, acc[t], 0, 0, 0);
    }
  }

  bool bf = *flag != 0;
#pragma unroll
  for (int t = 0; t < 8; t++) {
    int n = t * 16 + l15;
    float bv = (boff >= 0) ? ldf(bias, boff + n, bf) : 0.f;
#pragma unroll
    for (int r = 0; r < 4; r++) {
      int row = rbase + mstrip + quad * 4 + r;
      if (row < NN) {
        float o = acc[t][r] + bv;
        if (relu) o = fmaxf(o, 0.f);
        if (outp) outp[(size_t)row * HID + n] = o;
        if (out16) out16[(size_t)row * HID + n] = f2bf_bits(o);
      }
    }
  }
}

// ---------------- tail GEMM via MFMA ----------------------------------------
__global__ __launch_bounds__(256) void gemm_tail_mfma(
    const float* __restrict__ A, int lda, const unsigned short* __restrict__ Wt,
    int Kp, const void* __restrict__ bias, float* __restrict__ outp, int ldo,
    int relu, const int* __restrict__ flag) {
  __shared__ alignas(16) unsigned short sA[64 * 264];
  __shared__ alignas(16) unsigned short sW[64 * 264];
  int tid = threadIdx.x;
  int rbase = blockIdx.x * 64;
  int nbase = blockIdx.y * 64;
  int wave = tid >> 6, lane = tid & 63;
  int l15 = lane & 15, quad = lane >> 4;
  int mstrip = wave * 16;

  f32x4 acc[4];
#pragma unroll
  for (int t = 0; t < 4; t++) acc[t] = (f32x4){0.f, 0.f, 0.f, 0.f};

  for (int kc = 0; kc < Kp; kc += 256) {
#pragma unroll 4
    for (int p = 0; p < 16; p++) {
      int idx = p * 1024 + tid * 4;
      int m = idx >> 8, k = idx & 255;
      float4 v = *reinterpret_cast<const float4*>(&A[(size_t)(rbase + m) * lda + kc + k]);
      ushort4 b;
      b.x = f2bf_bits(v.x); b.y = f2bf_bits(v.y);
      b.z = f2bf_bits(v.z); b.w = f2bf_bits(v.w);
      *reinterpret_cast<ushort4*>(&sA[m * 264 + k]) = b;
    }
#pragma unroll 4
    for (int p = 0; p < 8; p++) {
      int idx8 = p * 256 + tid;
      int n = idx8 >> 5, kk = (idx8 & 31) * 8;
      uint4 v = *reinterpret_cast<const uint4*>(&Wt[(size_t)(nbase + n) * Kp + kc + kk]);
      *reinterpret_cast<uint4*>(&sW[n * 264 + kk]) = v;
    }
    __syncthreads();
#pragma unroll
    for (int ks = 0; ks < 8; ks++) {
      int k0 = ks * 32 + quad * 8;
      bf16x8 a = *reinterpret_cast<const bf16x8*>(&sA[(mstrip + l15) * 264 + k0]);
#pragma unroll
      for (int nt = 0; nt < 4; nt++) {
        bf16x8 b = *reinterpret_cast<const bf16x8*>(&sW[(nt * 16 + l15) * 264 + k0]);
        acc[nt] = __builtin_amdgcn_mfma_f32_16x16x32_bf16(a, b, acc[nt], 0, 0, 0);
      }
    }
    __syncthreads();
  }

  bool bf = *flag != 0;
#pragma unroll
  for (int nt = 0; nt < 4; nt++) {
    int col = nbase + nt * 16 + l15;
    float bv = ldf(bias, col, bf);
#pragma unroll
    for (int r = 0; r < 4; r++) {
      int row = rbase + mstrip + quad * 4 + r;
      float o = acc[nt][r] + bv;
      if (relu) o = fmaxf(o, 0.f);
      outp[(size_t)row * ldo + col] = o;
    }
  }
}

// ---------------- aggregation (bf16 gather, f32 accumulate) -----------------
__global__ __launch_bounds__(128) void aggregate_kernel(
    const unsigned short* __restrict__ hl16, const int* __restrict__ offs,
    const int* __restrict__ csr_src, const float* __restrict__ csr_val,
    const float* __restrict__ dinv, const void* __restrict__ bias, long boff,
    float* __restrict__ outp, const int* __restrict__ flag) {
  bool bf = *flag != 0;
  int n = blockIdx.x;
  int c = threadIdx.x;
  __shared__ int s_src[128];
  __shared__ float s_val[128];
  int start = offs[n], end = offs[n + 1];
  float acc = 0.f;
  for (int base = start; base < end; base += 128) {
    int k = base + c;
    if (k < end) {
      s_src[c] = min(max(csr_src[k], 0), NN - 1);
      s_val[c] = csr_val[k];
    }
    __syncthreads();
    int m = min(128, end - base);
    for (int j = 0; j < m; j++)
      acc = fmaf(s_val[j], bfl((unsigned)hl16[(size_t)s_src[j] * HID + c]), acc);
    __syncthreads();
  }
  float dn = dinv[n];
  float selfv = bfl((unsigned)hl16[(size_t)n * HID + c]);
  outp[(size_t)n * HID + c] = dn * acc + dn * dn * selfv + ldf(bias, boff + c, bf);
}

// ---------------- mean pool, 2-phase ----------------------------------------
// phase 1: grid (GG, PCH); each block sums its chunk of graph g's rows.
__global__ __launch_bounds__(128) void pool_partial(const float* __restrict__ h,
                                                    const int* __restrict__ batch,
                                                    float* __restrict__ part) {
  int g = blockIdx.x, chunk = blockIdx.y, c = threadIdx.x;
  int lo = 0, hi = NN;
  while (lo < hi) { int mid = (lo + hi) >> 1; if (batch[mid] < g) lo = mid + 1; else hi = mid; }
  int start = lo;
  hi = NN;
  while (lo < hi) { int mid = (lo + hi) >> 1; if (batch[mid] < g + 1) lo = mid + 1; else hi = mid; }
  int end = lo;
  int len = end - start;
  int per = (len + PCH - 1) / PCH;
  int s = start + chunk * per;
  int e = min(s + per, end);
  float sum = 0.f;
  for (int n = s; n < e; n++) sum += h[(size_t)n * HID + c];
  part[((size_t)g * PCH + chunk) * HID + c] = sum;
}

// phase 2: combine partials, divide by count, write cat[:, 0:128].
__global__ __launch_bounds__(128) void pool_combine(const float* __restrict__ part,
                                                    const int* __restrict__ batch,
                                                    float* __restrict__ cat) {
  int g = blockIdx.x, c = threadIdx.x;
  int lo = 0, hi = NN;
  while (lo < hi) { int mid = (lo + hi) >> 1; if (batch[mid] < g) lo = mid + 1; else hi = mid; }
  int start = lo;
  hi = NN;
  while (lo < hi) { int mid = (lo + hi) >> 1; if (batch[mid] < g + 1) lo = mid + 1; else hi = mid; }
  int end = lo;
  float s = 0.f;
#pragma unroll
  for (int k = 0; k < PCH; k++) s += part[((size_t)g * PCH + k) * HID + c];
  float cntf = (float)(end - start);
  cat[(size_t)g * PIN + c] = s / fmaxf(cntf, 1.f);
}

// ---------------- final [G,512] @ [512,1] + b -> out ------------------------
__global__ __launch_bounds__(64) void final_kernel(const float* __restrict__ A,
                                                   const void* __restrict__ W,
                                                   const void* __restrict__ b,
                                                   void* __restrict__ outp,
                                                   const int* __restrict__ flag) {
  bool bf = *flag != 0;
  int g = blockIdx.x, lane = threadIdx.x;
  float s = 0.f;
  for (int k = lane; k < PH; k += 64) s = fmaf(A[(size_t)g * PH + k], ldf(W, k, bf), s);
#pragma unroll
  for (int off = 32; off > 0; off >>= 1) s += __shfl_down(s, off);
  if (lane == 0) {
    float r = s + ldf(b, 0, bf);
    if (bf) ((bf16*)outp)[g] = __float2bfloat16(r);
    else    ((float*)outp)[g] = r;
  }
}

// ---------------------------------------------------------------------------
extern "C" void kernel_launch(void* const* d_in, const int* in_sizes, int n_in,
                              void* d_out, int out_size, void* d_ws, size_t ws_size,
                              hipStream_t stream) {
  const void* x      = d_in[0];
  const int*  ei     = (const int*)d_in[1];
  const void* eattr  = d_in[2];
  const int*  batch  = (const int*)d_in[3];
  const void* molf   = d_in[4];
  const void* lin_W  = d_in[5];
  const void* mW1    = d_in[6];
  const void* mb1    = d_in[7];
  const void* mW2    = d_in[8];
  const void* mb2    = d_in[9];
  const void* cbias  = d_in[10];
  const void* gW     = d_in[11];
  const void* gb     = d_in[12];
  const void* mlpW0  = d_in[13];
  const void* mlpb0  = d_in[14];
  const void* mlpW1  = d_in[15];
  const void* mlpb1  = d_in[16];
  const void* mlpW2  = d_in[17];
  const void* mlpb2  = d_in[18];
  const void* mlpW3  = d_in[19];
  const void* mlpb3  = d_in[20];
  const void* predW0 = d_in[21];
  const void* predb0 = d_in[22];
  const void* predW1 = d_in[23];
  const void* predb1 = d_in[24];
  const void* outW   = d_in[25];
  const void* outb   = d_in[26];

  char* base = (char*)d_ws;
  size_t off = 0;
  auto alloc = [&](size_t bytes) -> char* {
    char* p = base + off;
    off = (off + bytes + 255) & ~(size_t)255;
    return p;
  };
  float* bufA     = (float*)alloc((size_t)NN * HID * 4);   // h (layer state, f32)
  float* bufB     = (float*)alloc((size_t)NN * HID * 4);   // t (aggregate out, f32)
  unsigned short* hl16 = (unsigned short*)alloc((size_t)NN * HID * 2);  // lin out, bf16
  float* dinv_all = (float*)alloc((size_t)NL * NN * 4);
  int*   cnt      = (int*)alloc((size_t)NN * 4);
  int*   offs     = (int*)alloc((size_t)(NN + 1) * 4);
  int*   cursor   = (int*)alloc((size_t)NN * 4);
  int*   bsum     = (int*)alloc((size_t)256 * 4);
  int*   csr_src  = (int*)alloc((size_t)EE * 4);
  int*   csr_eid  = (int*)alloc((size_t)EE * 4);
  float* csr_val  = (float*)alloc((size_t)NL * EE * 4);
  unsigned short* Wt    = (unsigned short*)alloc((size_t)8 * HID * HID * 2);
  unsigned short* tailW = (unsigned short*)alloc((size_t)622592 * 2);
  unsigned short* edgeW = (unsigned short*)alloc((size_t)256 * 32 * 2);
  int*   flag     = (int*)alloc(256);
  float* part     = (float*)alloc((size_t)GG * PCH * HID * 4);  // 1 MB pooling partials
  float* molf32   = (float*)alloc((size_t)GG * 256 * 4);
  float* m0       = (float*)alloc((size_t)GG * MH * 4);
  float* m1       = (float*)alloc((size_t)GG * MH * 4);
  float* cat      = (float*)alloc((size_t)GG * PIN * 4);
  float* p0       = (float*)alloc((size_t)GG * PH * 4);
  float* p1       = (float*)alloc((size_t)GG * PH * 4);

  hipMemsetAsync(cnt, 0, (size_t)NN * 4, stream);
  hipMemsetAsync(cursor, 0, (size_t)NN * 4, stream);
  hipMemsetAsync(molf32, 0, (size_t)GG * 256 * 4, stream);

  // dtype probe first — everything downstream branches on it
  probe_kernel<<<1, 64, 0, stream>>>((const unsigned short*)x, flag);

  // weight prep
  prep_weights<<<512, 256, 0, stream>>>(lin_W, gW, Wt, flag);
  prep_tail<<<(622592 + 255) / 256, 256, 0, stream>>>(mlpW0, mlpW1, mlpW2, mlpW3,
                                                      predW0, predW1, tailW, flag);
  prep_edge_w<<<32, 256, 0, stream>>>(mW1, edgeW, flag);

  // x -> f32
  {
    int n4 = NN * HID / 4;
    cvt_any<<<(n4 + 255) / 256, 256, 0, stream>>>(x, bufA, n4, flag);
  }
  // CSR build (3-phase parallel scan)
  count_kernel<<<(EE + 255) / 256, 256, 0, stream>>>(ei, cnt);
  scan_phase1<<<SCAN_B, 256, 0, stream>>>(cnt, bsum);
  scan_phase2<<<1, 256, 0, stream>>>(bsum, offs);
  scan_phase3<<<SCAN_B, 256, 0, stream>>>(cnt, bsum, offs);
  fill_kernel<<<(EE + 255) / 256, 256, 0, stream>>>(ei, offs, cursor, csr_src, csr_eid);
  // edge gates (MFMA, LDS-free, CSR order), degrees, scaling
  edge_mlp_mfma<<<(EE + 255) / 256, 256, 0, stream>>>(eattr, edgeW, mb1, mW2, mb2,
                                                      csr_eid, csr_val, flag);
  deg_kernel<<<(NN + 255) / 256, 256, 0, stream>>>(offs, csr_val, dinv_all);
  csr_scale_kernel<<<(EE + 255) / 256, 256, 0, stream>>>(csr_src, dinv_all, csr_val);

  // GCN layers: lin(h)->hl16(bf16); aggregate(hl16)->bufB; gcn(bufB)->h
  float* h = bufA;
  float* t = bufB;
  const int gemm_blocks = (NN + 63) / 64;  // 782
  for (int l = 0; l < NL; l++) {
    gemm_nodes_mfma<<<gemm_blocks, 256, 0, stream>>>(
        h, Wt + (size_t)l * HID * HID, nullptr, -1, nullptr, hl16, 0, flag);
    aggregate_kernel<<<NN, 128, 0, stream>>>(hl16, offs, csr_src,
                                             csr_val + (size_t)l * EE,
                                             dinv_all + (size_t)l * NN, cbias,
                                             (long)l * HID, t, flag);
    gemm_nodes_mfma<<<gemm_blocks, 256, 0, stream>>>(
        t, Wt + (size_t)(4 + l) * HID * HID, gb, (long)l * HID, h, nullptr, 1, flag);
  }

  // pooling -> cat[:, 0:128]  (2-phase)
  pool_partial<<<dim3(GG, PCH), 128, 0, stream>>>(h, batch, part);
  pool_combine<<<GG, 128, 0, stream>>>(part, batch, cat);

  // molecular MLP -> cat[:, 128:256]  (MFMA tail, K-padded weights)
  cvt_molf<<<(GG * 50 + 255) / 256, 256, 0, stream>>>(molf, molf32, flag);
  gemm_tail_mfma<<<dim3(4, 4), 256, 0, stream>>>(molf32, 256, tailW + 0,      256, mlpb0, m0, 256, 1, flag);
  gemm_tail_mfma<<<dim3(4, 4), 256, 0, stream>>>(m0,     256, tailW + 65536,  256, mlpb1, m1, 256, 1, flag);
  gemm_tail_mfma<<<dim3(4, 4), 256, 0, stream>>>(m1,     256, tailW + 131072, 256, mlpb2, m0, 256, 1, flag);
  gemm_tail_mfma<<<dim3(4, 2), 256, 0, stream>>>(m0,     256, tailW + 196608, 256, mlpb3, cat + MOUT, 256, 1, flag);

  // predictor
  gemm_tail_mfma<<<dim3(4, 8), 256, 0, stream>>>(cat, 256, tailW + 229376, 256, predb0, p0, 512, 1, flag);
  gemm_tail_mfma<<<dim3(4, 8), 256, 0, stream>>>(p0,  512, tailW + 360448, 512, predb1, p1, 512, 1, flag);
  final_kernel<<<GG, 64, 0, stream>>>(p1, outW, outb, d_out, flag);
}

// Round 12
// 723.875 us; speedup vs baseline: 1.2444x; 1.0110x over previous
//
#include <hip/hip_runtime.h>
#include <hip/hip_bf16.h>

// ---------------------------------------------------------------------------
// PDNConv GNN, MI355X round 12.
// Round-11: edge_mlp (CSR-ordered eattr gather) was latency/overfetch-bound:
// FETCH 37.5MB vs 21.6MB unique (64B lines for 32B rows), dep chain
// eid->gather->MFMA. Restructure:
//  - edge MLP runs in ORIGINAL edge order (coalesced eattr, no csr_eid),
//    writes w_all4[e]=float4{4 layer gates} (one 16B record/edge);
//  - new csr_gather permutes gates to CSR order via one float4 random load
//    per edge (9.6MB L2/L3-resident source);
//  - dinv stored interleaved float4 -> csr_scale does one float4 gather;
//  - epilogue shuffle reduce 64 -> 20 ops via reduce-scatter butterfly.
// Everything else identical to round 11.
// ---------------------------------------------------------------------------

#define NN 50000
#define EE 600000
#define GG 256
#define HID 128
#define EDIM 16
#define EHID 64
#define NL 4
#define MIN_F 200
#define MH 256
#define MOUT 128
#define PH 512
#define PIN 256
#define SCAN_B 196  // ceil(NN/256)
#define PCH 8       // pooling chunks per graph

typedef __hip_bfloat16 bf16;
typedef __attribute__((ext_vector_type(8))) short bf16x8;
typedef __attribute__((ext_vector_type(4))) float f32x4;

__device__ __forceinline__ float bfl(unsigned u) { return __uint_as_float(u << 16); }
__device__ __forceinline__ float bfh(unsigned u) { return __uint_as_float(u & 0xffff0000u); }
__device__ __forceinline__ float b2f(bf16 x) { return __bfloat162float(x); }
__device__ __forceinline__ float ldf(const void* p, long i, bool bf) {
  return bf ? __bfloat162float(((const bf16*)p)[i]) : ((const float*)p)[i];
}
__device__ __forceinline__ unsigned short f2bf_bits(float v) {
  bf16 h = __float2bfloat16(v);
  return *reinterpret_cast<unsigned short*>(&h);
}

// ---------------- dtype probe ------------------------------------------------
__global__ void probe_kernel(const unsigned short* __restrict__ xs, int* flag) {
  if (threadIdx.x == 0 && blockIdx.x == 0) {
    int sane = 0;
    for (int i = 0; i < 128; i++) {
      unsigned e = (xs[i] >> 7) & 0xFF;
      if (e >= 96 && e <= 159) sane++;
    }
    *flag = (sane >= 112) ? 1 : 0;  // 1 = bf16 inputs
  }
}

// ---------------- input -> f32 conversion (4 elems/thread) ------------------
__global__ __launch_bounds__(256) void cvt_any(const void* __restrict__ in,
                                               float* __restrict__ outp, int n4,
                                               const int* __restrict__ flag) {
  bool bf = *flag != 0;
  int i = blockIdx.x * 256 + threadIdx.x;
  if (i >= n4) return;
  float4 v;
  if (bf) {
    uint2 u = reinterpret_cast<const uint2*>(in)[i];
    v.x = bfl(u.x); v.y = bfh(u.x); v.z = bfl(u.y); v.w = bfh(u.y);
  } else {
    v = reinterpret_cast<const float4*>(in)[i];
  }
  reinterpret_cast<float4*>(outp)[i] = v;
}

// ---------------- mol_features [G,200] -> padded f32 [G,256] ----------------
__global__ __launch_bounds__(256) void cvt_molf(const void* __restrict__ in,
                                                float* __restrict__ outp,
                                                const int* __restrict__ flag) {
  bool bf = *flag != 0;
  int i = blockIdx.x * 256 + threadIdx.x;  // GG*50
  if (i >= GG * 50) return;
  int row = i / 50, c4 = (i % 50) * 4;
  float4 v;
  if (bf) {
    const unsigned short* p = (const unsigned short*)in + (size_t)row * MIN_F + c4;
    uint2 u = *reinterpret_cast<const uint2*>(p);
    v.x = bfl(u.x); v.y = bfh(u.x); v.z = bfl(u.y); v.w = bfh(u.y);
  } else {
    v = *reinterpret_cast<const float4*>((const float*)in + (size_t)row * MIN_F + c4);
  }
  *reinterpret_cast<float4*>(&outp[(size_t)row * 256 + c4]) = v;
}

// ---------------- weight prep: node GEMM weights -> bf16 Wt[n][k] -----------
__global__ __launch_bounds__(256) void prep_weights(const void* __restrict__ lin_W,
                                                    const void* __restrict__ gW,
                                                    unsigned short* __restrict__ Wt,
                                                    const int* __restrict__ flag) {
  bool bf = *flag != 0;
  int idx = blockIdx.x * 256 + threadIdx.x;  // 0 .. 8*16384-1
  if (idx >= 8 * 16384) return;
  int mat = idx >> 14;
  int rem = idx & 16383;
  int n = rem >> 7, k = rem & 127;
  const void* src = (mat < 4) ? lin_W : gW;
  long srcIdx = (long)(mat & 3) * 16384 + (long)k * 128 + n;
  Wt[idx] = f2bf_bits(ldf(src, srcIdx, bf));
}

// ---------------- weight prep: edge MLP W1 -> bf16 W1t[256 cols][32 K] ------
__global__ __launch_bounds__(256) void prep_edge_w(const void* __restrict__ mW1,
                                                   unsigned short* __restrict__ W1t,
                                                   const int* __restrict__ flag) {
  bool bf = *flag != 0;
  int idx = blockIdx.x * 256 + threadIdx.x;  // 256*32
  if (idx >= 256 * 32) return;
  int col = idx >> 5, k = idx & 31;
  float v = 0.f;
  if (k < EDIM) v = ldf(mW1, (long)(col >> 6) * (EDIM * EHID) + (long)k * EHID + (col & 63), bf);
  W1t[idx] = f2bf_bits(v);
}

// ---------------- weight prep: tail (MLP+predictor) -> bf16 [N][Kp], K-pad --
__global__ __launch_bounds__(256) void prep_tail(
    const void* __restrict__ mlpW0, const void* __restrict__ mlpW1,
    const void* __restrict__ mlpW2, const void* __restrict__ mlpW3,
    const void* __restrict__ predW0, const void* __restrict__ predW1,
    unsigned short* __restrict__ T, const int* __restrict__ flag) {
  bool bf = *flag != 0;
  int idx = blockIdx.x * 256 + threadIdx.x;
  const void* src; int N, Kp, Ksrc, off;
  if      (idx < 65536)  { src = mlpW0;  N = 256; Kp = 256; Ksrc = 200; off = 0; }
  else if (idx < 131072) { src = mlpW1;  N = 256; Kp = 256; Ksrc = 256; off = 65536; }
  else if (idx < 196608) { src = mlpW2;  N = 256; Kp = 256; Ksrc = 256; off = 131072; }
  else if (idx < 229376) { src = mlpW3;  N = 128; Kp = 256; Ksrc = 256; off = 196608; }
  else if (idx < 360448) { src = predW0; N = 512; Kp = 256; Ksrc = 256; off = 229376; }
  else if (idx < 622592) { src = predW1; N = 512; Kp = 512; Ksrc = 512; off = 360448; }
  else return;
  int rem = idx - off;
  int n = rem / Kp, k = rem % Kp;
  float v = (k < Ksrc) ? ldf(src, (long)k * N + n, bf) : 0.f;
  T[idx] = f2bf_bits(v);
}

// ---------------- CSR build: histogram / 3-phase scan / fill ----------------
__global__ __launch_bounds__(256) void count_kernel(const int* __restrict__ ei,
                                                    int* __restrict__ cnt) {
  int e = blockIdx.x * 256 + threadIdx.x;
  if (e >= EE) return;
  int c = ei[EE + e];
  c = min(max(c, 0), NN - 1);
  atomicAdd(&cnt[c], 1);
}

__global__ __launch_bounds__(256) void scan_phase1(const int* __restrict__ cnt,
                                                   int* __restrict__ bsum) {
  __shared__ int red[256];
  int tid = threadIdx.x;
  int i = blockIdx.x * 256 + tid;
  red[tid] = (i < NN) ? cnt[i] : 0;
  __syncthreads();
  for (int off = 128; off > 0; off >>= 1) {
    if (tid < off) red[tid] += red[tid + off];
    __syncthreads();
  }
  if (tid == 0) bsum[blockIdx.x] = red[0];
}

__global__ __launch_bounds__(256) void scan_phase2(int* __restrict__ bsum,
                                                   int* __restrict__ offs) {
  __shared__ int buf[256];
  int tid = threadIdx.x;
  int v = (tid < SCAN_B) ? bsum[tid] : 0;
  buf[tid] = v;
  __syncthreads();
  for (int off = 1; off < 256; off <<= 1) {
    int t = (tid >= off) ? buf[tid - off] : 0;
    __syncthreads();
    buf[tid] += t;
    __syncthreads();
  }
  if (tid < SCAN_B) bsum[tid] = buf[tid] - v;  // exclusive block offsets
  if (tid == 255) offs[NN] = buf[255];
}

__global__ __launch_bounds__(256) void scan_phase3(const int* __restrict__ cnt,
                                                   const int* __restrict__ bsum,
                                                   int* __restrict__ offs) {
  __shared__ int buf[256];
  int tid = threadIdx.x;
  int i = blockIdx.x * 256 + tid;
  int v = (i < NN) ? cnt[i] : 0;
  buf[tid] = v;
  __syncthreads();
  for (int off = 1; off < 256; off <<= 1) {
    int t = (tid >= off) ? buf[tid - off] : 0;
    __syncthreads();
    buf[tid] += t;
    __syncthreads();
  }
  if (i < NN) offs[i] = bsum[blockIdx.x] + buf[tid] - v;
}

__global__ __launch_bounds__(256) void fill_kernel(const int* __restrict__ ei,
                                                   const int* __restrict__ offs,
                                                   int* __restrict__ cursor,
                                                   int* __restrict__ csr_src,
                                                   int* __restrict__ csr_eid) {
  int e = blockIdx.x * 256 + threadIdx.x;
  if (e >= EE) return;
  int c = ei[EE + e];
  c = min(max(c, 0), NN - 1);
  int pos = offs[c] + atomicAdd(&cursor[c], 1);
  pos = min(max(pos, 0), EE - 1);
  csr_src[pos] = ei[e];
  csr_eid[pos] = e;
}

// ---------------- edge-gate MLP via MFMA: ORIGINAL edge order ---------------
// Coalesced eattr reads (no csr_eid), writes w_all4[e] = float4 of the 4
// layers' gates. Reduce-scatter butterfly: 20 shfl/fragment instead of 64.
__global__ __launch_bounds__(256) void edge_mlp_mfma(
    const void* __restrict__ eattr, const unsigned short* __restrict__ W1t,
    const void* __restrict__ mb1, const void* __restrict__ mW2,
    const void* __restrict__ mb2, float* __restrict__ w_all4,
    const int* __restrict__ flag) {
  bool bf = *flag != 0;
  int tid = threadIdx.x;
  int wave = tid >> 6, lane = tid & 63;
  int l15 = lane & 15, quad = lane >> 4;

  bf16x8 bfrag[16];
#pragma unroll
  for (int t = 0; t < 16; t++)
    bfrag[t] = *reinterpret_cast<const bf16x8*>(&W1t[(t * 16 + l15) * 32 + quad * 8]);

  float b1v[16], w2v[16];
#pragma unroll
  for (int t = 0; t < 16; t++) {
    int col = t * 16 + l15;
    b1v[t] = ldf(mb1, col, bf);
    w2v[t] = ldf(mW2, col, bf);
  }
  float b2v0 = ldf(mb2, 0, bf), b2v1 = ldf(mb2, 1, bf);
  float b2v2 = ldf(mb2, 2, bf), b2v3 = ldf(mb2, 3, bf);
  float b2 = b2v0;
  b2 = (l15 == 1) ? b2v1 : b2;
  b2 = (l15 == 2) ? b2v2 : b2;
  b2 = (l15 == 3) ? b2v3 : b2;
  bool o1 = (l15 & 1) != 0;
  bool o2 = (l15 & 2) != 0;

  int ebase = blockIdx.x * 256 + wave * 64;
#pragma unroll
  for (int f = 0; f < 4; f++) {
    int fbase = ebase + f * 16;
    if (fbase < EE) {  // EE%16==0 -> whole fragment in-bounds
      long erow = fbase + l15;  // ORIGINAL order: consecutive rows, coalesced
      bf16x8 a = (bf16x8){0, 0, 0, 0, 0, 0, 0, 0};
      if (quad < 2) {
        if (bf) {
          uint4 v = *reinterpret_cast<const uint4*>((const bf16*)eattr + erow * EDIM + quad * 8);
          a = *reinterpret_cast<bf16x8*>(&v);
        } else {
          const float4* p =
              reinterpret_cast<const float4*>((const float*)eattr + erow * EDIM + quad * 8);
          float4 v0 = p[0], v1 = p[1];
          a[0] = (short)f2bf_bits(v0.x); a[1] = (short)f2bf_bits(v0.y);
          a[2] = (short)f2bf_bits(v0.z); a[3] = (short)f2bf_bits(v0.w);
          a[4] = (short)f2bf_bits(v1.x); a[5] = (short)f2bf_bits(v1.y);
          a[6] = (short)f2bf_bits(v1.z); a[7] = (short)f2bf_bits(v1.w);
        }
      }
      float s00 = 0.f, s01 = 0.f, s02 = 0.f, s03 = 0.f;
      float s10 = 0.f, s11 = 0.f, s12 = 0.f, s13 = 0.f;
      float s20 = 0.f, s21 = 0.f, s22 = 0.f, s23 = 0.f;
      float s30 = 0.f, s31 = 0.f, s32 = 0.f, s33 = 0.f;
#define DO_T(T, S0, S1, S2, S3)                                               \
  {                                                                           \
    f32x4 acc = __builtin_amdgcn_mfma_f32_16x16x32_bf16(                      \
        a, bfrag[T], (f32x4){0.f, 0.f, 0.f, 0.f}, 0, 0, 0);                   \
    S0 += fmaxf(acc.x + b1v[T], 0.f) * w2v[T];                                \
    S1 += fmaxf(acc.y + b1v[T], 0.f) * w2v[T];                                \
    S2 += fmaxf(acc.z + b1v[T], 0.f) * w2v[T];                                \
    S3 += fmaxf(acc.w + b1v[T], 0.f) * w2v[T];                                \
  }
      DO_T(0,  s00, s01, s02, s03) DO_T(1,  s00, s01, s02, s03)
      DO_T(2,  s00, s01, s02, s03) DO_T(3,  s00, s01, s02, s03)
      DO_T(4,  s10, s11, s12, s13) DO_T(5,  s10, s11, s12, s13)
      DO_T(6,  s10, s11, s12, s13) DO_T(7,  s10, s11, s12, s13)
      DO_T(8,  s20, s21, s22, s23) DO_T(9,  s20, s21, s22, s23)
      DO_T(10, s20, s21, s22, s23) DO_T(11, s20, s21, s22, s23)
      DO_T(12, s30, s31, s32, s33) DO_T(13, s30, s31, s32, s33)
      DO_T(14, s30, s31, s32, s33) DO_T(15, s30, s31, s32, s33)
#undef DO_T
      // reduce-scatter butterfly over l15 (16 lanes); lane l15<4 ends with
      // the full sum for layer g=l15. Verified select/send pairing:
      // step m: keep my g-half, send partner's wanted half.
#define RS_STEP1(AR, S0R, S1R) \
  float AR = (o1 ? S1R : S0R) + __shfl_xor(o1 ? S0R : S1R, 1);
      RS_STEP1(a0, s00, s10)  // NOTE: pairs (g0,g1) by bit0
      RS_STEP1(a1, s01, s11)
      RS_STEP1(a2, s02, s12)
      RS_STEP1(a3, s03, s13)
      RS_STEP1(bb0, s20, s30)
      RS_STEP1(bb1, s21, s31)
      RS_STEP1(bb2, s22, s32)
      RS_STEP1(bb3, s23, s33)
#undef RS_STEP1
      float c0 = (o2 ? bb0 : a0) + __shfl_xor(o2 ? a0 : bb0, 2);
      float c1 = (o2 ? bb1 : a1) + __shfl_xor(o2 ? a1 : bb1, 2);
      float c2 = (o2 ? bb2 : a2) + __shfl_xor(o2 ? a2 : bb2, 2);
      float c3 = (o2 ? bb3 : a3) + __shfl_xor(o2 ? a3 : bb3, 2);
      c0 += __shfl_xor(c0, 4); c1 += __shfl_xor(c1, 4);
      c2 += __shfl_xor(c2, 4); c3 += __shfl_xor(c3, 4);
      c0 += __shfl_xor(c0, 8); c1 += __shfl_xor(c1, 8);
      c2 += __shfl_xor(c2, 8); c3 += __shfl_xor(c3, 8);
      // lane l15: holds layer g = l15&3 sums for rows r=0..3
      if (l15 < NL) {
        float g0 = 1.f / (1.f + __expf(-(c0 + b2)));
        float g1 = 1.f / (1.f + __expf(-(c1 + b2)));
        float g2 = 1.f / (1.f + __expf(-(c2 + b2)));
        float g3 = 1.f / (1.f + __expf(-(c3 + b2)));
        // w_all4[e][layer]: scalar stores, 4 consecutive lanes cover 16B
        w_all4[(size_t)(fbase + quad * 4 + 0) * 4 + l15] = g0;
        w_all4[(size_t)(fbase + quad * 4 + 1) * 4 + l15] = g1;
        w_all4[(size_t)(fbase + quad * 4 + 2) * 4 + l15] = g2;
        w_all4[(size_t)(fbase + quad * 4 + 3) * 4 + l15] = g3;
      }
    }
  }
}

// ---------------- gather gates into CSR order -------------------------------
__global__ __launch_bounds__(256) void csr_gather(const int* __restrict__ csr_eid,
                                                  const float* __restrict__ w_all4,
                                                  float* __restrict__ csr_val) {
  int k = blockIdx.x * 256 + threadIdx.x;
  if (k >= EE) return;
  int eid = csr_eid[k];
  eid = min(max(eid, 0), EE - 1);
  float4 w = reinterpret_cast<const float4*>(w_all4)[eid];
  csr_val[k] = w.x;
  csr_val[(size_t)EE + k] = w.y;
  csr_val[2 * (size_t)EE + k] = w.z;
  csr_val[3 * (size_t)EE + k] = w.w;
}

// ---------------- degree / dinv per layer (interleaved float4 out) ----------
__global__ __launch_bounds__(256) void deg_kernel(const int* __restrict__ offs,
                                                  const float* __restrict__ csr_val,
                                                  float* __restrict__ dinv4) {
  int n = blockIdx.x * 256 + threadIdx.x;
  if (n >= NN) return;
  int s = offs[n], e = offs[n + 1];
  float d0 = 1.f, d1 = 1.f, d2 = 1.f, d3 = 1.f;  // self-loop weight 1.0
  for (int k = s; k < e; k++) {
    d0 += csr_val[k];
    d1 += csr_val[EE + k];
    d2 += csr_val[2 * (size_t)EE + k];
    d3 += csr_val[3 * (size_t)EE + k];
  }
  float4 o;
  o.x = rsqrtf(d0); o.y = rsqrtf(d1); o.z = rsqrtf(d2); o.w = rsqrtf(d3);
  reinterpret_cast<float4*>(dinv4)[n] = o;
}

// csr_val[l][k] *= dinv_l[src_k]   (one float4 gather per edge)
__global__ __launch_bounds__(256) void csr_scale_kernel(const int* __restrict__ csr_src,
                                                        const float* __restrict__ dinv4,
                                                        float* __restrict__ csr_val) {
  int k = blockIdx.x * 256 + threadIdx.x;
  if (k >= EE) return;
  int s = csr_src[k];
  s = min(max(s, 0), NN - 1);
  float4 d = reinterpret_cast<const float4*>(dinv4)[s];
  csr_val[k] *= d.x;
  csr_val[(size_t)EE + k] *= d.y;
  csr_val[2 * (size_t)EE + k] *= d.z;
  csr_val[3 * (size_t)EE + k] *= d.w;
}

// ---------------- node GEMM via MFMA ----------------------------------------
__global__ __launch_bounds__(256) void gemm_nodes_mfma(
    const float* __restrict__ A, const unsigned short* __restrict__ Wt,
    const void* __restrict__ bias, long boff, float* __restrict__ outp,
    unsigned short* __restrict__ out16, int relu, const int* __restrict__ flag) {
  __shared__ alignas(16) unsigned short sA[64 * 136];
  __shared__ alignas(16) unsigned short sW[128 * 136];
  int tid = threadIdx.x;
  int rbase = blockIdx.x * 64;

#pragma unroll
  for (int p = 0; p < 8; p++) {
    int idx8 = p * 256 + tid;
    int n = idx8 >> 4, kc = idx8 & 15;
    uint4 v = reinterpret_cast<const uint4*>(Wt)[idx8];
    *reinterpret_cast<uint4*>(&sW[n * 136 + kc * 8]) = v;
  }
#pragma unroll
  for (int p = 0; p < 8; p++) {
    int idx = p * 1024 + tid * 4;
    int m = idx >> 7, k = idx & 127;
    int row = rbase + m;
    float4 v = make_float4(0.f, 0.f, 0.f, 0.f);
    if (row < NN) v = *reinterpret_cast<const float4*>(&A[(size_t)row * HID + k]);
    ushort4 b;
    b.x = f2bf_bits(v.x); b.y = f2bf_bits(v.y);
    b.z = f2bf_bits(v.z); b.w = f2bf_bits(v.w);
    *reinterpret_cast<ushort4*>(&sA[m * 136 + k]) = b;
  }
  __syncthreads();

  int wave = tid >> 6, lane = tid & 63;
  int l15 = lane & 15, quad = lane >> 4;
  int mstrip = wave * 16;

  f32x4 acc[8];
#pragma unroll
  for (int t = 0; t < 8; t++) acc[t] = (f32x4){0.f, 0.f, 0.f, 0.f};

#pragma unroll
  for (int ks = 0; ks < 4; ks++) {
    int k0 = ks * 32 + quad * 8;
    bf16x8 a = *reinterpret_cast<const bf16x8*>(&sA[(mstrip + l15) * 136 + k0]);
#pragma unroll
    for (int t = 0; t < 8; t++) {
      bf16x8 b = *reinterpret_cast<const bf16x8*>(&sW[(t * 16 + l15) * 136 + k0]);
      acc[t] = __builtin_amdgcn_mfma_f32_16x16x32_bf16(a, b, acc[t], 0, 0, 0);
    }
  }

  bool bf = *flag != 0;
#pragma unroll
  for (int t = 0; t < 8; t++) {
    int n = t * 16 + l15;
    float bv = (boff >= 0) ? ldf(bias, boff + n, bf) : 0.f;
#pragma unroll
    for (int r = 0; r < 4; r++) {
      int row = rbase + mstrip + quad * 4 + r;
      if (row < NN) {
        float o = acc[t][r] + bv;
        if (relu) o = fmaxf(o, 0.f);
        if (outp) outp[(size_t)row * HID + n] = o;
        if (out16) out16[(size_t)row * HID + n] = f2bf_bits(o);
      }
    }
  }
}

// ---------------- tail GEMM via MFMA ----------------------------------------
__global__ __launch_bounds__(256) void gemm_tail_mfma(
    const float* __restrict__ A, int lda, const unsigned short* __restrict__ Wt,
    int Kp, const void* __restrict__ bias, float* __restrict__ outp, int ldo,
    int relu, const int* __restrict__ flag) {
  __shared__ alignas(16) unsigned short sA[64 * 264];
  __shared__ alignas(16) unsigned short sW[64 * 264];
  int tid = threadIdx.x;
  int rbase = blockIdx.x * 64;
  int nbase = blockIdx.y * 64;
  int wave = tid >> 6, lane = tid & 63;
  int l15 = lane & 15, quad = lane >> 4;
  int mstrip = wave * 16;

  f32x4 acc[4];
#pragma unroll
  for (int t = 0; t < 4; t++) acc[t] = (f32x4){0.f, 0.f, 0.f, 0.f};

  for (int kc = 0; kc < Kp; kc += 256) {
#pragma unroll 4
    for (int p = 0; p < 16; p++) {
      int idx = p * 1024 + tid * 4;
      int m = idx >> 8, k = idx & 255;
      float4 v = *reinterpret_cast<const float4*>(&A[(size_t)(rbase + m) * lda + kc + k]);
      ushort4 b;
      b.x = f2bf_bits(v.x); b.y = f2bf_bits(v.y);
      b.z = f2bf_bits(v.z); b.w = f2bf_bits(v.w);
      *reinterpret_cast<ushort4*>(&sA[m * 264 + k]) = b;
    }
#pragma unroll 4
    for (int p = 0; p < 8; p++) {
      int idx8 = p * 256 + tid;
      int n = idx8 >> 5, kk = (idx8 & 31) * 8;
      uint4 v = *reinterpret_cast<const uint4*>(&Wt[(size_t)(nbase + n) * Kp + kc + kk]);
      *reinterpret_cast<uint4*>(&sW[n * 264 + kk]) = v;
    }
    __syncthreads();
#pragma unroll
    for (int ks = 0; ks < 8; ks++) {
      int k0 = ks * 32 + quad * 8;
      bf16x8 a = *reinterpret_cast<const bf16x8*>(&sA[(mstrip + l15) * 264 + k0]);
#pragma unroll
      for (int nt = 0; nt < 4; nt++) {
        bf16x8 b = *reinterpret_cast<const bf16x8*>(&sW[(nt * 16 + l15) * 264 + k0]);
        acc[nt] = __builtin_amdgcn_mfma_f32_16x16x32_bf16(a, b, acc[nt], 0, 0, 0);
      }
    }
    __syncthreads();
  }

  bool bf = *flag != 0;
#pragma unroll
  for (int nt = 0; nt < 4; nt++) {
    int col = nbase + nt * 16 + l15;
    float bv = ldf(bias, col, bf);
#pragma unroll
    for (int r = 0; r < 4; r++) {
      int row = rbase + mstrip + quad * 4 + r;
      float o = acc[nt][r] + bv;
      if (relu) o = fmaxf(o, 0.f);
      outp[(size_t)row * ldo + col] = o;
    }
  }
}

// ---------------- aggregation (bf16 gather, f32 accumulate) -----------------
__global__ __launch_bounds__(128) void aggregate_kernel(
    const unsigned short* __restrict__ hl16, const int* __restrict__ offs,
    const int* __restrict__ csr_src, const float* __restrict__ csr_val,
    const float* __restrict__ dinv4, int layer, const void* __restrict__ bias,
    long boff, float* __restrict__ outp, const int* __restrict__ flag) {
  bool bf = *flag != 0;
  int n = blockIdx.x;
  int c = threadIdx.x;
  __shared__ int s_src[128];
  __shared__ float s_val[128];
  int start = offs[n], end = offs[n + 1];
  float acc = 0.f;
  for (int base = start; base < end; base += 128) {
    int k = base + c;
    if (k < end) {
      s_src[c] = min(max(csr_src[k], 0), NN - 1);
      s_val[c] = csr_val[k];
    }
    __syncthreads();
    int m = min(128, end - base);
    for (int j = 0; j < m; j++)
      acc = fmaf(s_val[j], bfl((unsigned)hl16[(size_t)s_src[j] * HID + c]), acc);
    __syncthreads();
  }
  float dn = dinv4[(size_t)n * 4 + layer];
  float selfv = bfl((unsigned)hl16[(size_t)n * HID + c]);
  outp[(size_t)n * HID + c] = dn * acc + dn * dn * selfv + ldf(bias, boff + c, bf);
}

// ---------------- mean pool, 2-phase ----------------------------------------
__global__ __launch_bounds__(128) void pool_partial(const float* __restrict__ h,
                                                    const int* __restrict__ batch,
                                                    float* __restrict__ part) {
  int g = blockIdx.x, chunk = blockIdx.y, c = threadIdx.x;
  int lo = 0, hi = NN;
  while (lo < hi) { int mid = (lo + hi) >> 1; if (batch[mid] < g) lo = mid + 1; else hi = mid; }
  int start = lo;
  hi = NN;
  while (lo < hi) { int mid = (lo + hi) >> 1; if (batch[mid] < g + 1) lo = mid + 1; else hi = mid; }
  int end = lo;
  int len = end - start;
  int per = (len + PCH - 1) / PCH;
  int s = start + chunk * per;
  int e = min(s + per, end);
  float sum = 0.f;
  for (int n = s; n < e; n++) sum += h[(size_t)n * HID + c];
  part[((size_t)g * PCH + chunk) * HID + c] = sum;
}

__global__ __launch_bounds__(128) void pool_combine(const float* __restrict__ part,
                                                    const int* __restrict__ batch,
                                                    float* __restrict__ cat) {
  int g = blockIdx.x, c = threadIdx.x;
  int lo = 0, hi = NN;
  while (lo < hi) { int mid = (lo + hi) >> 1; if (batch[mid] < g) lo = mid + 1; else hi = mid; }
  int start = lo;
  hi = NN;
  while (lo < hi) { int mid = (lo + hi) >> 1; if (batch[mid] < g + 1) lo = mid + 1; else hi = mid; }
  int end = lo;
  float s = 0.f;
#pragma unroll
  for (int k = 0; k < PCH; k++) s += part[((size_t)g * PCH + k) * HID + c];
  float cntf = (float)(end - start);
  cat[(size_t)g * PIN + c] = s / fmaxf(cntf, 1.f);
}

// ---------------- final [G,512] @ [512,1] + b -> out ------------------------
__global__ __launch_bounds__(64) void final_kernel(const float* __restrict__ A,
                                                   const void* __restrict__ W,
                                                   const void* __restrict__ b,
                                                   void* __restrict__ outp,
                                                   const int* __restrict__ flag) {
  bool bf = *flag != 0;
  int g = blockIdx.x, lane = threadIdx.x;
  float s = 0.f;
  for (int k = lane; k < PH; k += 64) s = fmaf(A[(size_t)g * PH + k], ldf(W, k, bf), s);
#pragma unroll
  for (int off = 32; off > 0; off >>= 1) s += __shfl_down(s, off);
  if (lane == 0) {
    float r = s + ldf(b, 0, bf);
    if (bf) ((bf16*)outp)[g] = __float2bfloat16(r);
    else    ((float*)outp)[g] = r;
  }
}

// ---------------------------------------------------------------------------
extern "C" void kernel_launch(void* const* d_in, const int* in_sizes, int n_in,
                              void* d_out, int out_size, void* d_ws, size_t ws_size,
                              hipStream_t stream) {
  const void* x      = d_in[0];
  const int*  ei     = (const int*)d_in[1];
  const void* eattr  = d_in[2];
  const int*  batch  = (const int*)d_in[3];
  const void* molf   = d_in[4];
  const void* lin_W  = d_in[5];
  const void* mW1    = d_in[6];
  const void* mb1    = d_in[7];
  const void* mW2    = d_in[8];
  const void* mb2    = d_in[9];
  const void* cbias  = d_in[10];
  const void* gW     = d_in[11];
  const void* gb     = d_in[12];
  const void* mlpW0  = d_in[13];
  const void* mlpb0  = d_in[14];
  const void* mlpW1  = d_in[15];
  const void* mlpb1  = d_in[16];
  const void* mlpW2  = d_in[17];
  const void* mlpb2  = d_in[18];
  const void* mlpW3  = d_in[19];
  const void* mlpb3  = d_in[20];
  const void* predW0 = d_in[21];
  const void* predb0 = d_in[22];
  const void* predW1 = d_in[23];
  const void* predb1 = d_in[24];
  const void* outW   = d_in[25];
  const void* outb   = d_in[26];

  char* base = (char*)d_ws;
  size_t off = 0;
  auto alloc = [&](size_t bytes) -> char* {
    char* p = base + off;
    off = (off + bytes + 255) & ~(size_t)255;
    return p;
  };
  float* bufA     = (float*)alloc((size_t)NN * HID * 4);   // h (layer state, f32)
  float* bufB     = (float*)alloc((size_t)NN * HID * 4);   // t (aggregate out, f32)
  unsigned short* hl16 = (unsigned short*)alloc((size_t)NN * HID * 2);  // lin out, bf16
  float* dinv4    = (float*)alloc((size_t)NN * 4 * 4);     // interleaved
  int*   cnt      = (int*)alloc((size_t)NN * 4);
  int*   offs     = (int*)alloc((size_t)(NN + 1) * 4);
  int*   cursor   = (int*)alloc((size_t)NN * 4);
  int*   bsum     = (int*)alloc((size_t)256 * 4);
  int*   csr_src  = (int*)alloc((size_t)EE * 4);
  int*   csr_eid  = (int*)alloc((size_t)EE * 4);
  float* csr_val  = (float*)alloc((size_t)NL * EE * 4);
  float* w_all4   = (float*)alloc((size_t)EE * 4 * 4);     // gates, orig order
  unsigned short* Wt    = (unsigned short*)alloc((size_t)8 * HID * HID * 2);
  unsigned short* tailW = (unsigned short*)alloc((size_t)622592 * 2);
  unsigned short* edgeW = (unsigned short*)alloc((size_t)256 * 32 * 2);
  int*   flag     = (int*)alloc(256);
  float* part     = (float*)alloc((size_t)GG * PCH * HID * 4);
  float* molf32   = (float*)alloc((size_t)GG * 256 * 4);
  float* m0       = (float*)alloc((size_t)GG * MH * 4);
  float* m1       = (float*)alloc((size_t)GG * MH * 4);
  float* cat      = (float*)alloc((size_t)GG * PIN * 4);
  float* p0       = (float*)alloc((size_t)GG * PH * 4);
  float* p1       = (float*)alloc((size_t)GG * PH * 4);

  hipMemsetAsync(cnt, 0, (size_t)NN * 4, stream);
  hipMemsetAsync(cursor, 0, (size_t)NN * 4, stream);
  hipMemsetAsync(molf32, 0, (size_t)GG * 256 * 4, stream);

  // dtype probe first — everything downstream branches on it
  probe_kernel<<<1, 64, 0, stream>>>((const unsigned short*)x, flag);

  // weight prep
  prep_weights<<<512, 256, 0, stream>>>(lin_W, gW, Wt, flag);
  prep_tail<<<(622592 + 255) / 256, 256, 0, stream>>>(mlpW0, mlpW1, mlpW2, mlpW3,
                                                      predW0, predW1, tailW, flag);
  prep_edge_w<<<32, 256, 0, stream>>>(mW1, edgeW, flag);

  // x -> f32
  {
    int n4 = NN * HID / 4;
    cvt_any<<<(n4 + 255) / 256, 256, 0, stream>>>(x, bufA, n4, flag);
  }
  // edge gates (MFMA, ORIGINAL order, coalesced) — independent of CSR build
  edge_mlp_mfma<<<(EE + 255) / 256, 256, 0, stream>>>(eattr, edgeW, mb1, mW2, mb2,
                                                      w_all4, flag);
  // CSR build (3-phase parallel scan)
  count_kernel<<<(EE + 255) / 256, 256, 0, stream>>>(ei, cnt);
  scan_phase1<<<SCAN_B, 256, 0, stream>>>(cnt, bsum);
  scan_phase2<<<1, 256, 0, stream>>>(bsum, offs);
  scan_phase3<<<SCAN_B, 256, 0, stream>>>(cnt, bsum, offs);
  fill_kernel<<<(EE + 255) / 256, 256, 0, stream>>>(ei, offs, cursor, csr_src, csr_eid);
  // permute gates to CSR order, degrees, scaling
  csr_gather<<<(EE + 255) / 256, 256, 0, stream>>>(csr_eid, w_all4, csr_val);
  deg_kernel<<<(NN + 255) / 256, 256, 0, stream>>>(offs, csr_val, dinv4);
  csr_scale_kernel<<<(EE + 255) / 256, 256, 0, stream>>>(csr_src, dinv4, csr_val);

  // GCN layers: lin(h)->hl16(bf16); aggregate(hl16)->bufB; gcn(bufB)->h
  float* h = bufA;
  float* t = bufB;
  const int gemm_blocks = (NN + 63) / 64;  // 782
  for (int l = 0; l < NL; l++) {
    gemm_nodes_mfma<<<gemm_blocks, 256, 0, stream>>>(
        h, Wt + (size_t)l * HID * HID, nullptr, -1, nullptr, hl16, 0, flag);
    aggregate_kernel<<<NN, 128, 0, stream>>>(hl16, offs, csr_src,
                                             csr_val + (size_t)l * EE, dinv4, l,
                                             cbias, (long)l * HID, t, flag);
    gemm_nodes_mfma<<<gemm_blocks, 256, 0, stream>>>(
        t, Wt + (size_t)(4 + l) * HID * HID, gb, (long)l * HID, h, nullptr, 1, flag);
  }

  // pooling -> cat[:, 0:128]  (2-phase)
  pool_partial<<<dim3(GG, PCH), 128, 0, stream>>>(h, batch, part);
  pool_combine<<<GG, 128, 0, stream>>>(part, batch, cat);

  // molecular MLP -> cat[:, 128:256]  (MFMA tail, K-padded weights)
  cvt_molf<<<(GG * 50 + 255) / 256, 256, 0, stream>>>(molf, molf32, flag);
  gemm_tail_mfma<<<dim3(4, 4), 256, 0, stream>>>(molf32, 256, tailW + 0,      256, mlpb0, m0, 256, 1, flag);
  gemm_tail_mfma<<<dim3(4, 4), 256, 0, stream>>>(m0,     256, tailW + 65536,  256, mlpb1, m1, 256, 1, flag);
  gemm_tail_mfma<<<dim3(4, 4), 256, 0, stream>>>(m1,     256, tailW + 131072, 256, mlpb2, m0, 256, 1, flag);
  gemm_tail_mfma<<<dim3(4, 2), 256, 0, stream>>>(m0,     256, tailW + 196608, 256, mlpb3, cat + MOUT, 256, 1, flag);

  // predictor
  gemm_tail_mfma<<<dim3(4, 8), 256, 0, stream>>>(cat, 256, tailW + 229376, 256, predb0, p0, 512, 1, flag);
  gemm_tail_mfma<<<dim3(4, 8), 256, 0, stream>>>(p0,  512, tailW + 360448, 512, predb1, p1, 512, 1, flag);
  final_kernel<<<GG, 64, 0, stream>>>(p1, outW, outb, d_out, flag);
}

// Round 13
// 687.878 us; speedup vs baseline: 1.3096x; 1.0523x over previous
//
#include <hip/hip_runtime.h>
#include <hip/hip_bf16.h>

// ---------------------------------------------------------------------------
// PDNConv GNN, MI355X round 13.
// Round-12: layer loop (aggregate x4 @45us + gemm x8) dominates; t/h round-
// trip HBM as f32 though every GEMM input is bf16-rounded at staging anyway.
// Change: node state bf16 end-to-end (h16/t16/hl16):
//  - gemm_nodes_bf16: bf16 in (pure uint4 staging, no convert) / bf16 out;
//  - aggregate writes bf16; pool reads bf16; cvt emits bf16 (copy for bf in).
// Saves ~205MB HBM traffic across the 4 layers. Everything else = round 12.
// ---------------------------------------------------------------------------

#define NN 50000
#define EE 600000
#define GG 256
#define HID 128
#define EDIM 16
#define EHID 64
#define NL 4
#define MIN_F 200
#define MH 256
#define MOUT 128
#define PH 512
#define PIN 256
#define SCAN_B 196  // ceil(NN/256)
#define PCH 8       // pooling chunks per graph

typedef __hip_bfloat16 bf16;
typedef __attribute__((ext_vector_type(8))) short bf16x8;
typedef __attribute__((ext_vector_type(4))) float f32x4;

__device__ __forceinline__ float bfl(unsigned u) { return __uint_as_float(u << 16); }
__device__ __forceinline__ float bfh(unsigned u) { return __uint_as_float(u & 0xffff0000u); }
__device__ __forceinline__ float b2f(bf16 x) { return __bfloat162float(x); }
__device__ __forceinline__ float ldf(const void* p, long i, bool bf) {
  return bf ? __bfloat162float(((const bf16*)p)[i]) : ((const float*)p)[i];
}
__device__ __forceinline__ unsigned short f2bf_bits(float v) {
  bf16 h = __float2bfloat16(v);
  return *reinterpret_cast<unsigned short*>(&h);
}

// ---------------- dtype probe ------------------------------------------------
__global__ void probe_kernel(const unsigned short* __restrict__ xs, int* flag) {
  if (threadIdx.x == 0 && blockIdx.x == 0) {
    int sane = 0;
    for (int i = 0; i < 128; i++) {
      unsigned e = (xs[i] >> 7) & 0xFF;
      if (e >= 96 && e <= 159) sane++;
    }
    *flag = (sane >= 112) ? 1 : 0;  // 1 = bf16 inputs
  }
}

// ---------------- input -> bf16 conversion (8 elems/thread) -----------------
__global__ __launch_bounds__(256) void cvt_to_bf16(const void* __restrict__ in,
                                                   unsigned short* __restrict__ outp,
                                                   int n8, const int* __restrict__ flag) {
  bool bf = *flag != 0;
  int i = blockIdx.x * 256 + threadIdx.x;
  if (i >= n8) return;
  if (bf) {
    reinterpret_cast<uint4*>(outp)[i] = reinterpret_cast<const uint4*>(in)[i];
  } else {
    const float4* p = reinterpret_cast<const float4*>(in) + (size_t)i * 2;
    float4 v0 = p[0], v1 = p[1];
    ushort4 a, b;
    a.x = f2bf_bits(v0.x); a.y = f2bf_bits(v0.y);
    a.z = f2bf_bits(v0.z); a.w = f2bf_bits(v0.w);
    b.x = f2bf_bits(v1.x); b.y = f2bf_bits(v1.y);
    b.z = f2bf_bits(v1.z); b.w = f2bf_bits(v1.w);
    reinterpret_cast<ushort4*>(outp)[i * 2] = a;
    reinterpret_cast<ushort4*>(outp)[i * 2 + 1] = b;
  }
}

// ---------------- mol_features [G,200] -> padded f32 [G,256] ----------------
__global__ __launch_bounds__(256) void cvt_molf(const void* __restrict__ in,
                                                float* __restrict__ outp,
                                                const int* __restrict__ flag) {
  bool bf = *flag != 0;
  int i = blockIdx.x * 256 + threadIdx.x;  // GG*50
  if (i >= GG * 50) return;
  int row = i / 50, c4 = (i % 50) * 4;
  float4 v;
  if (bf) {
    const unsigned short* p = (const unsigned short*)in + (size_t)row * MIN_F + c4;
    uint2 u = *reinterpret_cast<const uint2*>(p);
    v.x = bfl(u.x); v.y = bfh(u.x); v.z = bfl(u.y); v.w = bfh(u.y);
  } else {
    v = *reinterpret_cast<const float4*>((const float*)in + (size_t)row * MIN_F + c4);
  }
  *reinterpret_cast<float4*>(&outp[(size_t)row * 256 + c4]) = v;
}

// ---------------- weight prep: node GEMM weights -> bf16 Wt[n][k] -----------
__global__ __launch_bounds__(256) void prep_weights(const void* __restrict__ lin_W,
                                                    const void* __restrict__ gW,
                                                    unsigned short* __restrict__ Wt,
                                                    const int* __restrict__ flag) {
  bool bf = *flag != 0;
  int idx = blockIdx.x * 256 + threadIdx.x;  // 0 .. 8*16384-1
  if (idx >= 8 * 16384) return;
  int mat = idx >> 14;
  int rem = idx & 16383;
  int n = rem >> 7, k = rem & 127;
  const void* src = (mat < 4) ? lin_W : gW;
  long srcIdx = (long)(mat & 3) * 16384 + (long)k * 128 + n;
  Wt[idx] = f2bf_bits(ldf(src, srcIdx, bf));
}

// ---------------- weight prep: edge MLP W1 -> bf16 W1t[256 cols][32 K] ------
__global__ __launch_bounds__(256) void prep_edge_w(const void* __restrict__ mW1,
                                                   unsigned short* __restrict__ W1t,
                                                   const int* __restrict__ flag) {
  bool bf = *flag != 0;
  int idx = blockIdx.x * 256 + threadIdx.x;  // 256*32
  if (idx >= 256 * 32) return;
  int col = idx >> 5, k = idx & 31;
  float v = 0.f;
  if (k < EDIM) v = ldf(mW1, (long)(col >> 6) * (EDIM * EHID) + (long)k * EHID + (col & 63), bf);
  W1t[idx] = f2bf_bits(v);
}

// ---------------- weight prep: tail (MLP+predictor) -> bf16 [N][Kp], K-pad --
__global__ __launch_bounds__(256) void prep_tail(
    const void* __restrict__ mlpW0, const void* __restrict__ mlpW1,
    const void* __restrict__ mlpW2, const void* __restrict__ mlpW3,
    const void* __restrict__ predW0, const void* __restrict__ predW1,
    unsigned short* __restrict__ T, const int* __restrict__ flag) {
  bool bf = *flag != 0;
  int idx = blockIdx.x * 256 + threadIdx.x;
  const void* src; int N, Kp, Ksrc, off;
  if      (idx < 65536)  { src = mlpW0;  N = 256; Kp = 256; Ksrc = 200; off = 0; }
  else if (idx < 131072) { src = mlpW1;  N = 256; Kp = 256; Ksrc = 256; off = 65536; }
  else if (idx < 196608) { src = mlpW2;  N = 256; Kp = 256; Ksrc = 256; off = 131072; }
  else if (idx < 229376) { src = mlpW3;  N = 128; Kp = 256; Ksrc = 256; off = 196608; }
  else if (idx < 360448) { src = predW0; N = 512; Kp = 256; Ksrc = 256; off = 229376; }
  else if (idx < 622592) { src = predW1; N = 512; Kp = 512; Ksrc = 512; off = 360448; }
  else return;
  int rem = idx - off;
  int n = rem / Kp, k = rem % Kp;
  float v = (k < Ksrc) ? ldf(src, (long)k * N + n, bf) : 0.f;
  T[idx] = f2bf_bits(v);
}

// ---------------- CSR build: histogram / 3-phase scan / fill ----------------
__global__ __launch_bounds__(256) void count_kernel(const int* __restrict__ ei,
                                                    int* __restrict__ cnt) {
  int e = blockIdx.x * 256 + threadIdx.x;
  if (e >= EE) return;
  int c = ei[EE + e];
  c = min(max(c, 0), NN - 1);
  atomicAdd(&cnt[c], 1);
}

__global__ __launch_bounds__(256) void scan_phase1(const int* __restrict__ cnt,
                                                   int* __restrict__ bsum) {
  __shared__ int red[256];
  int tid = threadIdx.x;
  int i = blockIdx.x * 256 + tid;
  red[tid] = (i < NN) ? cnt[i] : 0;
  __syncthreads();
  for (int off = 128; off > 0; off >>= 1) {
    if (tid < off) red[tid] += red[tid + off];
    __syncthreads();
  }
  if (tid == 0) bsum[blockIdx.x] = red[0];
}

__global__ __launch_bounds__(256) void scan_phase2(int* __restrict__ bsum,
                                                   int* __restrict__ offs) {
  __shared__ int buf[256];
  int tid = threadIdx.x;
  int v = (tid < SCAN_B) ? bsum[tid] : 0;
  buf[tid] = v;
  __syncthreads();
  for (int off = 1; off < 256; off <<= 1) {
    int t = (tid >= off) ? buf[tid - off] : 0;
    __syncthreads();
    buf[tid] += t;
    __syncthreads();
  }
  if (tid < SCAN_B) bsum[tid] = buf[tid] - v;  // exclusive block offsets
  if (tid == 255) offs[NN] = buf[255];
}

__global__ __launch_bounds__(256) void scan_phase3(const int* __restrict__ cnt,
                                                   const int* __restrict__ bsum,
                                                   int* __restrict__ offs) {
  __shared__ int buf[256];
  int tid = threadIdx.x;
  int i = blockIdx.x * 256 + tid;
  int v = (i < NN) ? cnt[i] : 0;
  buf[tid] = v;
  __syncthreads();
  for (int off = 1; off < 256; off <<= 1) {
    int t = (tid >= off) ? buf[tid - off] : 0;
    __syncthreads();
    buf[tid] += t;
    __syncthreads();
  }
  if (i < NN) offs[i] = bsum[blockIdx.x] + buf[tid] - v;
}

__global__ __launch_bounds__(256) void fill_kernel(const int* __restrict__ ei,
                                                   const int* __restrict__ offs,
                                                   int* __restrict__ cursor,
                                                   int* __restrict__ csr_src,
                                                   int* __restrict__ csr_eid) {
  int e = blockIdx.x * 256 + threadIdx.x;
  if (e >= EE) return;
  int c = ei[EE + e];
  c = min(max(c, 0), NN - 1);
  int pos = offs[c] + atomicAdd(&cursor[c], 1);
  pos = min(max(pos, 0), EE - 1);
  csr_src[pos] = ei[e];
  csr_eid[pos] = e;
}

// ---------------- edge-gate MLP via MFMA: ORIGINAL edge order ---------------
__global__ __launch_bounds__(256) void edge_mlp_mfma(
    const void* __restrict__ eattr, const unsigned short* __restrict__ W1t,
    const void* __restrict__ mb1, const void* __restrict__ mW2,
    const void* __restrict__ mb2, float* __restrict__ w_all4,
    const int* __restrict__ flag) {
  bool bf = *flag != 0;
  int tid = threadIdx.x;
  int wave = tid >> 6, lane = tid & 63;
  int l15 = lane & 15, quad = lane >> 4;

  bf16x8 bfrag[16];
#pragma unroll
  for (int t = 0; t < 16; t++)
    bfrag[t] = *reinterpret_cast<const bf16x8*>(&W1t[(t * 16 + l15) * 32 + quad * 8]);

  float b1v[16], w2v[16];
#pragma unroll
  for (int t = 0; t < 16; t++) {
    int col = t * 16 + l15;
    b1v[t] = ldf(mb1, col, bf);
    w2v[t] = ldf(mW2, col, bf);
  }
  float b2v0 = ldf(mb2, 0, bf), b2v1 = ldf(mb2, 1, bf);
  float b2v2 = ldf(mb2, 2, bf), b2v3 = ldf(mb2, 3, bf);
  float b2 = b2v0;
  b2 = (l15 == 1) ? b2v1 : b2;
  b2 = (l15 == 2) ? b2v2 : b2;
  b2 = (l15 == 3) ? b2v3 : b2;
  bool o1 = (l15 & 1) != 0;
  bool o2 = (l15 & 2) != 0;

  int ebase = blockIdx.x * 256 + wave * 64;
#pragma unroll
  for (int f = 0; f < 4; f++) {
    int fbase = ebase + f * 16;
    if (fbase < EE) {  // EE%16==0 -> whole fragment in-bounds
      long erow = fbase + l15;
      bf16x8 a = (bf16x8){0, 0, 0, 0, 0, 0, 0, 0};
      if (quad < 2) {
        if (bf) {
          uint4 v = *reinterpret_cast<const uint4*>((const bf16*)eattr + erow * EDIM + quad * 8);
          a = *reinterpret_cast<bf16x8*>(&v);
        } else {
          const float4* p =
              reinterpret_cast<const float4*>((const float*)eattr + erow * EDIM + quad * 8);
          float4 v0 = p[0], v1 = p[1];
          a[0] = (short)f2bf_bits(v0.x); a[1] = (short)f2bf_bits(v0.y);
          a[2] = (short)f2bf_bits(v0.z); a[3] = (short)f2bf_bits(v0.w);
          a[4] = (short)f2bf_bits(v1.x); a[5] = (short)f2bf_bits(v1.y);
          a[6] = (short)f2bf_bits(v1.z); a[7] = (short)f2bf_bits(v1.w);
        }
      }
      float s00 = 0.f, s01 = 0.f, s02 = 0.f, s03 = 0.f;
      float s10 = 0.f, s11 = 0.f, s12 = 0.f, s13 = 0.f;
      float s20 = 0.f, s21 = 0.f, s22 = 0.f, s23 = 0.f;
      float s30 = 0.f, s31 = 0.f, s32 = 0.f, s33 = 0.f;
#define DO_T(T, S0, S1, S2, S3)                                               \
  {                                                                           \
    f32x4 acc = __builtin_amdgcn_mfma_f32_16x16x32_bf16(                      \
        a, bfrag[T], (f32x4){0.f, 0.f, 0.f, 0.f}, 0, 0, 0);                   \
    S0 += fmaxf(acc.x + b1v[T], 0.f) * w2v[T];                                \
    S1 += fmaxf(acc.y + b1v[T], 0.f) * w2v[T];                                \
    S2 += fmaxf(acc.z + b1v[T], 0.f) * w2v[T];                                \
    S3 += fmaxf(acc.w + b1v[T], 0.f) * w2v[T];                                \
  }
      DO_T(0,  s00, s01, s02, s03) DO_T(1,  s00, s01, s02, s03)
      DO_T(2,  s00, s01, s02, s03) DO_T(3,  s00, s01, s02, s03)
      DO_T(4,  s10, s11, s12, s13) DO_T(5,  s10, s11, s12, s13)
      DO_T(6,  s10, s11, s12, s13) DO_T(7,  s10, s11, s12, s13)
      DO_T(8,  s20, s21, s22, s23) DO_T(9,  s20, s21, s22, s23)
      DO_T(10, s20, s21, s22, s23) DO_T(11, s20, s21, s22, s23)
      DO_T(12, s30, s31, s32, s33) DO_T(13, s30, s31, s32, s33)
      DO_T(14, s30, s31, s32, s33) DO_T(15, s30, s31, s32, s33)
#undef DO_T
#define RS_STEP1(AR, S0R, S1R) \
  float AR = (o1 ? S1R : S0R) + __shfl_xor(o1 ? S0R : S1R, 1);
      RS_STEP1(a0, s00, s10)
      RS_STEP1(a1, s01, s11)
      RS_STEP1(a2, s02, s12)
      RS_STEP1(a3, s03, s13)
      RS_STEP1(bb0, s20, s30)
      RS_STEP1(bb1, s21, s31)
      RS_STEP1(bb2, s22, s32)
      RS_STEP1(bb3, s23, s33)
#undef RS_STEP1
      float c0 = (o2 ? bb0 : a0) + __shfl_xor(o2 ? a0 : bb0, 2);
      float c1 = (o2 ? bb1 : a1) + __shfl_xor(o2 ? a1 : bb1, 2);
      float c2 = (o2 ? bb2 : a2) + __shfl_xor(o2 ? a2 : bb2, 2);
      float c3 = (o2 ? bb3 : a3) + __shfl_xor(o2 ? a3 : bb3, 2);
      c0 += __shfl_xor(c0, 4); c1 += __shfl_xor(c1, 4);
      c2 += __shfl_xor(c2, 4); c3 += __shfl_xor(c3, 4);
      c0 += __shfl_xor(c0, 8); c1 += __shfl_xor(c1, 8);
      c2 += __shfl_xor(c2, 8); c3 += __shfl_xor(c3, 8);
      if (l15 < NL) {
        float g0 = 1.f / (1.f + __expf(-(c0 + b2)));
        float g1 = 1.f / (1.f + __expf(-(c1 + b2)));
        float g2 = 1.f / (1.f + __expf(-(c2 + b2)));
        float g3 = 1.f / (1.f + __expf(-(c3 + b2)));
        w_all4[(size_t)(fbase + quad * 4 + 0) * 4 + l15] = g0;
        w_all4[(size_t)(fbase + quad * 4 + 1) * 4 + l15] = g1;
        w_all4[(size_t)(fbase + quad * 4 + 2) * 4 + l15] = g2;
        w_all4[(size_t)(fbase + quad * 4 + 3) * 4 + l15] = g3;
      }
    }
  }
}

// ---------------- gather gates into CSR order -------------------------------
__global__ __launch_bounds__(256) void csr_gather(const int* __restrict__ csr_eid,
                                                  const float* __restrict__ w_all4,
                                                  float* __restrict__ csr_val) {
  int k = blockIdx.x * 256 + threadIdx.x;
  if (k >= EE) return;
  int eid = csr_eid[k];
  eid = min(max(eid, 0), EE - 1);
  float4 w = reinterpret_cast<const float4*>(w_all4)[eid];
  csr_val[k] = w.x;
  csr_val[(size_t)EE + k] = w.y;
  csr_val[2 * (size_t)EE + k] = w.z;
  csr_val[3 * (size_t)EE + k] = w.w;
}

// ---------------- degree / dinv per layer (interleaved float4 out) ----------
__global__ __launch_bounds__(256) void deg_kernel(const int* __restrict__ offs,
                                                  const float* __restrict__ csr_val,
                                                  float* __restrict__ dinv4) {
  int n = blockIdx.x * 256 + threadIdx.x;
  if (n >= NN) return;
  int s = offs[n], e = offs[n + 1];
  float d0 = 1.f, d1 = 1.f, d2 = 1.f, d3 = 1.f;  // self-loop weight 1.0
  for (int k = s; k < e; k++) {
    d0 += csr_val[k];
    d1 += csr_val[EE + k];
    d2 += csr_val[2 * (size_t)EE + k];
    d3 += csr_val[3 * (size_t)EE + k];
  }
  float4 o;
  o.x = rsqrtf(d0); o.y = rsqrtf(d1); o.z = rsqrtf(d2); o.w = rsqrtf(d3);
  reinterpret_cast<float4*>(dinv4)[n] = o;
}

// csr_val[l][k] *= dinv_l[src_k]   (one float4 gather per edge)
__global__ __launch_bounds__(256) void csr_scale_kernel(const int* __restrict__ csr_src,
                                                        const float* __restrict__ dinv4,
                                                        float* __restrict__ csr_val) {
  int k = blockIdx.x * 256 + threadIdx.x;
  if (k >= EE) return;
  int s = csr_src[k];
  s = min(max(s, 0), NN - 1);
  float4 d = reinterpret_cast<const float4*>(dinv4)[s];
  csr_val[k] *= d.x;
  csr_val[(size_t)EE + k] *= d.y;
  csr_val[2 * (size_t)EE + k] *= d.z;
  csr_val[3 * (size_t)EE + k] *= d.w;
}

// ---------------- node GEMM via MFMA: bf16 in, bf16 out ---------------------
// out16[N,128] = A16[N,128] @ Wt[n][k] (+bias)(+relu)
__global__ __launch_bounds__(256) void gemm_nodes_bf16(
    const unsigned short* __restrict__ A16, const unsigned short* __restrict__ Wt,
    const void* __restrict__ bias, long boff, unsigned short* __restrict__ out16,
    int relu, const int* __restrict__ flag) {
  __shared__ alignas(16) unsigned short sA[64 * 136];
  __shared__ alignas(16) unsigned short sW[128 * 136];
  int tid = threadIdx.x;
  int rbase = blockIdx.x * 64;

#pragma unroll
  for (int p = 0; p < 8; p++) {
    int idx8 = p * 256 + tid;
    int n = idx8 >> 4, kc = idx8 & 15;
    uint4 v = reinterpret_cast<const uint4*>(Wt)[idx8];
    *reinterpret_cast<uint4*>(&sW[n * 136 + kc * 8]) = v;
  }
  // A staging: pure uint4 copies (8 bf16/thread x 4 iters)
#pragma unroll
  for (int p = 0; p < 4; p++) {
    int idx8 = p * 256 + tid;
    int m = idx8 >> 4, kc = idx8 & 15;
    int row = rbase + m;
    uint4 v = make_uint4(0u, 0u, 0u, 0u);
    if (row < NN)
      v = *reinterpret_cast<const uint4*>(&A16[(size_t)row * HID + kc * 8]);
    *reinterpret_cast<uint4*>(&sA[m * 136 + kc * 8]) = v;
  }
  __syncthreads();

  int wave = tid >> 6, lane = tid & 63;
  int l15 = lane & 15, quad = lane >> 4;
  int mstrip = wave * 16;

  f32x4 acc[8];
#pragma unroll
  for (int t = 0; t < 8; t++) acc[t] = (f32x4){0.f, 0.f, 0.f, 0.f};

#pragma unroll
  for (int ks = 0; ks < 4; ks++) {
    int k0 = ks * 32 + quad * 8;
    bf16x8 a = *reinterpret_cast<const bf16x8*>(&sA[(mstrip + l15) * 136 + k0]);
#pragma unroll
    for (int t = 0; t < 8; t++) {
      bf16x8 b = *reinterpret_cast<const bf16x8*>(&sW[(t * 16 + l15) * 136 + k0]);
      acc[t] = __builtin_amdgcn_mfma_f32_16x16x32_bf16(a, b, acc[t], 0, 0, 0);
    }
  }

  bool bf = *flag != 0;
#pragma unroll
  for (int t = 0; t < 8; t++) {
    int n = t * 16 + l15;
    float bv = (boff >= 0) ? ldf(bias, boff + n, bf) : 0.f;
#pragma unroll
    for (int r = 0; r < 4; r++) {
      int row = rbase + mstrip + quad * 4 + r;
      if (row < NN) {
        float o = acc[t][r] + bv;
        if (relu) o = fmaxf(o, 0.f);
        out16[(size_t)row * HID + n] = f2bf_bits(o);
      }
    }
  }
}

// ---------------- tail GEMM via MFMA ----------------------------------------
__global__ __launch_bounds__(256) void gemm_tail_mfma(
    const float* __restrict__ A, int lda, const unsigned short* __restrict__ Wt,
    int Kp, const void* __restrict__ bias, float* __restrict__ outp, int ldo,
    int relu, const int* __restrict__ flag) {
  __shared__ alignas(16) unsigned short sA[64 * 264];
  __shared__ alignas(16) unsigned short sW[64 * 264];
  int tid = threadIdx.x;
  int rbase = blockIdx.x * 64;
  int nbase = blockIdx.y * 64;
  int wave = tid >> 6, lane = tid & 63;
  int l15 = lane & 15, quad = lane >> 4;
  int mstrip = wave * 16;

  f32x4 acc[4];
#pragma unroll
  for (int t = 0; t < 4; t++) acc[t] = (f32x4){0.f, 0.f, 0.f, 0.f};

  for (int kc = 0; kc < Kp; kc += 256) {
#pragma unroll 4
    for (int p = 0; p < 16; p++) {
      int idx = p * 1024 + tid * 4;
      int m = idx >> 8, k = idx & 255;
      float4 v = *reinterpret_cast<const float4*>(&A[(size_t)(rbase + m) * lda + kc + k]);
      ushort4 b;
      b.x = f2bf_bits(v.x); b.y = f2bf_bits(v.y);
      b.z = f2bf_bits(v.z); b.w = f2bf_bits(v.w);
      *reinterpret_cast<ushort4*>(&sA[m * 264 + k]) = b;
    }
#pragma unroll 4
    for (int p = 0; p < 8; p++) {
      int idx8 = p * 256 + tid;
      int n = idx8 >> 5, kk = (idx8 & 31) * 8;
      uint4 v = *reinterpret_cast<const uint4*>(&Wt[(size_t)(nbase + n) * Kp + kc + kk]);
      *reinterpret_cast<uint4*>(&sW[n * 264 + kk]) = v;
    }
    __syncthreads();
#pragma unroll
    for (int ks = 0; ks < 8; ks++) {
      int k0 = ks * 32 + quad * 8;
      bf16x8 a = *reinterpret_cast<const bf16x8*>(&sA[(mstrip + l15) * 264 + k0]);
#pragma unroll
      for (int nt = 0; nt < 4; nt++) {
        bf16x8 b = *reinterpret_cast<const bf16x8*>(&sW[(nt * 16 + l15) * 264 + k0]);
        acc[nt] = __builtin_amdgcn_mfma_f32_16x16x32_bf16(a, b, acc[nt], 0, 0, 0);
      }
    }
    __syncthreads();
  }

  bool bf = *flag != 0;
#pragma unroll
  for (int nt = 0; nt < 4; nt++) {
    int col = nbase + nt * 16 + l15;
    float bv = ldf(bias, col, bf);
#pragma unroll
    for (int r = 0; r < 4; r++) {
      int row = rbase + mstrip + quad * 4 + r;
      float o = acc[nt][r] + bv;
      if (relu) o = fmaxf(o, 0.f);
      outp[(size_t)row * ldo + col] = o;
    }
  }
}

// ---------------- aggregation (bf16 gather, f32 accumulate, bf16 out) -------
__global__ __launch_bounds__(128) void aggregate_kernel(
    const unsigned short* __restrict__ hl16, const int* __restrict__ offs,
    const int* __restrict__ csr_src, const float* __restrict__ csr_val,
    const float* __restrict__ dinv4, int layer, const void* __restrict__ bias,
    long boff, unsigned short* __restrict__ out16, const int* __restrict__ flag) {
  bool bf = *flag != 0;
  int n = blockIdx.x;
  int c = threadIdx.x;
  __shared__ int s_src[128];
  __shared__ float s_val[128];
  int start = offs[n], end = offs[n + 1];
  float acc = 0.f;
  for (int base = start; base < end; base += 128) {
    int k = base + c;
    if (k < end) {
      s_src[c] = min(max(csr_src[k], 0), NN - 1);
      s_val[c] = csr_val[k];
    }
    __syncthreads();
    int m = min(128, end - base);
    for (int j = 0; j < m; j++)
      acc = fmaf(s_val[j], bfl((unsigned)hl16[(size_t)s_src[j] * HID + c]), acc);
    __syncthreads();
  }
  float dn = dinv4[(size_t)n * 4 + layer];
  float selfv = bfl((unsigned)hl16[(size_t)n * HID + c]);
  out16[(size_t)n * HID + c] =
      f2bf_bits(dn * acc + dn * dn * selfv + ldf(bias, boff + c, bf));
}

// ---------------- mean pool, 2-phase (bf16 input) ---------------------------
__global__ __launch_bounds__(128) void pool_partial(const unsigned short* __restrict__ h16,
                                                    const int* __restrict__ batch,
                                                    float* __restrict__ part) {
  int g = blockIdx.x, chunk = blockIdx.y, c = threadIdx.x;
  int lo = 0, hi = NN;
  while (lo < hi) { int mid = (lo + hi) >> 1; if (batch[mid] < g) lo = mid + 1; else hi = mid; }
  int start = lo;
  hi = NN;
  while (lo < hi) { int mid = (lo + hi) >> 1; if (batch[mid] < g + 1) lo = mid + 1; else hi = mid; }
  int end = lo;
  int len = end - start;
  int per = (len + PCH - 1) / PCH;
  int s = start + chunk * per;
  int e = min(s + per, end);
  float sum = 0.f;
  for (int n = s; n < e; n++) sum += bfl((unsigned)h16[(size_t)n * HID + c]);
  part[((size_t)g * PCH + chunk) * HID + c] = sum;
}

__global__ __launch_bounds__(128) void pool_combine(const float* __restrict__ part,
                                                    const int* __restrict__ batch,
                                                    float* __restrict__ cat) {
  int g = blockIdx.x, c = threadIdx.x;
  int lo = 0, hi = NN;
  while (lo < hi) { int mid = (lo + hi) >> 1; if (batch[mid] < g) lo = mid + 1; else hi = mid; }
  int start = lo;
  hi = NN;
  while (lo < hi) { int mid = (lo + hi) >> 1; if (batch[mid] < g + 1) lo = mid + 1; else hi = mid; }
  int end = lo;
  float s = 0.f;
#pragma unroll
  for (int k = 0; k < PCH; k++) s += part[((size_t)g * PCH + k) * HID + c];
  float cntf = (float)(end - start);
  cat[(size_t)g * PIN + c] = s / fmaxf(cntf, 1.f);
}

// ---------------- final [G,512] @ [512,1] + b -> out ------------------------
__global__ __launch_bounds__(64) void final_kernel(const float* __restrict__ A,
                                                   const void* __restrict__ W,
                                                   const void* __restrict__ b,
                                                   void* __restrict__ outp,
                                                   const int* __restrict__ flag) {
  bool bf = *flag != 0;
  int g = blockIdx.x, lane = threadIdx.x;
  float s = 0.f;
  for (int k = lane; k < PH; k += 64) s = fmaf(A[(size_t)g * PH + k], ldf(W, k, bf), s);
#pragma unroll
  for (int off = 32; off > 0; off >>= 1) s += __shfl_down(s, off);
  if (lane == 0) {
    float r = s + ldf(b, 0, bf);
    if (bf) ((bf16*)outp)[g] = __float2bfloat16(r);
    else    ((float*)outp)[g] = r;
  }
}

// ---------------------------------------------------------------------------
extern "C" void kernel_launch(void* const* d_in, const int* in_sizes, int n_in,
                              void* d_out, int out_size, void* d_ws, size_t ws_size,
                              hipStream_t stream) {
  const void* x      = d_in[0];
  const int*  ei     = (const int*)d_in[1];
  const void* eattr  = d_in[2];
  const int*  batch  = (const int*)d_in[3];
  const void* molf   = d_in[4];
  const void* lin_W  = d_in[5];
  const void* mW1    = d_in[6];
  const void* mb1    = d_in[7];
  const void* mW2    = d_in[8];
  const void* mb2    = d_in[9];
  const void* cbias  = d_in[10];
  const void* gW     = d_in[11];
  const void* gb     = d_in[12];
  const void* mlpW0  = d_in[13];
  const void* mlpb0  = d_in[14];
  const void* mlpW1  = d_in[15];
  const void* mlpb1  = d_in[16];
  const void* mlpW2  = d_in[17];
  const void* mlpb2  = d_in[18];
  const void* mlpW3  = d_in[19];
  const void* mlpb3  = d_in[20];
  const void* predW0 = d_in[21];
  const void* predb0 = d_in[22];
  const void* predW1 = d_in[23];
  const void* predb1 = d_in[24];
  const void* outW   = d_in[25];
  const void* outb   = d_in[26];

  char* base = (char*)d_ws;
  size_t off = 0;
  auto alloc = [&](size_t bytes) -> char* {
    char* p = base + off;
    off = (off + bytes + 255) & ~(size_t)255;
    return p;
  };
  unsigned short* h16  = (unsigned short*)alloc((size_t)NN * HID * 2);  // layer state
  unsigned short* t16  = (unsigned short*)alloc((size_t)NN * HID * 2);  // aggregate out
  unsigned short* hl16 = (unsigned short*)alloc((size_t)NN * HID * 2);  // lin out
  float* dinv4    = (float*)alloc((size_t)NN * 4 * 4);
  int*   cnt      = (int*)alloc((size_t)NN * 4);
  int*   offs     = (int*)alloc((size_t)(NN + 1) * 4);
  int*   cursor   = (int*)alloc((size_t)NN * 4);
  int*   bsum     = (int*)alloc((size_t)256 * 4);
  int*   csr_src  = (int*)alloc((size_t)EE * 4);
  int*   csr_eid  = (int*)alloc((size_t)EE * 4);
  float* csr_val  = (float*)alloc((size_t)NL * EE * 4);
  float* w_all4   = (float*)alloc((size_t)EE * 4 * 4);
  unsigned short* Wt    = (unsigned short*)alloc((size_t)8 * HID * HID * 2);
  unsigned short* tailW = (unsigned short*)alloc((size_t)622592 * 2);
  unsigned short* edgeW = (unsigned short*)alloc((size_t)256 * 32 * 2);
  int*   flag     = (int*)alloc(256);
  float* part     = (float*)alloc((size_t)GG * PCH * HID * 4);
  float* molf32   = (float*)alloc((size_t)GG * 256 * 4);
  float* m0       = (float*)alloc((size_t)GG * MH * 4);
  float* m1       = (float*)alloc((size_t)GG * MH * 4);
  float* cat      = (float*)alloc((size_t)GG * PIN * 4);
  float* p0       = (float*)alloc((size_t)GG * PH * 4);
  float* p1       = (float*)alloc((size_t)GG * PH * 4);

  hipMemsetAsync(cnt, 0, (size_t)NN * 4, stream);
  hipMemsetAsync(cursor, 0, (size_t)NN * 4, stream);
  hipMemsetAsync(molf32, 0, (size_t)GG * 256 * 4, stream);

  // dtype probe first — everything downstream branches on it
  probe_kernel<<<1, 64, 0, stream>>>((const unsigned short*)x, flag);

  // weight prep
  prep_weights<<<512, 256, 0, stream>>>(lin_W, gW, Wt, flag);
  prep_tail<<<(622592 + 255) / 256, 256, 0, stream>>>(mlpW0, mlpW1, mlpW2, mlpW3,
                                                      predW0, predW1, tailW, flag);
  prep_edge_w<<<32, 256, 0, stream>>>(mW1, edgeW, flag);

  // x -> bf16 layer state
  {
    int n8 = NN * HID / 8;
    cvt_to_bf16<<<(n8 + 255) / 256, 256, 0, stream>>>(x, h16, n8, flag);
  }
  // edge gates (MFMA, ORIGINAL order, coalesced) — independent of CSR build
  edge_mlp_mfma<<<(EE + 255) / 256, 256, 0, stream>>>(eattr, edgeW, mb1, mW2, mb2,
                                                      w_all4, flag);
  // CSR build (3-phase parallel scan)
  count_kernel<<<(EE + 255) / 256, 256, 0, stream>>>(ei, cnt);
  scan_phase1<<<SCAN_B, 256, 0, stream>>>(cnt, bsum);
  scan_phase2<<<1, 256, 0, stream>>>(bsum, offs);
  scan_phase3<<<SCAN_B, 256, 0, stream>>>(cnt, bsum, offs);
  fill_kernel<<<(EE + 255) / 256, 256, 0, stream>>>(ei, offs, cursor, csr_src, csr_eid);
  // permute gates to CSR order, degrees, scaling
  csr_gather<<<(EE + 255) / 256, 256, 0, stream>>>(csr_eid, w_all4, csr_val);
  deg_kernel<<<(NN + 255) / 256, 256, 0, stream>>>(offs, csr_val, dinv4);
  csr_scale_kernel<<<(EE + 255) / 256, 256, 0, stream>>>(csr_src, dinv4, csr_val);

  // GCN layers: lin(h16)->hl16; aggregate(hl16)->t16; gcn(t16)->h16
  const int gemm_blocks = (NN + 63) / 64;  // 782
  for (int l = 0; l < NL; l++) {
    gemm_nodes_bf16<<<gemm_blocks, 256, 0, stream>>>(
        h16, Wt + (size_t)l * HID * HID, nullptr, -1, hl16, 0, flag);
    aggregate_kernel<<<NN, 128, 0, stream>>>(hl16, offs, csr_src,
                                             csr_val + (size_t)l * EE, dinv4, l,
                                             cbias, (long)l * HID, t16, flag);
    gemm_nodes_bf16<<<gemm_blocks, 256, 0, stream>>>(
        t16, Wt + (size_t)(4 + l) * HID * HID, gb, (long)l * HID, h16, 1, flag);
  }

  // pooling -> cat[:, 0:128]  (2-phase, bf16 input)
  pool_partial<<<dim3(GG, PCH), 128, 0, stream>>>(h16, batch, part);
  pool_combine<<<GG, 128, 0, stream>>>(part, batch, cat);

  // molecular MLP -> cat[:, 128:256]  (MFMA tail, K-padded weights)
  cvt_molf<<<(GG * 50 + 255) / 256, 256, 0, stream>>>(molf, molf32, flag);
  gemm_tail_mfma<<<dim3(4, 4), 256, 0, stream>>>(molf32, 256, tailW + 0,      256, mlpb0, m0, 256, 1, flag);
  gemm_tail_mfma<<<dim3(4, 4), 256, 0, stream>>>(m0,     256, tailW + 65536,  256, mlpb1, m1, 256, 1, flag);
  gemm_tail_mfma<<<dim3(4, 4), 256, 0, stream>>>(m1,     256, tailW + 131072, 256, mlpb2, m0, 256, 1, flag);
  gemm_tail_mfma<<<dim3(4, 2), 256, 0, stream>>>(m0,     256, tailW + 196608, 256, mlpb3, cat + MOUT, 256, 1, flag);

  // predictor
  gemm_tail_mfma<<<dim3(4, 8), 256, 0, stream>>>(cat, 256, tailW + 229376, 256, predb0, p0, 512, 1, flag);
  gemm_tail_mfma<<<dim3(4, 8), 256, 0, stream>>>(p0,  512, tailW + 360448, 512, predb1, p1, 512, 1, flag);
  final_kernel<<<GG, 64, 0, stream>>>(p1, outW, outb, d_out, flag);
}

// Round 14
// 673.707 us; speedup vs baseline: 1.3371x; 1.0210x over previous
//
#include <hip/hip_runtime.h>
#include <hip/hip_bf16.h>

// ---------------------------------------------------------------------------
// PDNConv GNN, MI355X round 14.
// Round-13 profile: edge_mlp 46us (VALU/setup-bound: ~50-load setup per wave
// amortized over only 4 fragments) and fill 45us (WRITE 66MB: two scattered
// 4B stores/edge each dirtying a 64B line). Fixes:
//  - fill writes one int2{src,eid} to csr_se (1 line/edge, slots share lines);
//    csr_gather/csr_scale/aggregate read .x/.y from the combined stream.
//  - edge_mlp: 8 fragments per wave (128 edges), grid halved, unroll 1.
// Everything else identical to round 13.
// ---------------------------------------------------------------------------

#define NN 50000
#define EE 600000
#define GG 256
#define HID 128
#define EDIM 16
#define EHID 64
#define NL 4
#define MIN_F 200
#define MH 256
#define MOUT 128
#define PH 512
#define PIN 256
#define SCAN_B 196  // ceil(NN/256)
#define PCH 8       // pooling chunks per graph

typedef __hip_bfloat16 bf16;
typedef __attribute__((ext_vector_type(8))) short bf16x8;
typedef __attribute__((ext_vector_type(4))) float f32x4;

__device__ __forceinline__ float bfl(unsigned u) { return __uint_as_float(u << 16); }
__device__ __forceinline__ float bfh(unsigned u) { return __uint_as_float(u & 0xffff0000u); }
__device__ __forceinline__ float b2f(bf16 x) { return __bfloat162float(x); }
__device__ __forceinline__ float ldf(const void* p, long i, bool bf) {
  return bf ? __bfloat162float(((const bf16*)p)[i]) : ((const float*)p)[i];
}
__device__ __forceinline__ unsigned short f2bf_bits(float v) {
  bf16 h = __float2bfloat16(v);
  return *reinterpret_cast<unsigned short*>(&h);
}

// ---------------- dtype probe ------------------------------------------------
__global__ void probe_kernel(const unsigned short* __restrict__ xs, int* flag) {
  if (threadIdx.x == 0 && blockIdx.x == 0) {
    int sane = 0;
    for (int i = 0; i < 128; i++) {
      unsigned e = (xs[i] >> 7) & 0xFF;
      if (e >= 96 && e <= 159) sane++;
    }
    *flag = (sane >= 112) ? 1 : 0;  // 1 = bf16 inputs
  }
}

// ---------------- input -> bf16 conversion (8 elems/thread) -----------------
__global__ __launch_bounds__(256) void cvt_to_bf16(const void* __restrict__ in,
                                                   unsigned short* __restrict__ outp,
                                                   int n8, const int* __restrict__ flag) {
  bool bf = *flag != 0;
  int i = blockIdx.x * 256 + threadIdx.x;
  if (i >= n8) return;
  if (bf) {
    reinterpret_cast<uint4*>(outp)[i] = reinterpret_cast<const uint4*>(in)[i];
  } else {
    const float4* p = reinterpret_cast<const float4*>(in) + (size_t)i * 2;
    float4 v0 = p[0], v1 = p[1];
    ushort4 a, b;
    a.x = f2bf_bits(v0.x); a.y = f2bf_bits(v0.y);
    a.z = f2bf_bits(v0.z); a.w = f2bf_bits(v0.w);
    b.x = f2bf_bits(v1.x); b.y = f2bf_bits(v1.y);
    b.z = f2bf_bits(v1.z); b.w = f2bf_bits(v1.w);
    reinterpret_cast<ushort4*>(outp)[i * 2] = a;
    reinterpret_cast<ushort4*>(outp)[i * 2 + 1] = b;
  }
}

// ---------------- mol_features [G,200] -> padded f32 [G,256] ----------------
__global__ __launch_bounds__(256) void cvt_molf(const void* __restrict__ in,
                                                float* __restrict__ outp,
                                                const int* __restrict__ flag) {
  bool bf = *flag != 0;
  int i = blockIdx.x * 256 + threadIdx.x;  // GG*50
  if (i >= GG * 50) return;
  int row = i / 50, c4 = (i % 50) * 4;
  float4 v;
  if (bf) {
    const unsigned short* p = (const unsigned short*)in + (size_t)row * MIN_F + c4;
    uint2 u = *reinterpret_cast<const uint2*>(p);
    v.x = bfl(u.x); v.y = bfh(u.x); v.z = bfl(u.y); v.w = bfh(u.y);
  } else {
    v = *reinterpret_cast<const float4*>((const float*)in + (size_t)row * MIN_F + c4);
  }
  *reinterpret_cast<float4*>(&outp[(size_t)row * 256 + c4]) = v;
}

// ---------------- weight prep: node GEMM weights -> bf16 Wt[n][k] -----------
__global__ __launch_bounds__(256) void prep_weights(const void* __restrict__ lin_W,
                                                    const void* __restrict__ gW,
                                                    unsigned short* __restrict__ Wt,
                                                    const int* __restrict__ flag) {
  bool bf = *flag != 0;
  int idx = blockIdx.x * 256 + threadIdx.x;  // 0 .. 8*16384-1
  if (idx >= 8 * 16384) return;
  int mat = idx >> 14;
  int rem = idx & 16383;
  int n = rem >> 7, k = rem & 127;
  const void* src = (mat < 4) ? lin_W : gW;
  long srcIdx = (long)(mat & 3) * 16384 + (long)k * 128 + n;
  Wt[idx] = f2bf_bits(ldf(src, srcIdx, bf));
}

// ---------------- weight prep: edge MLP W1 -> bf16 W1t[256 cols][32 K] ------
__global__ __launch_bounds__(256) void prep_edge_w(const void* __restrict__ mW1,
                                                   unsigned short* __restrict__ W1t,
                                                   const int* __restrict__ flag) {
  bool bf = *flag != 0;
  int idx = blockIdx.x * 256 + threadIdx.x;  // 256*32
  if (idx >= 256 * 32) return;
  int col = idx >> 5, k = idx & 31;
  float v = 0.f;
  if (k < EDIM) v = ldf(mW1, (long)(col >> 6) * (EDIM * EHID) + (long)k * EHID + (col & 63), bf);
  W1t[idx] = f2bf_bits(v);
}

// ---------------- weight prep: tail (MLP+predictor) -> bf16 [N][Kp], K-pad --
__global__ __launch_bounds__(256) void prep_tail(
    const void* __restrict__ mlpW0, const void* __restrict__ mlpW1,
    const void* __restrict__ mlpW2, const void* __restrict__ mlpW3,
    const void* __restrict__ predW0, const void* __restrict__ predW1,
    unsigned short* __restrict__ T, const int* __restrict__ flag) {
  bool bf = *flag != 0;
  int idx = blockIdx.x * 256 + threadIdx.x;
  const void* src; int N, Kp, Ksrc, off;
  if      (idx < 65536)  { src = mlpW0;  N = 256; Kp = 256; Ksrc = 200; off = 0; }
  else if (idx < 131072) { src = mlpW1;  N = 256; Kp = 256; Ksrc = 256; off = 65536; }
  else if (idx < 196608) { src = mlpW2;  N = 256; Kp = 256; Ksrc = 256; off = 131072; }
  else if (idx < 229376) { src = mlpW3;  N = 128; Kp = 256; Ksrc = 256; off = 196608; }
  else if (idx < 360448) { src = predW0; N = 512; Kp = 256; Ksrc = 256; off = 229376; }
  else if (idx < 622592) { src = predW1; N = 512; Kp = 512; Ksrc = 512; off = 360448; }
  else return;
  int rem = idx - off;
  int n = rem / Kp, k = rem % Kp;
  float v = (k < Ksrc) ? ldf(src, (long)k * N + n, bf) : 0.f;
  T[idx] = f2bf_bits(v);
}

// ---------------- CSR build: histogram / 3-phase scan / fill ----------------
__global__ __launch_bounds__(256) void count_kernel(const int* __restrict__ ei,
                                                    int* __restrict__ cnt) {
  int e = blockIdx.x * 256 + threadIdx.x;
  if (e >= EE) return;
  int c = ei[EE + e];
  c = min(max(c, 0), NN - 1);
  atomicAdd(&cnt[c], 1);
}

__global__ __launch_bounds__(256) void scan_phase1(const int* __restrict__ cnt,
                                                   int* __restrict__ bsum) {
  __shared__ int red[256];
  int tid = threadIdx.x;
  int i = blockIdx.x * 256 + tid;
  red[tid] = (i < NN) ? cnt[i] : 0;
  __syncthreads();
  for (int off = 128; off > 0; off >>= 1) {
    if (tid < off) red[tid] += red[tid + off];
    __syncthreads();
  }
  if (tid == 0) bsum[blockIdx.x] = red[0];
}

__global__ __launch_bounds__(256) void scan_phase2(int* __restrict__ bsum,
                                                   int* __restrict__ offs) {
  __shared__ int buf[256];
  int tid = threadIdx.x;
  int v = (tid < SCAN_B) ? bsum[tid] : 0;
  buf[tid] = v;
  __syncthreads();
  for (int off = 1; off < 256; off <<= 1) {
    int t = (tid >= off) ? buf[tid - off] : 0;
    __syncthreads();
    buf[tid] += t;
    __syncthreads();
  }
  if (tid < SCAN_B) bsum[tid] = buf[tid] - v;  // exclusive block offsets
  if (tid == 255) offs[NN] = buf[255];
}

__global__ __launch_bounds__(256) void scan_phase3(const int* __restrict__ cnt,
                                                   const int* __restrict__ bsum,
                                                   int* __restrict__ offs) {
  __shared__ int buf[256];
  int tid = threadIdx.x;
  int i = blockIdx.x * 256 + tid;
  int v = (i < NN) ? cnt[i] : 0;
  buf[tid] = v;
  __syncthreads();
  for (int off = 1; off < 256; off <<= 1) {
    int t = (tid >= off) ? buf[tid - off] : 0;
    __syncthreads();
    buf[tid] += t;
    __syncthreads();
  }
  if (i < NN) offs[i] = bsum[blockIdx.x] + buf[tid] - v;
}

// fill: one int2{src,eid} store per edge -> one dirtied line, slots share lines
__global__ __launch_bounds__(256) void fill_kernel(const int* __restrict__ ei,
                                                   const int* __restrict__ offs,
                                                   int* __restrict__ cursor,
                                                   int2* __restrict__ csr_se) {
  int e = blockIdx.x * 256 + threadIdx.x;
  if (e >= EE) return;
  int c = ei[EE + e];
  c = min(max(c, 0), NN - 1);
  int pos = offs[c] + atomicAdd(&cursor[c], 1);
  pos = min(max(pos, 0), EE - 1);
  csr_se[pos] = make_int2(ei[e], e);
}

// ---------------- edge-gate MLP via MFMA: ORIGINAL edge order ---------------
// 8 fragments (128 edges) per wave — setup amortized 2x vs round 13.
__global__ __launch_bounds__(256) void edge_mlp_mfma(
    const void* __restrict__ eattr, const unsigned short* __restrict__ W1t,
    const void* __restrict__ mb1, const void* __restrict__ mW2,
    const void* __restrict__ mb2, float* __restrict__ w_all4,
    const int* __restrict__ flag) {
  bool bf = *flag != 0;
  int tid = threadIdx.x;
  int wave = tid >> 6, lane = tid & 63;
  int l15 = lane & 15, quad = lane >> 4;

  bf16x8 bfrag[16];
#pragma unroll
  for (int t = 0; t < 16; t++)
    bfrag[t] = *reinterpret_cast<const bf16x8*>(&W1t[(t * 16 + l15) * 32 + quad * 8]);

  float b1v[16], w2v[16];
#pragma unroll
  for (int t = 0; t < 16; t++) {
    int col = t * 16 + l15;
    b1v[t] = ldf(mb1, col, bf);
    w2v[t] = ldf(mW2, col, bf);
  }
  float b2v0 = ldf(mb2, 0, bf), b2v1 = ldf(mb2, 1, bf);
  float b2v2 = ldf(mb2, 2, bf), b2v3 = ldf(mb2, 3, bf);
  float b2 = b2v0;
  b2 = (l15 == 1) ? b2v1 : b2;
  b2 = (l15 == 2) ? b2v2 : b2;
  b2 = (l15 == 3) ? b2v3 : b2;
  bool o1 = (l15 & 1) != 0;
  bool o2 = (l15 & 2) != 0;

  int ebase = blockIdx.x * 512 + wave * 128;
#pragma unroll 1
  for (int f = 0; f < 8; f++) {
    int fbase = ebase + f * 16;
    if (fbase < EE) {  // EE%16==0 -> whole fragment in-bounds
      long erow = fbase + l15;
      bf16x8 a = (bf16x8){0, 0, 0, 0, 0, 0, 0, 0};
      if (quad < 2) {
        if (bf) {
          uint4 v = *reinterpret_cast<const uint4*>((const bf16*)eattr + erow * EDIM + quad * 8);
          a = *reinterpret_cast<bf16x8*>(&v);
        } else {
          const float4* p =
              reinterpret_cast<const float4*>((const float*)eattr + erow * EDIM + quad * 8);
          float4 v0 = p[0], v1 = p[1];
          a[0] = (short)f2bf_bits(v0.x); a[1] = (short)f2bf_bits(v0.y);
          a[2] = (short)f2bf_bits(v0.z); a[3] = (short)f2bf_bits(v0.w);
          a[4] = (short)f2bf_bits(v1.x); a[5] = (short)f2bf_bits(v1.y);
          a[6] = (short)f2bf_bits(v1.z); a[7] = (short)f2bf_bits(v1.w);
        }
      }
      float s00 = 0.f, s01 = 0.f, s02 = 0.f, s03 = 0.f;
      float s10 = 0.f, s11 = 0.f, s12 = 0.f, s13 = 0.f;
      float s20 = 0.f, s21 = 0.f, s22 = 0.f, s23 = 0.f;
      float s30 = 0.f, s31 = 0.f, s32 = 0.f, s33 = 0.f;
#define DO_T(T, S0, S1, S2, S3)                                               \
  {                                                                           \
    f32x4 acc = __builtin_amdgcn_mfma_f32_16x16x32_bf16(                      \
        a, bfrag[T], (f32x4){0.f, 0.f, 0.f, 0.f}, 0, 0, 0);                   \
    S0 += fmaxf(acc.x + b1v[T], 0.f) * w2v[T];                                \
    S1 += fmaxf(acc.y + b1v[T], 0.f) * w2v[T];                                \
    S2 += fmaxf(acc.z + b1v[T], 0.f) * w2v[T];                                \
    S3 += fmaxf(acc.w + b1v[T], 0.f) * w2v[T];                                \
  }
      DO_T(0,  s00, s01, s02, s03) DO_T(1,  s00, s01, s02, s03)
      DO_T(2,  s00, s01, s02, s03) DO_T(3,  s00, s01, s02, s03)
      DO_T(4,  s10, s11, s12, s13) DO_T(5,  s10, s11, s12, s13)
      DO_T(6,  s10, s11, s12, s13) DO_T(7,  s10, s11, s12, s13)
      DO_T(8,  s20, s21, s22, s23) DO_T(9,  s20, s21, s22, s23)
      DO_T(10, s20, s21, s22, s23) DO_T(11, s20, s21, s22, s23)
      DO_T(12, s30, s31, s32, s33) DO_T(13, s30, s31, s32, s33)
      DO_T(14, s30, s31, s32, s33) DO_T(15, s30, s31, s32, s33)
#undef DO_T
#define RS_STEP1(AR, S0R, S1R) \
  float AR = (o1 ? S1R : S0R) + __shfl_xor(o1 ? S0R : S1R, 1);
      RS_STEP1(a0, s00, s10)
      RS_STEP1(a1, s01, s11)
      RS_STEP1(a2, s02, s12)
      RS_STEP1(a3, s03, s13)
      RS_STEP1(bb0, s20, s30)
      RS_STEP1(bb1, s21, s31)
      RS_STEP1(bb2, s22, s32)
      RS_STEP1(bb3, s23, s33)
#undef RS_STEP1
      float c0 = (o2 ? bb0 : a0) + __shfl_xor(o2 ? a0 : bb0, 2);
      float c1 = (o2 ? bb1 : a1) + __shfl_xor(o2 ? a1 : bb1, 2);
      float c2 = (o2 ? bb2 : a2) + __shfl_xor(o2 ? a2 : bb2, 2);
      float c3 = (o2 ? bb3 : a3) + __shfl_xor(o2 ? a3 : bb3, 2);
      c0 += __shfl_xor(c0, 4); c1 += __shfl_xor(c1, 4);
      c2 += __shfl_xor(c2, 4); c3 += __shfl_xor(c3, 4);
      c0 += __shfl_xor(c0, 8); c1 += __shfl_xor(c1, 8);
      c2 += __shfl_xor(c2, 8); c3 += __shfl_xor(c3, 8);
      if (l15 < NL) {
        float g0 = 1.f / (1.f + __expf(-(c0 + b2)));
        float g1 = 1.f / (1.f + __expf(-(c1 + b2)));
        float g2 = 1.f / (1.f + __expf(-(c2 + b2)));
        float g3 = 1.f / (1.f + __expf(-(c3 + b2)));
        w_all4[(size_t)(fbase + quad * 4 + 0) * 4 + l15] = g0;
        w_all4[(size_t)(fbase + quad * 4 + 1) * 4 + l15] = g1;
        w_all4[(size_t)(fbase + quad * 4 + 2) * 4 + l15] = g2;
        w_all4[(size_t)(fbase + quad * 4 + 3) * 4 + l15] = g3;
      }
    }
  }
}

// ---------------- gather gates into CSR order -------------------------------
__global__ __launch_bounds__(256) void csr_gather(const int2* __restrict__ csr_se,
                                                  const float* __restrict__ w_all4,
                                                  float* __restrict__ csr_val) {
  int k = blockIdx.x * 256 + threadIdx.x;
  if (k >= EE) return;
  int eid = csr_se[k].y;
  eid = min(max(eid, 0), EE - 1);
  float4 w = reinterpret_cast<const float4*>(w_all4)[eid];
  csr_val[k] = w.x;
  csr_val[(size_t)EE + k] = w.y;
  csr_val[2 * (size_t)EE + k] = w.z;
  csr_val[3 * (size_t)EE + k] = w.w;
}

// ---------------- degree / dinv per layer (interleaved float4 out) ----------
__global__ __launch_bounds__(256) void deg_kernel(const int* __restrict__ offs,
                                                  const float* __restrict__ csr_val,
                                                  float* __restrict__ dinv4) {
  int n = blockIdx.x * 256 + threadIdx.x;
  if (n >= NN) return;
  int s = offs[n], e = offs[n + 1];
  float d0 = 1.f, d1 = 1.f, d2 = 1.f, d3 = 1.f;  // self-loop weight 1.0
  for (int k = s; k < e; k++) {
    d0 += csr_val[k];
    d1 += csr_val[EE + k];
    d2 += csr_val[2 * (size_t)EE + k];
    d3 += csr_val[3 * (size_t)EE + k];
  }
  float4 o;
  o.x = rsqrtf(d0); o.y = rsqrtf(d1); o.z = rsqrtf(d2); o.w = rsqrtf(d3);
  reinterpret_cast<float4*>(dinv4)[n] = o;
}

// csr_val[l][k] *= dinv_l[src_k]   (one float4 gather per edge)
__global__ __launch_bounds__(256) void csr_scale_kernel(const int2* __restrict__ csr_se,
                                                        const float* __restrict__ dinv4,
                                                        float* __restrict__ csr_val) {
  int k = blockIdx.x * 256 + threadIdx.x;
  if (k >= EE) return;
  int s = csr_se[k].x;
  s = min(max(s, 0), NN - 1);
  float4 d = reinterpret_cast<const float4*>(dinv4)[s];
  csr_val[k] *= d.x;
  csr_val[(size_t)EE + k] *= d.y;
  csr_val[2 * (size_t)EE + k] *= d.z;
  csr_val[3 * (size_t)EE + k] *= d.w;
}

// ---------------- node GEMM via MFMA: bf16 in, bf16 out ---------------------
__global__ __launch_bounds__(256) void gemm_nodes_bf16(
    const unsigned short* __restrict__ A16, const unsigned short* __restrict__ Wt,
    const void* __restrict__ bias, long boff, unsigned short* __restrict__ out16,
    int relu, const int* __restrict__ flag) {
  __shared__ alignas(16) unsigned short sA[64 * 136];
  __shared__ alignas(16) unsigned short sW[128 * 136];
  int tid = threadIdx.x;
  int rbase = blockIdx.x * 64;

#pragma unroll
  for (int p = 0; p < 8; p++) {
    int idx8 = p * 256 + tid;
    int n = idx8 >> 4, kc = idx8 & 15;
    uint4 v = reinterpret_cast<const uint4*>(Wt)[idx8];
    *reinterpret_cast<uint4*>(&sW[n * 136 + kc * 8]) = v;
  }
#pragma unroll
  for (int p = 0; p < 4; p++) {
    int idx8 = p * 256 + tid;
    int m = idx8 >> 4, kc = idx8 & 15;
    int row = rbase + m;
    uint4 v = make_uint4(0u, 0u, 0u, 0u);
    if (row < NN)
      v = *reinterpret_cast<const uint4*>(&A16[(size_t)row * HID + kc * 8]);
    *reinterpret_cast<uint4*>(&sA[m * 136 + kc * 8]) = v;
  }
  __syncthreads();

  int wave = tid >> 6, lane = tid & 63;
  int l15 = lane & 15, quad = lane >> 4;
  int mstrip = wave * 16;

  f32x4 acc[8];
#pragma unroll
  for (int t = 0; t < 8; t++) acc[t] = (f32x4){0.f, 0.f, 0.f, 0.f};

#pragma unroll
  for (int ks = 0; ks < 4; ks++) {
    int k0 = ks * 32 + quad * 8;
    bf16x8 a = *reinterpret_cast<const bf16x8*>(&sA[(mstrip + l15) * 136 + k0]);
#pragma unroll
    for (int t = 0; t < 8; t++) {
      bf16x8 b = *reinterpret_cast<const bf16x8*>(&sW[(t * 16 + l15) * 136 + k0]);
      acc[t] = __builtin_amdgcn_mfma_f32_16x16x32_bf16(a, b, acc[t], 0, 0, 0);
    }
  }

  bool bf = *flag != 0;
#pragma unroll
  for (int t = 0; t < 8; t++) {
    int n = t * 16 + l15;
    float bv = (boff >= 0) ? ldf(bias, boff + n, bf) : 0.f;
#pragma unroll
    for (int r = 0; r < 4; r++) {
      int row = rbase + mstrip + quad * 4 + r;
      if (row < NN) {
        float o = acc[t][r] + bv;
        if (relu) o = fmaxf(o, 0.f);
        out16[(size_t)row * HID + n] = f2bf_bits(o);
      }
    }
  }
}

// ---------------- tail GEMM via MFMA ----------------------------------------
__global__ __launch_bounds__(256) void gemm_tail_mfma(
    const float* __restrict__ A, int lda, const unsigned short* __restrict__ Wt,
    int Kp, const void* __restrict__ bias, float* __restrict__ outp, int ldo,
    int relu, const int* __restrict__ flag) {
  __shared__ alignas(16) unsigned short sA[64 * 264];
  __shared__ alignas(16) unsigned short sW[64 * 264];
  int tid = threadIdx.x;
  int rbase = blockIdx.x * 64;
  int nbase = blockIdx.y * 64;
  int wave = tid >> 6, lane = tid & 63;
  int l15 = lane & 15, quad = lane >> 4;
  int mstrip = wave * 16;

  f32x4 acc[4];
#pragma unroll
  for (int t = 0; t < 4; t++) acc[t] = (f32x4){0.f, 0.f, 0.f, 0.f};

  for (int kc = 0; kc < Kp; kc += 256) {
#pragma unroll 4
    for (int p = 0; p < 16; p++) {
      int idx = p * 1024 + tid * 4;
      int m = idx >> 8, k = idx & 255;
      float4 v = *reinterpret_cast<const float4*>(&A[(size_t)(rbase + m) * lda + kc + k]);
      ushort4 b;
      b.x = f2bf_bits(v.x); b.y = f2bf_bits(v.y);
      b.z = f2bf_bits(v.z); b.w = f2bf_bits(v.w);
      *reinterpret_cast<ushort4*>(&sA[m * 264 + k]) = b;
    }
#pragma unroll 4
    for (int p = 0; p < 8; p++) {
      int idx8 = p * 256 + tid;
      int n = idx8 >> 5, kk = (idx8 & 31) * 8;
      uint4 v = *reinterpret_cast<const uint4*>(&Wt[(size_t)(nbase + n) * Kp + kc + kk]);
      *reinterpret_cast<uint4*>(&sW[n * 264 + kk]) = v;
    }
    __syncthreads();
#pragma unroll
    for (int ks = 0; ks < 8; ks++) {
      int k0 = ks * 32 + quad * 8;
      bf16x8 a = *reinterpret_cast<const bf16x8*>(&sA[(mstrip + l15) * 264 + k0]);
#pragma unroll
      for (int nt = 0; nt < 4; nt++) {
        bf16x8 b = *reinterpret_cast<const bf16x8*>(&sW[(nt * 16 + l15) * 264 + k0]);
        acc[nt] = __builtin_amdgcn_mfma_f32_16x16x32_bf16(a, b, acc[nt], 0, 0, 0);
      }
    }
    __syncthreads();
  }

  bool bf = *flag != 0;
#pragma unroll
  for (int nt = 0; nt < 4; nt++) {
    int col = nbase + nt * 16 + l15;
    float bv = ldf(bias, col, bf);
#pragma unroll
    for (int r = 0; r < 4; r++) {
      int row = rbase + mstrip + quad * 4 + r;
      float o = acc[nt][r] + bv;
      if (relu) o = fmaxf(o, 0.f);
      outp[(size_t)row * ldo + col] = o;
    }
  }
}

// ---------------- aggregation (bf16 gather, f32 accumulate, bf16 out) -------
__global__ __launch_bounds__(128) void aggregate_kernel(
    const unsigned short* __restrict__ hl16, const int* __restrict__ offs,
    const int2* __restrict__ csr_se, const float* __restrict__ csr_val,
    const float* __restrict__ dinv4, int layer, const void* __restrict__ bias,
    long boff, unsigned short* __restrict__ out16, const int* __restrict__ flag) {
  bool bf = *flag != 0;
  int n = blockIdx.x;
  int c = threadIdx.x;
  __shared__ int s_src[128];
  __shared__ float s_val[128];
  int start = offs[n], end = offs[n + 1];
  float acc = 0.f;
  for (int base = start; base < end; base += 128) {
    int k = base + c;
    if (k < end) {
      s_src[c] = min(max(csr_se[k].x, 0), NN - 1);
      s_val[c] = csr_val[k];
    }
    __syncthreads();
    int m = min(128, end - base);
    for (int j = 0; j < m; j++)
      acc = fmaf(s_val[j], bfl((unsigned)hl16[(size_t)s_src[j] * HID + c]), acc);
    __syncthreads();
  }
  float dn = dinv4[(size_t)n * 4 + layer];
  float selfv = bfl((unsigned)hl16[(size_t)n * HID + c]);
  out16[(size_t)n * HID + c] =
      f2bf_bits(dn * acc + dn * dn * selfv + ldf(bias, boff + c, bf));
}

// ---------------- mean pool, 2-phase (bf16 input) ---------------------------
__global__ __launch_bounds__(128) void pool_partial(const unsigned short* __restrict__ h16,
                                                    const int* __restrict__ batch,
                                                    float* __restrict__ part) {
  int g = blockIdx.x, chunk = blockIdx.y, c = threadIdx.x;
  int lo = 0, hi = NN;
  while (lo < hi) { int mid = (lo + hi) >> 1; if (batch[mid] < g) lo = mid + 1; else hi = mid; }
  int start = lo;
  hi = NN;
  while (lo < hi) { int mid = (lo + hi) >> 1; if (batch[mid] < g + 1) lo = mid + 1; else hi = mid; }
  int end = lo;
  int len = end - start;
  int per = (len + PCH - 1) / PCH;
  int s = start + chunk * per;
  int e = min(s + per, end);
  float sum = 0.f;
  for (int n = s; n < e; n++) sum += bfl((unsigned)h16[(size_t)n * HID + c]);
  part[((size_t)g * PCH + chunk) * HID + c] = sum;
}

__global__ __launch_bounds__(128) void pool_combine(const float* __restrict__ part,
                                                    const int* __restrict__ batch,
                                                    float* __restrict__ cat) {
  int g = blockIdx.x, c = threadIdx.x;
  int lo = 0, hi = NN;
  while (lo < hi) { int mid = (lo + hi) >> 1; if (batch[mid] < g) lo = mid + 1; else hi = mid; }
  int start = lo;
  hi = NN;
  while (lo < hi) { int mid = (lo + hi) >> 1; if (batch[mid] < g + 1) lo = mid + 1; else hi = mid; }
  int end = lo;
  float s = 0.f;
#pragma unroll
  for (int k = 0; k < PCH; k++) s += part[((size_t)g * PCH + k) * HID + c];
  float cntf = (float)(end - start);
  cat[(size_t)g * PIN + c] = s / fmaxf(cntf, 1.f);
}

// ---------------- final [G,512] @ [512,1] + b -> out ------------------------
__global__ __launch_bounds__(64) void final_kernel(const float* __restrict__ A,
                                                   const void* __restrict__ W,
                                                   const void* __restrict__ b,
                                                   void* __restrict__ outp,
                                                   const int* __restrict__ flag) {
  bool bf = *flag != 0;
  int g = blockIdx.x, lane = threadIdx.x;
  float s = 0.f;
  for (int k = lane; k < PH; k += 64) s = fmaf(A[(size_t)g * PH + k], ldf(W, k, bf), s);
#pragma unroll
  for (int off = 32; off > 0; off >>= 1) s += __shfl_down(s, off);
  if (lane == 0) {
    float r = s + ldf(b, 0, bf);
    if (bf) ((bf16*)outp)[g] = __float2bfloat16(r);
    else    ((float*)outp)[g] = r;
  }
}

// ---------------------------------------------------------------------------
extern "C" void kernel_launch(void* const* d_in, const int* in_sizes, int n_in,
                              void* d_out, int out_size, void* d_ws, size_t ws_size,
                              hipStream_t stream) {
  const void* x      = d_in[0];
  const int*  ei     = (const int*)d_in[1];
  const void* eattr  = d_in[2];
  const int*  batch  = (const int*)d_in[3];
  const void* molf   = d_in[4];
  const void* lin_W  = d_in[5];
  const void* mW1    = d_in[6];
  const void* mb1    = d_in[7];
  const void* mW2    = d_in[8];
  const void* mb2    = d_in[9];
  const void* cbias  = d_in[10];
  const void* gW     = d_in[11];
  const void* gb     = d_in[12];
  const void* mlpW0  = d_in[13];
  const void* mlpb0  = d_in[14];
  const void* mlpW1  = d_in[15];
  const void* mlpb1  = d_in[16];
  const void* mlpW2  = d_in[17];
  const void* mlpb2  = d_in[18];
  const void* mlpW3  = d_in[19];
  const void* mlpb3  = d_in[20];
  const void* predW0 = d_in[21];
  const void* predb0 = d_in[22];
  const void* predW1 = d_in[23];
  const void* predb1 = d_in[24];
  const void* outW   = d_in[25];
  const void* outb   = d_in[26];

  char* base = (char*)d_ws;
  size_t off = 0;
  auto alloc = [&](size_t bytes) -> char* {
    char* p = base + off;
    off = (off + bytes + 255) & ~(size_t)255;
    return p;
  };
  unsigned short* h16  = (unsigned short*)alloc((size_t)NN * HID * 2);
  unsigned short* t16  = (unsigned short*)alloc((size_t)NN * HID * 2);
  unsigned short* hl16 = (unsigned short*)alloc((size_t)NN * HID * 2);
  float* dinv4    = (float*)alloc((size_t)NN * 4 * 4);
  int*   cnt      = (int*)alloc((size_t)NN * 4);
  int*   offs     = (int*)alloc((size_t)(NN + 1) * 4);
  int*   cursor   = (int*)alloc((size_t)NN * 4);
  int*   bsum     = (int*)alloc((size_t)256 * 4);
  int2*  csr_se   = (int2*)alloc((size_t)EE * 8);
  float* csr_val  = (float*)alloc((size_t)NL * EE * 4);
  float* w_all4   = (float*)alloc((size_t)EE * 4 * 4);
  unsigned short* Wt    = (unsigned short*)alloc((size_t)8 * HID * HID * 2);
  unsigned short* tailW = (unsigned short*)alloc((size_t)622592 * 2);
  unsigned short* edgeW = (unsigned short*)alloc((size_t)256 * 32 * 2);
  int*   flag     = (int*)alloc(256);
  float* part     = (float*)alloc((size_t)GG * PCH * HID * 4);
  float* molf32   = (float*)alloc((size_t)GG * 256 * 4);
  float* m0       = (float*)alloc((size_t)GG * MH * 4);
  float* m1       = (float*)alloc((size_t)GG * MH * 4);
  float* cat      = (float*)alloc((size_t)GG * PIN * 4);
  float* p0       = (float*)alloc((size_t)GG * PH * 4);
  float* p1       = (float*)alloc((size_t)GG * PH * 4);

  hipMemsetAsync(cnt, 0, (size_t)NN * 4, stream);
  hipMemsetAsync(cursor, 0, (size_t)NN * 4, stream);
  hipMemsetAsync(molf32, 0, (size_t)GG * 256 * 4, stream);

  // dtype probe first — everything downstream branches on it
  probe_kernel<<<1, 64, 0, stream>>>((const unsigned short*)x, flag);

  // weight prep
  prep_weights<<<512, 256, 0, stream>>>(lin_W, gW, Wt, flag);
  prep_tail<<<(622592 + 255) / 256, 256, 0, stream>>>(mlpW0, mlpW1, mlpW2, mlpW3,
                                                      predW0, predW1, tailW, flag);
  prep_edge_w<<<32, 256, 0, stream>>>(mW1, edgeW, flag);

  // x -> bf16 layer state
  {
    int n8 = NN * HID / 8;
    cvt_to_bf16<<<(n8 + 255) / 256, 256, 0, stream>>>(x, h16, n8, flag);
  }
  // edge gates (MFMA, ORIGINAL order, 8 frags/wave)
  edge_mlp_mfma<<<(EE + 511) / 512, 256, 0, stream>>>(eattr, edgeW, mb1, mW2, mb2,
                                                      w_all4, flag);
  // CSR build (3-phase parallel scan)
  count_kernel<<<(EE + 255) / 256, 256, 0, stream>>>(ei, cnt);
  scan_phase1<<<SCAN_B, 256, 0, stream>>>(cnt, bsum);
  scan_phase2<<<1, 256, 0, stream>>>(bsum, offs);
  scan_phase3<<<SCAN_B, 256, 0, stream>>>(cnt, bsum, offs);
  fill_kernel<<<(EE + 255) / 256, 256, 0, stream>>>(ei, offs, cursor, csr_se);
  // permute gates to CSR order, degrees, scaling
  csr_gather<<<(EE + 255) / 256, 256, 0, stream>>>(csr_se, w_all4, csr_val);
  deg_kernel<<<(NN + 255) / 256, 256, 0, stream>>>(offs, csr_val, dinv4);
  csr_scale_kernel<<<(EE + 255) / 256, 256, 0, stream>>>(csr_se, dinv4, csr_val);

  // GCN layers: lin(h16)->hl16; aggregate(hl16)->t16; gcn(t16)->h16
  const int gemm_blocks = (NN + 63) / 64;  // 782
  for (int l = 0; l < NL; l++) {
    gemm_nodes_bf16<<<gemm_blocks, 256, 0, stream>>>(
        h16, Wt + (size_t)l * HID * HID, nullptr, -1, hl16, 0, flag);
    aggregate_kernel<<<NN, 128, 0, stream>>>(hl16, offs, csr_se,
                                             csr_val + (size_t)l * EE, dinv4, l,
                                             cbias, (long)l * HID, t16, flag);
    gemm_nodes_bf16<<<gemm_blocks, 256, 0, stream>>>(
        t16, Wt + (size_t)(4 + l) * HID * HID, gb, (long)l * HID, h16, 1, flag);
  }

  // pooling -> cat[:, 0:128]  (2-phase, bf16 input)
  pool_partial<<<dim3(GG, PCH), 128, 0, stream>>>(h16, batch, part);
  pool_combine<<<GG, 128, 0, stream>>>(part, batch, cat);

  // molecular MLP -> cat[:, 128:256]  (MFMA tail, K-padded weights)
  cvt_molf<<<(GG * 50 + 255) / 256, 256, 0, stream>>>(molf, molf32, flag);
  gemm_tail_mfma<<<dim3(4, 4), 256, 0, stream>>>(molf32, 256, tailW + 0,      256, mlpb0, m0, 256, 1, flag);
  gemm_tail_mfma<<<dim3(4, 4), 256, 0, stream>>>(m0,     256, tailW + 65536,  256, mlpb1, m1, 256, 1, flag);
  gemm_tail_mfma<<<dim3(4, 4), 256, 0, stream>>>(m1,     256, tailW + 131072, 256, mlpb2, m0, 256, 1, flag);
  gemm_tail_mfma<<<dim3(4, 2), 256, 0, stream>>>(m0,     256, tailW + 196608, 256, mlpb3, cat + MOUT, 256, 1, flag);

  // predictor
  gemm_tail_mfma<<<dim3(4, 8), 256, 0, stream>>>(cat, 256, tailW + 229376, 256, predb0, p0, 512, 1, flag);
  gemm_tail_mfma<<<dim3(4, 8), 256, 0, stream>>>(p0,  512, tailW + 360448, 512, predb1, p1, 512, 1, flag);
  final_kernel<<<GG, 64, 0, stream>>>(p1, outW, outb, d_out, flag);
}